// Round 1
// baseline (6712.428 us; speedup 1.0000x reference)
//
#include <hip/hip_runtime.h>

// VoxelNet forward on MI355X. All f32 compute (no fp32 MFMA on CDNA4; bf16
// cast too risky vs absolute threshold). Pipeline:
//  voxelize (dense count + exact rank scan) -> feat -> PFN x3 (train-mode BN,
//  recompute strategy) -> scatter-max BEV -> 5x conv3x3+BN+relu -> head 1x1.

#define BATCH 2
#define NPTS 100000
#define GNX 176
#define GNY 200
#define GNZ 10
#define NCELL (GNX*GNY*GNZ)      // 352000
#define PMAX 32
#define MAXV 20000
#define NVOX (BATCH*MAXV)        // 40000
#define NPFN (NVOX*PMAX)         // 1,280,000
#define CONVH 200
#define CONVW 176
#define NPIX (CONVH*CONVW)       // 35200
#define SCAN_NB ((NCELL + 1023)/1024)   // 344

__device__ __forceinline__ int voxel_id(float x, float y, float z){
  float fx = (x - 0.0f)   / 0.4f;
  float fy = (y - -40.0f) / 0.4f;
  float fz = (z - -3.0f)  / 0.4f;
  int ix = (int)floorf(fx);
  int iy = (int)floorf(fy);
  int iz = (int)floorf(fz);
  if (ix < 0 || iy < 0 || iz < 0 || ix >= GNX || iy >= GNY || iz >= GNZ) return -1;
  return (ix*GNY + iy)*GNZ + iz;
}

extern "C" __global__ void k_count(const float* __restrict__ pts, int* __restrict__ cellcnt){
  int i = blockIdx.x*256 + threadIdx.x;
  if (i >= BATCH*NPTS) return;
  const float* q = pts + (size_t)i*4;
  int vid = voxel_id(q[0], q[1], q[2]);
  if (vid < 0) return;
  int b = i / NPTS;
  atomicAdd(&cellcnt[b*NCELL + vid], 1);
}

extern "C" __global__ void __launch_bounds__(256) k_blkcount(const int* __restrict__ cellcnt,
                                                             int* __restrict__ blks){
  int b = blockIdx.y, blk = blockIdx.x, t = threadIdx.x;
  int base = blk*1024 + t*4;
  int s = 0;
  #pragma unroll
  for (int i=0;i<4;i++){ int c = base+i; if (c < NCELL) s += (cellcnt[b*NCELL+c] > 0); }
  #pragma unroll
  for (int m=32;m>=1;m>>=1) s += __shfl_xor(s, m);
  __shared__ int red[4];
  if ((t&63)==0) red[t>>6] = s;
  __syncthreads();
  if (t==0) blks[b*512+blk] = red[0]+red[1]+red[2]+red[3];
}

extern "C" __global__ void k_scan(int* __restrict__ blks){
  if (threadIdx.x != 0) return;
  int b = blockIdx.x;
  int acc = 0;
  for (int i=0;i<SCAN_NB;i++){ int v = blks[b*512+i]; blks[b*512+i] = acc; acc += v; }
}

extern "C" __global__ void __launch_bounds__(256) k_assign(const int* __restrict__ cellcnt,
    const int* __restrict__ blks, int* __restrict__ slotmap, int* __restrict__ vv,
    int* __restrict__ cnt){
  int b = blockIdx.y, blk = blockIdx.x, t = threadIdx.x;
  int base = blk*1024 + t*4;
  int flag[4]; int s = 0;
  #pragma unroll
  for (int i=0;i<4;i++){
    int c = base+i;
    flag[i] = (c < NCELL) ? (cellcnt[b*NCELL+c] > 0) : 0;
    s += flag[i];
  }
  __shared__ int lds[256];
  lds[t] = s; __syncthreads();
  for (int o=1;o<256;o<<=1){
    int v = (t>=o) ? lds[t-o] : 0;
    __syncthreads();
    lds[t] += v;
    __syncthreads();
  }
  int run = blks[b*512+blk] + (lds[t]-s);   // exclusive rank among nonempty cells
  #pragma unroll
  for (int i=0;i<4;i++){
    int c = base+i;
    if (c >= NCELL) break;
    int sm = -1;
    if (flag[i]){
      if (run < MAXV){
        sm = run;
        vv[b*MAXV+run]  = c;
        cnt[b*MAXV+run] = min(cellcnt[b*NCELL+c], PMAX);
      }
      run++;
    }
    slotmap[b*NCELL+c] = sm;
  }
}

extern "C" __global__ void k_fill(const float* __restrict__ pts, const int* __restrict__ slotmap,
                                  int* __restrict__ fill, int* __restrict__ plist){
  int i = blockIdx.x*256 + threadIdx.x;
  if (i >= BATCH*NPTS) return;
  const float* q = pts + (size_t)i*4;
  int vid = voxel_id(q[0], q[1], q[2]);
  if (vid < 0) return;
  int b = i / NPTS;
  int slot = slotmap[b*NCELL+vid];
  if (slot < 0) return;
  int pos = atomicAdd(&fill[b*MAXV+slot], 1);
  if (pos < PMAX) plist[((size_t)b*MAXV+slot)*PMAX + pos] = i - b*NPTS;
}

extern "C" __global__ void __launch_bounds__(64) k_feat(const float* __restrict__ pts,
    const int* __restrict__ cnt, const int* __restrict__ plist, float* __restrict__ feat){
  int g  = threadIdx.x >> 5;
  int fv = blockIdx.x*2 + g;
  int p  = threadIdx.x & 31;
  int b  = fv / MAXV;
  __shared__ int lst[2][32];
  int c = cnt[fv];
  if (p < c) lst[g][p] = plist[(size_t)fv*PMAX + p];
  __syncthreads();
  if (p == 0){           // deterministic order: sort point indices ascending
    for (int i=1;i<c;i++){
      int key = lst[g][i]; int j = i-1;
      while (j >= 0 && lst[g][j] > key){ lst[g][j+1] = lst[g][j]; j--; }
      lst[g][j+1] = key;
    }
  }
  __syncthreads();
  float4 pt = make_float4(0.f,0.f,0.f,0.f);
  if (p < c){
    int id = lst[g][p];
    pt = *(const float4*)(pts + ((size_t)b*NPTS + id)*4);
  }
  float sx = pt.x, sy = pt.y, sz = pt.z;
  #pragma unroll
  for (int m=16;m>=1;m>>=1){
    sx += __shfl_xor(sx, m, 32); sy += __shfl_xor(sy, m, 32); sz += __shfl_xor(sz, m, 32);
  }
  float cd = (float)max(c, 1);
  float mx = sx/cd, my = sy/cd, mz = sz/cd;
  float4 lo, hi;
  if (p < c){
    lo = make_float4(pt.x, pt.y, pt.z, pt.w);
    hi = make_float4(pt.x-mx, pt.y-my, pt.z-mz, 0.f);
  } else {
    lo = make_float4(0.f,0.f,0.f,0.f); hi = lo;
  }
  float* fo = feat + (size_t)fv*(PMAX*8) + p*8;
  *(float4*)fo     = lo;
  *(float4*)(fo+4) = hi;
}

// ---- PFN layer 1 stats: x1 = feat @ w1 (7x32); accumulate per-channel sum/sumsq
extern "C" __global__ void __launch_bounds__(256) k_pfn1(const float* __restrict__ feat,
    const float* __restrict__ w1, float* __restrict__ st){
  float sum[32], sq[32];
  #pragma unroll
  for (int c=0;c<32;c++){ sum[c]=0.f; sq[c]=0.f; }
  for (int e = blockIdx.x*256 + threadIdx.x; e < NPFN; e += gridDim.x*256){
    float4 lo = *(const float4*)(feat + (size_t)e*8);
    float4 hi = *(const float4*)(feat + (size_t)e*8 + 4);
    float in[7] = {lo.x, lo.y, lo.z, lo.w, hi.x, hi.y, hi.z};
    #pragma unroll
    for (int c=0;c<32;c++){
      float v = 0.f;
      #pragma unroll
      for (int k=0;k<7;k++) v += in[k]*w1[k*32+c];
      sum[c] += v; sq[c] += v*v;
    }
  }
  __shared__ float lds[64];
  if (threadIdx.x < 64) lds[threadIdx.x] = 0.f;
  __syncthreads();
  #pragma unroll
  for (int c=0;c<32;c++){
    float s1 = sum[c], s2 = sq[c];
    #pragma unroll
    for (int m=32;m>=1;m>>=1){ s1 += __shfl_xor(s1,m); s2 += __shfl_xor(s2,m); }
    if ((threadIdx.x&63)==0){ atomicAdd(&lds[c], s1); atomicAdd(&lds[32+c], s2); }
  }
  __syncthreads();
  if (threadIdx.x < 64) atomicAdd(&st[threadIdx.x], lds[threadIdx.x]);
}

// ---- PFN pass 2: h1 = relu(bn1(x1)); vmax1 per voxel; x2 = [feat,vmax1]@w2; stats2
extern "C" __global__ void __launch_bounds__(256) k_pfn2(const float* __restrict__ feat,
    const int* __restrict__ cnt, const float* __restrict__ w1, const float* __restrict__ g1,
    const float* __restrict__ b1, const float* __restrict__ w2, const float* __restrict__ st1,
    float* __restrict__ st2, float* __restrict__ vmax1){
  int fv = blockIdx.x*8 + (threadIdx.x>>5);
  int p  = threadIdx.x & 31;
  int c_ = cnt[fv];
  float4 flo = *(const float4*)(feat + (size_t)fv*(PMAX*8) + p*8);
  float4 fhi = *(const float4*)(feat + (size_t)fv*(PMAX*8) + p*8 + 4);
  float in[7] = {flo.x, flo.y, flo.z, flo.w, fhi.x, fhi.y, fhi.z};
  float vmx[32];
  #pragma unroll
  for (int c=0;c<32;c++){
    float v = 0.f;
    #pragma unroll
    for (int k=0;k<7;k++) v += in[k]*w1[k*32+c];
    float m  = st1[c]/(float)NPFN;
    float va = st1[32+c]/(float)NPFN - m*m;
    float sc = g1[c]/sqrtf(va + 1e-3f);
    float h  = fmaxf((v - m)*sc + b1[c], 0.f);
    h = (p < c_) ? h : 0.f;
    #pragma unroll
    for (int m2=16;m2>=1;m2>>=1) h = fmaxf(h, __shfl_xor(h, m2, 32));
    vmx[c] = h;
  }
  if (p == 0){
    float* o = vmax1 + (size_t)fv*32;
    #pragma unroll
    for (int c=0;c<32;c++) o[c] = vmx[c];
  }
  __shared__ float lds[128];
  if (threadIdx.x < 128) lds[threadIdx.x] = 0.f;
  __syncthreads();
  #pragma unroll
  for (int c=0;c<64;c++){
    float v = 0.f;
    #pragma unroll
    for (int k=0;k<7;k++)  v += in[k]*w2[k*64+c];
    #pragma unroll
    for (int j=0;j<32;j++) v += vmx[j]*w2[(7+j)*64+c];
    float s = v, q = v*v;
    #pragma unroll
    for (int m2=16;m2>=1;m2>>=1){ s += __shfl_xor(s,m2,32); q += __shfl_xor(q,m2,32); }
    if (p == 0){ atomicAdd(&lds[c], s); atomicAdd(&lds[64+c], q); }
  }
  __syncthreads();
  if (threadIdx.x < 128) atomicAdd(&st2[threadIdx.x], lds[threadIdx.x]);
}

// ---- PFN pass 3: h2 = relu(bn2(x2)); vmax2; x3 = [feat,vmax2]@w3; stats3
extern "C" __global__ void __launch_bounds__(256) k_pfn3(const float* __restrict__ feat,
    const int* __restrict__ cnt, const float* __restrict__ w2, const float* __restrict__ g2,
    const float* __restrict__ b2, const float* __restrict__ w3, const float* __restrict__ vmax1,
    const float* __restrict__ st2, float* __restrict__ st3, float* __restrict__ vmax2){
  int fv = blockIdx.x*8 + (threadIdx.x>>5);
  int p  = threadIdx.x & 31;
  int c_ = cnt[fv];
  float4 flo = *(const float4*)(feat + (size_t)fv*(PMAX*8) + p*8);
  float4 fhi = *(const float4*)(feat + (size_t)fv*(PMAX*8) + p*8 + 4);
  float in[7] = {flo.x, flo.y, flo.z, flo.w, fhi.x, fhi.y, fhi.z};
  float v1[32];
  const float* vp = vmax1 + (size_t)fv*32;
  #pragma unroll
  for (int j=0;j<32;j++) v1[j] = vp[j];
  float vmx2[64];
  #pragma unroll
  for (int c=0;c<64;c++){
    float v = 0.f;
    #pragma unroll
    for (int k=0;k<7;k++)  v += in[k]*w2[k*64+c];
    #pragma unroll
    for (int j=0;j<32;j++) v += v1[j]*w2[(7+j)*64+c];
    float m  = st2[c]/(float)NPFN;
    float va = st2[64+c]/(float)NPFN - m*m;
    float sc = g2[c]/sqrtf(va + 1e-3f);
    float h  = fmaxf((v - m)*sc + b2[c], 0.f);
    h = (p < c_) ? h : 0.f;
    #pragma unroll
    for (int m2=16;m2>=1;m2>>=1) h = fmaxf(h, __shfl_xor(h, m2, 32));
    vmx2[c] = h;
  }
  if (p == 0){
    float* o = vmax2 + (size_t)fv*64;
    #pragma unroll
    for (int c=0;c<64;c++) o[c] = vmx2[c];
  }
  __shared__ float lds[128];
  if (threadIdx.x < 128) lds[threadIdx.x] = 0.f;
  __syncthreads();
  #pragma unroll
  for (int c=0;c<64;c++){
    float v = 0.f;
    #pragma unroll
    for (int k=0;k<7;k++)  v += in[k]*w3[k*64+c];
    #pragma unroll
    for (int j=0;j<64;j++) v += vmx2[j]*w3[(7+j)*64+c];
    float s = v, q = v*v;
    #pragma unroll
    for (int m2=16;m2>=1;m2>>=1){ s += __shfl_xor(s,m2,32); q += __shfl_xor(q,m2,32); }
    if (p == 0){ atomicAdd(&lds[c], s); atomicAdd(&lds[64+c], q); }
  }
  __syncthreads();
  if (threadIdx.x < 128) atomicAdd(&st3[threadIdx.x], lds[threadIdx.x]);
}

// ---- PFN pass 4: h3 = relu(bn3(x3)); vf = masked max * (cnt>0); scatter-max to BEV
extern "C" __global__ void __launch_bounds__(256) k_pfn4(const float* __restrict__ feat,
    const int* __restrict__ cnt, const int* __restrict__ vv, const float* __restrict__ w3,
    const float* __restrict__ g3, const float* __restrict__ b3, const float* __restrict__ vmax2,
    const float* __restrict__ st3, float* __restrict__ bev){
  int fv = blockIdx.x*8 + (threadIdx.x>>5);
  int p  = threadIdx.x & 31;
  int c_ = cnt[fv];
  float4 flo = *(const float4*)(feat + (size_t)fv*(PMAX*8) + p*8);
  float4 fhi = *(const float4*)(feat + (size_t)fv*(PMAX*8) + p*8 + 4);
  float in[7] = {flo.x, flo.y, flo.z, flo.w, fhi.x, fhi.y, fhi.z};
  float v2[64];
  const float* vp = vmax2 + (size_t)fv*64;
  #pragma unroll
  for (int j=0;j<64;j++) v2[j] = vp[j];
  float vf[64];
  #pragma unroll
  for (int c=0;c<64;c++){
    float v = 0.f;
    #pragma unroll
    for (int k=0;k<7;k++)  v += in[k]*w3[k*64+c];
    #pragma unroll
    for (int j=0;j<64;j++) v += v2[j]*w3[(7+j)*64+c];
    float m  = st3[c]/(float)NPFN;
    float va = st3[64+c]/(float)NPFN - m*m;
    float sc = g3[c]/sqrtf(va + 1e-3f);
    float h  = fmaxf((v - m)*sc + b3[c], 0.f);
    h = (p < c_) ? h : 0.f;
    #pragma unroll
    for (int m2=16;m2>=1;m2>>=1) h = fmaxf(h, __shfl_xor(h, m2, 32));
    vf[c] = h;
  }
  if (p == 0 && c_ > 0){
    int vid = vv[fv];
    int b   = fv / MAXV;
    int cx  = vid / (GNY*GNZ);
    int cy  = (vid / GNZ) % GNY;
    float* base = bev + (size_t)b*64*NPIX + (size_t)cy*CONVW + cx;
    #pragma unroll
    for (int c=0;c<64;c++)
      atomicMax((int*)(base + (size_t)c*NPIX), __float_as_int(vf[c]));  // values >= 0
  }
}

// ---- 3x3 SAME conv + bias, accumulate per-channel sum/sumsq
#define CTW 16
#define CTH 16
extern "C" __global__ void __launch_bounds__(128) k_conv(const float* __restrict__ in,
    const float* __restrict__ w, const float* __restrict__ bias, float* __restrict__ out,
    float* __restrict__ st){
  const int b = blockIdx.z >> 1, half = blockIdx.z & 1;
  const int x0 = blockIdx.x*CTW, y0 = blockIdx.y*CTH;
  const int tx = threadIdx.x & 15, ty = threadIdx.x >> 4;   // ty in 0..7, 2 rows per thread
  __shared__ float tin[8][CTH+2][CTW+4];   // [8 ic][18][20] (pad to 20: 2-way bank alias only)
  __shared__ float twt[8][32][9];
  __shared__ float sred[128];
  float acc0[32], acc1[32];
  #pragma unroll
  for (int i=0;i<32;i++){ acc0[i]=0.f; acc1[i]=0.f; }
  for (int ch=0; ch<8; ch++){
    __syncthreads();
    for (int idx=threadIdx.x; idx<18*18*8; idx+=128){
      int ic = idx/324; int rem = idx - ic*324; int r = rem/18; int cc = rem - r*18;
      int gy = y0 + r - 1, gx = x0 + cc - 1;
      float v = 0.f;
      if (gy >= 0 && gy < CONVH && gx >= 0 && gx < CONVW)
        v = in[(((size_t)b*64 + ch*8+ic)*CONVH + gy)*CONVW + gx];
      tin[ic][r][cc] = v;
    }
    for (int idx=threadIdx.x; idx<2304; idx+=128){
      int ic = idx/288; int rem = idx - ic*288; int oc = rem/9; int k = rem - oc*9;
      twt[ic][oc][k] = w[(((size_t)(half*32+oc))*64 + ch*8+ic)*9 + k];
    }
    __syncthreads();
    #pragma unroll 1
    for (int ic=0;ic<8;ic++){
      float r_[4][3];
      #pragma unroll
      for (int dy=0;dy<4;dy++)
        #pragma unroll
        for (int dx=0;dx<3;dx++)
          r_[dy][dx] = tin[ic][2*ty+dy][tx+dx];
      #pragma unroll
      for (int oc=0;oc<32;oc++){
        float a0 = acc0[oc], a1 = acc1[oc];
        #pragma unroll
        for (int ky=0;ky<3;ky++)
          #pragma unroll
          for (int kx=0;kx<3;kx++){
            float wv = twt[ic][oc][ky*3+kx];
            a0 += r_[ky][kx]  *wv;
            a1 += r_[ky+1][kx]*wv;
          }
        acc0[oc] = a0; acc1[oc] = a1;
      }
    }
  }
  __syncthreads();
  if (threadIdx.x < 128) sred[threadIdx.x] = 0.f;
  __syncthreads();
  const int gx  = x0 + tx;
  const int gy0 = y0 + 2*ty, gy1 = gy0 + 1;
  const bool vl0 = gy0 < CONVH, vl1 = gy1 < CONVH;
  #pragma unroll
  for (int oc=0;oc<32;oc++){
    float bv = bias[half*32+oc];
    float o0 = acc0[oc]+bv, o1 = acc1[oc]+bv;
    size_t obase = ((size_t)b*64 + half*32+oc)*CONVH;
    if (vl0) out[(obase+gy0)*CONVW+gx] = o0;
    if (vl1) out[(obase+gy1)*CONVW+gx] = o1;
    float s = (vl0?o0:0.f)+(vl1?o1:0.f);
    float q = (vl0?o0*o0:0.f)+(vl1?o1*o1:0.f);
    #pragma unroll
    for (int m=32;m>=1;m>>=1){ s += __shfl_xor(s,m); q += __shfl_xor(q,m); }
    if ((threadIdx.x&63)==0){ atomicAdd(&sred[oc], s); atomicAdd(&sred[64+oc], q); }
  }
  __syncthreads();
  if (threadIdx.x < 32) atomicAdd(&st[half*32 + threadIdx.x], sred[threadIdx.x]);
  else if (threadIdx.x >= 64 && threadIdx.x < 96)
    atomicAdd(&st[64 + half*32 + (threadIdx.x-64)], sred[threadIdx.x]);
}

extern "C" __global__ void k_bnrelu(float* __restrict__ x, const float* __restrict__ st,
                                    const float* __restrict__ g, const float* __restrict__ be){
  int i = blockIdx.x*256 + threadIdx.x;
  if (i >= BATCH*64*NPIX) return;
  int c = (i / NPIX) & 63;
  float m  = st[c]   /(float)(BATCH*NPIX);
  float va = st[64+c]/(float)(BATCH*NPIX) - m*m;
  float sc = g[c]/sqrtf(va + 1e-5f);
  x[i] = fmaxf((x[i]-m)*sc + be[c], 0.f);
}

extern "C" __global__ void k_head(const float* __restrict__ in, const float* __restrict__ hw,
                                  const float* __restrict__ hb, float* __restrict__ outp){
  int i = blockIdx.x*256 + threadIdx.x;
  if (i >= BATCH*NPIX) return;
  int b = i / NPIX; int px = i - b*NPIX;
  const float* base = in + (size_t)b*64*NPIX + px;
  float a0 = hb[0], a1 = hb[1], a2 = hb[2];
  #pragma unroll
  for (int ic=0;ic<64;ic++){
    float v = base[(size_t)ic*NPIX];
    a0 += v*hw[ic]; a1 += v*hw[64+ic]; a2 += v*hw[128+ic];
  }
  size_t o = (size_t)i*3;
  outp[o+0] = a0; outp[o+1] = a1; outp[o+2] = a2;
}

extern "C" void kernel_launch(void* const* d_in, const int* in_sizes, int n_in,
                              void* d_out, int out_size, void* d_ws, size_t ws_size,
                              hipStream_t stream){
  (void)in_sizes; (void)n_in; (void)out_size;
  const float* pts   = (const float*)d_in[0];
  const float* w1    = (const float*)d_in[1];
  const float* g1    = (const float*)d_in[2];
  const float* b1    = (const float*)d_in[3];
  const float* w2    = (const float*)d_in[4];
  const float* g2    = (const float*)d_in[5];
  const float* b2    = (const float*)d_in[6];
  const float* w3    = (const float*)d_in[7];
  const float* g3    = (const float*)d_in[8];
  const float* b3    = (const float*)d_in[9];
  const float* cs_w  = (const float*)d_in[10];
  const float* cs_b  = (const float*)d_in[11];
  const float* cs_g  = (const float*)d_in[12];
  const float* cs_be = (const float*)d_in[13];
  const float* rpn_w = (const float*)d_in[14];
  const float* rpn_b = (const float*)d_in[15];
  const float* rpn_g = (const float*)d_in[16];
  const float* rpn_be= (const float*)d_in[17];
  const float* hw    = (const float*)d_in[18];
  const float* hb    = (const float*)d_in[19];

  char* ws = (char*)d_ws;
  size_t off = 0;
  auto alloc = [&](size_t bytes)->char*{
    char* p = ws + off; off += (bytes + 255) & ~(size_t)255; return p;
  };
  int*   cellcnt = (int*)  alloc((size_t)BATCH*NCELL*4);
  int*   slotmap = (int*)  alloc((size_t)BATCH*NCELL*4);
  int*   blks    = (int*)  alloc((size_t)BATCH*512*4);
  int*   vv      = (int*)  alloc((size_t)NVOX*4);
  int*   cnt     = (int*)  alloc((size_t)NVOX*4);
  int*   fill    = (int*)  alloc((size_t)NVOX*4);
  int*   plist   = (int*)  alloc((size_t)NVOX*PMAX*4);
  float* feat    = (float*)alloc((size_t)NPFN*8*4);
  float* vmax1   = (float*)alloc((size_t)NVOX*32*4);
  float* vmax2   = (float*)alloc((size_t)NVOX*64*4);
  float* stats   = (float*)alloc(4096);
  float* convA   = (float*)alloc((size_t)BATCH*64*NPIX*4);
  float* convB   = (float*)alloc((size_t)BATCH*64*NPIX*4);
  if (off > ws_size) return;   // ~99 MB needed

  hipMemsetAsync(cellcnt, 0, (size_t)BATCH*NCELL*4, stream);
  hipMemsetAsync(vv,   0, (size_t)NVOX*4, stream);
  hipMemsetAsync(cnt,  0, (size_t)NVOX*4, stream);
  hipMemsetAsync(fill, 0, (size_t)NVOX*4, stream);
  hipMemsetAsync(stats,0, 4096, stream);
  hipMemsetAsync(convA,0, (size_t)BATCH*64*NPIX*4, stream);

  k_count <<<(BATCH*NPTS+255)/256, 256, 0, stream>>>(pts, cellcnt);
  k_blkcount<<<dim3(SCAN_NB,BATCH), 256, 0, stream>>>(cellcnt, blks);
  k_scan  <<<BATCH, 64, 0, stream>>>(blks);
  k_assign<<<dim3(SCAN_NB,BATCH), 256, 0, stream>>>(cellcnt, blks, slotmap, vv, cnt);
  k_fill  <<<(BATCH*NPTS+255)/256, 256, 0, stream>>>(pts, slotmap, fill, plist);
  k_feat  <<<NVOX/2, 64, 0, stream>>>(pts, cnt, plist, feat);

  k_pfn1<<<2048, 256, 0, stream>>>(feat, w1, stats);
  k_pfn2<<<NVOX/8, 256, 0, stream>>>(feat, cnt, w1, g1, b1, w2, stats, stats+64, vmax1);
  k_pfn3<<<NVOX/8, 256, 0, stream>>>(feat, cnt, w2, g2, b2, w3, vmax1, stats+64, stats+192, vmax2);
  k_pfn4<<<NVOX/8, 256, 0, stream>>>(feat, cnt, vv, w3, g3, b3, vmax2, stats+192, convA);

  const float* wptr[5]  = {cs_w, cs_w+36864, rpn_w, rpn_w+36864, rpn_w+73728};
  const float* bptr[5]  = {cs_b, cs_b+64,   rpn_b, rpn_b+64,   rpn_b+128};
  const float* gptr[5]  = {cs_g, cs_g+64,   rpn_g, rpn_g+64,   rpn_g+128};
  const float* beptr[5] = {cs_be,cs_be+64,  rpn_be,rpn_be+64,  rpn_be+128};
  float* bufs[2] = {convA, convB};
  dim3 cgrid(CONVW/CTW, (CONVH+CTH-1)/CTH, BATCH*2);
  for (int l=0;l<5;l++){
    float* src = bufs[l&1];
    float* dst = bufs[(l&1)^1];
    float* stc = stats + 320 + l*128;
    k_conv  <<<cgrid, 128, 0, stream>>>(src, wptr[l], bptr[l], dst, stc);
    k_bnrelu<<<(BATCH*64*NPIX+255)/256, 256, 0, stream>>>(dst, stc, gptr[l], beptr[l]);
  }
  k_head<<<(BATCH*NPIX+255)/256, 256, 0, stream>>>(bufs[1], hw, hb, (float*)d_out);
}

// Round 2
// 2263.838 us; speedup vs baseline: 2.9651x; 2.9651x over previous
//
#include <hip/hip_runtime.h>

// VoxelNet forward on MI355X. Round 2: PFN restructured to wave-per-voxel,
// lane-per-channel. Key facts: vmax-part of PFN layer-2/3 matmuls is
// per-voxel constant; avg cnt ~1.3 points/voxel; pad-slot BN stats are
// closed-form. Eliminates the round-1 scratch spill (v2[64]/vf[64] arrays).

#define BATCH 2
#define NPTS 100000
#define GNX 176
#define GNY 200
#define GNZ 10
#define NCELL (GNX*GNY*GNZ)      // 352000
#define PMAX 32
#define MAXV 20000
#define NVOX (BATCH*MAXV)        // 40000
#define NPFN (NVOX*PMAX)         // 1,280,000
#define CONVH 200
#define CONVW 176
#define NPIX (CONVH*CONVW)       // 35200
#define SCAN_NB ((NCELL + 1023)/1024)   // 344

__device__ __forceinline__ int voxel_id(float x, float y, float z){
  int ix = (int)floorf(x / 0.4f);
  int iy = (int)floorf((y + 40.0f) / 0.4f);
  int iz = (int)floorf((z + 3.0f) / 0.4f);
  if (ix < 0 || iy < 0 || iz < 0 || ix >= GNX || iy >= GNY || iz >= GNZ) return -1;
  return (ix*GNY + iy)*GNZ + iz;
}

extern "C" __global__ void k_count(const float* __restrict__ pts, int* __restrict__ cellcnt){
  int i = blockIdx.x*256 + threadIdx.x;
  if (i >= BATCH*NPTS) return;
  const float* q = pts + (size_t)i*4;
  int vid = voxel_id(q[0], q[1], q[2]);
  if (vid < 0) return;
  int b = i / NPTS;
  atomicAdd(&cellcnt[b*NCELL + vid], 1);
}

extern "C" __global__ void __launch_bounds__(256) k_blkcount(const int* __restrict__ cellcnt,
                                                             int* __restrict__ blks){
  int b = blockIdx.y, blk = blockIdx.x, t = threadIdx.x;
  int base = blk*1024 + t*4;
  int s = 0;
  #pragma unroll
  for (int i=0;i<4;i++){ int c = base+i; if (c < NCELL) s += (cellcnt[b*NCELL+c] > 0); }
  #pragma unroll
  for (int m=32;m>=1;m>>=1) s += __shfl_xor(s, m);
  __shared__ int red[4];
  if ((t&63)==0) red[t>>6] = s;
  __syncthreads();
  if (t==0) blks[b*512+blk] = red[0]+red[1]+red[2]+red[3];
}

extern "C" __global__ void k_scan(int* __restrict__ blks){
  if (threadIdx.x != 0) return;
  int b = blockIdx.x;
  int acc = 0;
  for (int i=0;i<SCAN_NB;i++){ int v = blks[b*512+i]; blks[b*512+i] = acc; acc += v; }
}

extern "C" __global__ void __launch_bounds__(256) k_assign(const int* __restrict__ cellcnt,
    const int* __restrict__ blks, int* __restrict__ slotmap, int* __restrict__ vv,
    int* __restrict__ cnt){
  int b = blockIdx.y, blk = blockIdx.x, t = threadIdx.x;
  int base = blk*1024 + t*4;
  int flag[4]; int s = 0;
  #pragma unroll
  for (int i=0;i<4;i++){
    int c = base+i;
    flag[i] = (c < NCELL) ? (cellcnt[b*NCELL+c] > 0) : 0;
    s += flag[i];
  }
  __shared__ int lds[256];
  lds[t] = s; __syncthreads();
  for (int o=1;o<256;o<<=1){
    int v = (t>=o) ? lds[t-o] : 0;
    __syncthreads();
    lds[t] += v;
    __syncthreads();
  }
  int run = blks[b*512+blk] + (lds[t]-s);
  #pragma unroll
  for (int i=0;i<4;i++){
    int c = base+i;
    if (c >= NCELL) break;
    int sm = -1;
    if (flag[i]){
      if (run < MAXV){
        sm = run;
        vv[b*MAXV+run]  = c;
        cnt[b*MAXV+run] = min(cellcnt[b*NCELL+c], PMAX);
      }
      run++;
    }
    slotmap[b*NCELL+c] = sm;
  }
}

extern "C" __global__ void k_fill(const float* __restrict__ pts, const int* __restrict__ slotmap,
                                  int* __restrict__ fill, int* __restrict__ plist){
  int i = blockIdx.x*256 + threadIdx.x;
  if (i >= BATCH*NPTS) return;
  const float* q = pts + (size_t)i*4;
  int vid = voxel_id(q[0], q[1], q[2]);
  if (vid < 0) return;
  int b = i / NPTS;
  int slot = slotmap[b*NCELL+vid];
  if (slot < 0) return;
  int pos = atomicAdd(&fill[b*MAXV+slot], 1);
  if (pos < PMAX) plist[((size_t)b*MAXV+slot)*PMAX + pos] = i - b*NPTS;
}

extern "C" __global__ void __launch_bounds__(64) k_feat(const float* __restrict__ pts,
    const int* __restrict__ cnt, const int* __restrict__ plist, float* __restrict__ feat){
  int g  = threadIdx.x >> 5;
  int fv = blockIdx.x*2 + g;
  int p  = threadIdx.x & 31;
  int b  = fv / MAXV;
  __shared__ int lst[2][32];
  int c = cnt[fv];
  if (p < c) lst[g][p] = plist[(size_t)fv*PMAX + p];
  __syncthreads();
  if (p == 0){           // deterministic order: sort point indices ascending
    for (int i=1;i<c;i++){
      int key = lst[g][i]; int j = i-1;
      while (j >= 0 && lst[g][j] > key){ lst[g][j+1] = lst[g][j]; j--; }
      lst[g][j+1] = key;
    }
  }
  __syncthreads();
  float4 pt = make_float4(0.f,0.f,0.f,0.f);
  if (p < c){
    int id = lst[g][p];
    pt = *(const float4*)(pts + ((size_t)b*NPTS + id)*4);
  }
  float sx = pt.x, sy = pt.y, sz = pt.z;
  #pragma unroll
  for (int m=16;m>=1;m>>=1){
    sx += __shfl_xor(sx, m, 32); sy += __shfl_xor(sy, m, 32); sz += __shfl_xor(sz, m, 32);
  }
  float cd = (float)max(c, 1);
  if (p < c){
    float* fo = feat + (size_t)fv*(PMAX*8) + p*8;
    *(float4*)fo     = pt;
    *(float4*)(fo+4) = make_float4(pt.x-sx/cd, pt.y-sy/cd, pt.z-sz/cd, 0.f);
  }
}

// ================= PFN: wave-per-voxel, lane-per-channel =================
// stats1: x1 = feat@w1 (pads contribute exactly 0)
extern "C" __global__ void __launch_bounds__(256) k_p1(const float* __restrict__ feat,
    const int* __restrict__ cnt, const float* __restrict__ w1, float* __restrict__ st){
  int w = threadIdx.x >> 6, lane = threadIdx.x & 63;
  int fv = blockIdx.x*4 + w;
  __shared__ float fL[4][256];
  __shared__ float sL[64];
  if (threadIdx.x < 64) sL[threadIdx.x] = 0.f;
  int c_ = cnt[fv];
  for (int idx=lane; idx<c_*8; idx+=64) fL[w][idx] = feat[(size_t)fv*256 + idx];
  __syncthreads();
  int c = lane & 31, half = lane >> 5;
  float wr[7];
  #pragma unroll
  for (int k=0;k<7;k++) wr[k] = w1[k*32+c];
  float s=0.f, q=0.f;
  for (int p=half; p<c_; p+=2){
    float v = 0.f;
    #pragma unroll
    for (int k=0;k<7;k++) v += fL[w][p*8+k]*wr[k];
    s += v; q += v*v;
  }
  s += __shfl_xor(s, 32); q += __shfl_xor(q, 32);
  __syncthreads();
  if (half == 0){ atomicAdd(&sL[c], s); atomicAdd(&sL[32+c], q); }
  __syncthreads();
  if (threadIdx.x < 64) atomicAdd(&st[threadIdx.x], sL[threadIdx.x]);
}

// pass2: h1=relu(bn1(x1)); vmax1; stats of x2=[feat,vmax1]@w2 (pads = K_c)
extern "C" __global__ void __launch_bounds__(256) k_p2(const float* __restrict__ feat,
    const int* __restrict__ cnt, const float* __restrict__ w1, const float* __restrict__ g1,
    const float* __restrict__ b1, const float* __restrict__ w2, const float* __restrict__ st1,
    float* __restrict__ st2, float* __restrict__ vmax1){
  int w = threadIdx.x >> 6, lane = threadIdx.x & 63;
  int fv = blockIdx.x*4 + w;
  __shared__ float fL[4][256];
  __shared__ float vL[4][32];
  __shared__ float sL[128];
  if (threadIdx.x < 128) sL[threadIdx.x] = 0.f;
  int c_ = cnt[fv];
  for (int idx=lane; idx<c_*8; idx+=64) fL[w][idx] = feat[(size_t)fv*256 + idx];
  __syncthreads();
  const float invN = 1.f/(float)NPFN;
  int c1 = lane & 31, half = lane >> 5;
  {
    float m  = st1[c1]*invN;
    float va = st1[32+c1]*invN - m*m;
    float sc = g1[c1]*rsqrtf(va + 1e-3f);
    float sh = b1[c1] - m*sc;
    float wr[7];
    #pragma unroll
    for (int k=0;k<7;k++) wr[k] = w1[k*32+c1];
    float vm = 0.f;
    for (int p=half; p<c_; p+=2){
      float v = 0.f;
      #pragma unroll
      for (int k=0;k<7;k++) v += fL[w][p*8+k]*wr[k];
      vm = fmaxf(vm, fmaxf(v*sc+sh, 0.f));
    }
    vm = fmaxf(vm, __shfl_xor(vm, 32));
    if (half == 0){ vmax1[(size_t)fv*32+c1] = vm; vL[w][c1] = vm; }
  }
  __syncthreads();
  {
    int c = lane;
    float wr[7];
    #pragma unroll
    for (int k=0;k<7;k++) wr[k] = w2[k*64+c];
    float K = 0.f;
    #pragma unroll
    for (int j=0;j<32;j++) K += vL[w][j]*w2[(7+j)*64+c];
    float s = (float)(PMAX - c_)*K;
    float q = (float)(PMAX - c_)*K*K;
    for (int p=0; p<c_; p++){
      float a = 0.f;
      #pragma unroll
      for (int k=0;k<7;k++) a += fL[w][p*8+k]*wr[k];
      float x = a + K;
      s += x; q += x*x;
    }
    atomicAdd(&sL[c], s); atomicAdd(&sL[64+c], q);
  }
  __syncthreads();
  if (threadIdx.x < 128) atomicAdd(&st2[threadIdx.x], sL[threadIdx.x]);
}

// pass3: h2=relu(bn2(x2)); vmax2; stats of x3=[feat,vmax2]@w3
extern "C" __global__ void __launch_bounds__(256) k_p3(const float* __restrict__ feat,
    const int* __restrict__ cnt, const float* __restrict__ w2, const float* __restrict__ g2,
    const float* __restrict__ b2, const float* __restrict__ w3, const float* __restrict__ vmax1,
    const float* __restrict__ st2, float* __restrict__ st3, float* __restrict__ vmax2){
  int w = threadIdx.x >> 6, lane = threadIdx.x & 63;
  int fv = blockIdx.x*4 + w;
  __shared__ float fL[4][256];
  __shared__ float v1L[4][32];
  __shared__ float v2L[4][64];
  __shared__ float sL[128];
  if (threadIdx.x < 128) sL[threadIdx.x] = 0.f;
  int c_ = cnt[fv];
  for (int idx=lane; idx<c_*8; idx+=64) fL[w][idx] = feat[(size_t)fv*256 + idx];
  if (lane < 32) v1L[w][lane] = vmax1[(size_t)fv*32+lane];
  __syncthreads();
  const float invN = 1.f/(float)NPFN;
  int c = lane;
  {
    float m  = st2[c]*invN;
    float va = st2[64+c]*invN - m*m;
    float sc = g2[c]*rsqrtf(va + 1e-3f);
    float sh = b2[c] - m*sc;
    float wr[7];
    #pragma unroll
    for (int k=0;k<7;k++) wr[k] = w2[k*64+c];
    float K = 0.f;
    #pragma unroll
    for (int j=0;j<32;j++) K += v1L[w][j]*w2[(7+j)*64+c];
    float vm = 0.f;
    for (int p=0; p<c_; p++){
      float a = 0.f;
      #pragma unroll
      for (int k=0;k<7;k++) a += fL[w][p*8+k]*wr[k];
      vm = fmaxf(vm, fmaxf((a+K)*sc+sh, 0.f));
    }
    vmax2[(size_t)fv*64+c] = vm;
    v2L[w][c] = vm;
  }
  __syncthreads();
  {
    float wr[7];
    #pragma unroll
    for (int k=0;k<7;k++) wr[k] = w3[k*64+c];
    float K = 0.f;
    #pragma unroll
    for (int j=0;j<64;j++) K += v2L[w][j]*w3[(7+j)*64+c];
    float s = (float)(PMAX - c_)*K;
    float q = (float)(PMAX - c_)*K*K;
    for (int p=0; p<c_; p++){
      float a = 0.f;
      #pragma unroll
      for (int k=0;k<7;k++) a += fL[w][p*8+k]*wr[k];
      float x = a + K;
      s += x; q += x*x;
    }
    atomicAdd(&sL[c], s); atomicAdd(&sL[64+c], q);
  }
  __syncthreads();
  if (threadIdx.x < 128) atomicAdd(&st3[threadIdx.x], sL[threadIdx.x]);
}

// pass4: h3=relu(bn3(x3)); vf = per-voxel max; scatter-max into BEV (per-lane atomics)
extern "C" __global__ void __launch_bounds__(256) k_p4(const float* __restrict__ feat,
    const int* __restrict__ cnt, const int* __restrict__ vv, const float* __restrict__ w3,
    const float* __restrict__ g3, const float* __restrict__ b3, const float* __restrict__ vmax2,
    const float* __restrict__ st3, float* __restrict__ bev){
  int w = threadIdx.x >> 6, lane = threadIdx.x & 63;
  int fv = blockIdx.x*4 + w;
  __shared__ float fL[4][256];
  __shared__ float v2L[4][64];
  int c_ = cnt[fv];
  for (int idx=lane; idx<c_*8; idx+=64) fL[w][idx] = feat[(size_t)fv*256 + idx];
  v2L[w][lane] = vmax2[(size_t)fv*64+lane];
  __syncthreads();
  const float invN = 1.f/(float)NPFN;
  int c = lane;
  float m  = st3[c]*invN;
  float va = st3[64+c]*invN - m*m;
  float sc = g3[c]*rsqrtf(va + 1e-3f);
  float sh = b3[c] - m*sc;
  float wr[7];
  #pragma unroll
  for (int k=0;k<7;k++) wr[k] = w3[k*64+c];
  float K = 0.f;
  #pragma unroll
  for (int j=0;j<64;j++) K += v2L[w][j]*w3[(7+j)*64+c];
  float vf = 0.f;
  for (int p=0; p<c_; p++){
    float a = 0.f;
    #pragma unroll
    for (int k=0;k<7;k++) a += fL[w][p*8+k]*wr[k];
    vf = fmaxf(vf, fmaxf((a+K)*sc+sh, 0.f));
  }
  if (c_ > 0){
    int vid = vv[fv];
    int b   = fv / MAXV;
    int cx  = vid / (GNY*GNZ);
    int cy  = (vid / GNZ) % GNY;
    atomicMax((int*)(bev + ((size_t)b*64 + c)*NPIX + (size_t)cy*CONVW + cx),
              __float_as_int(vf));   // vf >= 0
  }
}

// ---- 3x3 SAME conv + bias, accumulate per-channel sum/sumsq
#define CTW 16
#define CTH 16
extern "C" __global__ void __launch_bounds__(128) k_conv(const float* __restrict__ in,
    const float* __restrict__ w, const float* __restrict__ bias, float* __restrict__ out,
    float* __restrict__ st){
  const int b = blockIdx.z >> 1, half = blockIdx.z & 1;
  const int x0 = blockIdx.x*CTW, y0 = blockIdx.y*CTH;
  const int tx = threadIdx.x & 15, ty = threadIdx.x >> 4;
  __shared__ float tin[8][CTH+2][CTW+4];
  __shared__ float twt[8][32][9];
  __shared__ float sred[128];
  float acc0[32], acc1[32];
  #pragma unroll
  for (int i=0;i<32;i++){ acc0[i]=0.f; acc1[i]=0.f; }
  for (int ch=0; ch<8; ch++){
    __syncthreads();
    for (int idx=threadIdx.x; idx<18*18*8; idx+=128){
      int ic = idx/324; int rem = idx - ic*324; int r = rem/18; int cc = rem - r*18;
      int gy = y0 + r - 1, gx = x0 + cc - 1;
      float v = 0.f;
      if (gy >= 0 && gy < CONVH && gx >= 0 && gx < CONVW)
        v = in[(((size_t)b*64 + ch*8+ic)*CONVH + gy)*CONVW + gx];
      tin[ic][r][cc] = v;
    }
    for (int idx=threadIdx.x; idx<2304; idx+=128){
      int ic = idx/288; int rem = idx - ic*288; int oc = rem/9; int k = rem - oc*9;
      twt[ic][oc][k] = w[(((size_t)(half*32+oc))*64 + ch*8+ic)*9 + k];
    }
    __syncthreads();
    #pragma unroll 1
    for (int ic=0;ic<8;ic++){
      float r_[4][3];
      #pragma unroll
      for (int dy=0;dy<4;dy++)
        #pragma unroll
        for (int dx=0;dx<3;dx++)
          r_[dy][dx] = tin[ic][2*ty+dy][tx+dx];
      #pragma unroll
      for (int oc=0;oc<32;oc++){
        float a0 = acc0[oc], a1 = acc1[oc];
        #pragma unroll
        for (int ky=0;ky<3;ky++)
          #pragma unroll
          for (int kx=0;kx<3;kx++){
            float wv = twt[ic][oc][ky*3+kx];
            a0 += r_[ky][kx]  *wv;
            a1 += r_[ky+1][kx]*wv;
          }
        acc0[oc] = a0; acc1[oc] = a1;
      }
    }
  }
  __syncthreads();
  if (threadIdx.x < 128) sred[threadIdx.x] = 0.f;
  __syncthreads();
  const int gx  = x0 + tx;
  const int gy0 = y0 + 2*ty, gy1 = gy0 + 1;
  const bool vl0 = gy0 < CONVH, vl1 = gy1 < CONVH;
  #pragma unroll
  for (int oc=0;oc<32;oc++){
    float bv = bias[half*32+oc];
    float o0 = acc0[oc]+bv, o1 = acc1[oc]+bv;
    size_t obase = ((size_t)b*64 + half*32+oc)*CONVH;
    if (vl0) out[(obase+gy0)*CONVW+gx] = o0;
    if (vl1) out[(obase+gy1)*CONVW+gx] = o1;
    float s = (vl0?o0:0.f)+(vl1?o1:0.f);
    float q = (vl0?o0*o0:0.f)+(vl1?o1*o1:0.f);
    #pragma unroll
    for (int m=32;m>=1;m>>=1){ s += __shfl_xor(s,m); q += __shfl_xor(q,m); }
    if ((threadIdx.x&63)==0){ atomicAdd(&sred[oc], s); atomicAdd(&sred[64+oc], q); }
  }
  __syncthreads();
  if (threadIdx.x < 32) atomicAdd(&st[half*32 + threadIdx.x], sred[threadIdx.x]);
  else if (threadIdx.x >= 64 && threadIdx.x < 96)
    atomicAdd(&st[64 + half*32 + (threadIdx.x-64)], sred[threadIdx.x]);
}

extern "C" __global__ void k_bnrelu(float* __restrict__ x, const float* __restrict__ st,
                                    const float* __restrict__ g, const float* __restrict__ be){
  int i = blockIdx.x*256 + threadIdx.x;
  if (i >= BATCH*64*NPIX) return;
  int c = (i / NPIX) & 63;
  float m  = st[c]   /(float)(BATCH*NPIX);
  float va = st[64+c]/(float)(BATCH*NPIX) - m*m;
  float sc = g[c]/sqrtf(va + 1e-5f);
  x[i] = fmaxf((x[i]-m)*sc + be[c], 0.f);
}

extern "C" __global__ void k_head(const float* __restrict__ in, const float* __restrict__ hw,
                                  const float* __restrict__ hb, float* __restrict__ outp){
  int i = blockIdx.x*256 + threadIdx.x;
  if (i >= BATCH*NPIX) return;
  int b = i / NPIX; int px = i - b*NPIX;
  const float* base = in + (size_t)b*64*NPIX + px;
  float a0 = hb[0], a1 = hb[1], a2 = hb[2];
  #pragma unroll
  for (int ic=0;ic<64;ic++){
    float v = base[(size_t)ic*NPIX];
    a0 += v*hw[ic]; a1 += v*hw[64+ic]; a2 += v*hw[128+ic];
  }
  size_t o = (size_t)i*3;
  outp[o+0] = a0; outp[o+1] = a1; outp[o+2] = a2;
}

extern "C" void kernel_launch(void* const* d_in, const int* in_sizes, int n_in,
                              void* d_out, int out_size, void* d_ws, size_t ws_size,
                              hipStream_t stream){
  (void)in_sizes; (void)n_in; (void)out_size;
  const float* pts   = (const float*)d_in[0];
  const float* w1    = (const float*)d_in[1];
  const float* g1    = (const float*)d_in[2];
  const float* b1    = (const float*)d_in[3];
  const float* w2    = (const float*)d_in[4];
  const float* g2    = (const float*)d_in[5];
  const float* b2    = (const float*)d_in[6];
  const float* w3    = (const float*)d_in[7];
  const float* g3    = (const float*)d_in[8];
  const float* b3    = (const float*)d_in[9];
  const float* cs_w  = (const float*)d_in[10];
  const float* cs_b  = (const float*)d_in[11];
  const float* cs_g  = (const float*)d_in[12];
  const float* cs_be = (const float*)d_in[13];
  const float* rpn_w = (const float*)d_in[14];
  const float* rpn_b = (const float*)d_in[15];
  const float* rpn_g = (const float*)d_in[16];
  const float* rpn_be= (const float*)d_in[17];
  const float* hw    = (const float*)d_in[18];
  const float* hb    = (const float*)d_in[19];

  char* ws = (char*)d_ws;
  size_t off = 0;
  auto alloc = [&](size_t bytes)->char*{
    char* p = ws + off; off += (bytes + 255) & ~(size_t)255; return p;
  };
  int*   cellcnt = (int*)  alloc((size_t)BATCH*NCELL*4);
  int*   slotmap = (int*)  alloc((size_t)BATCH*NCELL*4);
  int*   blks    = (int*)  alloc((size_t)BATCH*512*4);
  int*   vv      = (int*)  alloc((size_t)NVOX*4);
  int*   cnt     = (int*)  alloc((size_t)NVOX*4);
  int*   fill    = (int*)  alloc((size_t)NVOX*4);
  int*   plist   = (int*)  alloc((size_t)NVOX*PMAX*4);
  float* feat    = (float*)alloc((size_t)NPFN*8*4);
  float* vmax1   = (float*)alloc((size_t)NVOX*32*4);
  float* vmax2   = (float*)alloc((size_t)NVOX*64*4);
  float* stats   = (float*)alloc(4096);
  float* convA   = (float*)alloc((size_t)BATCH*64*NPIX*4);
  float* convB   = (float*)alloc((size_t)BATCH*64*NPIX*4);
  if (off > ws_size) return;

  hipMemsetAsync(cellcnt, 0, (size_t)BATCH*NCELL*4, stream);
  hipMemsetAsync(vv,   0, (size_t)NVOX*4, stream);
  hipMemsetAsync(cnt,  0, (size_t)NVOX*4, stream);
  hipMemsetAsync(fill, 0, (size_t)NVOX*4, stream);
  hipMemsetAsync(stats,0, 4096, stream);
  hipMemsetAsync(convA,0, (size_t)BATCH*64*NPIX*4, stream);

  k_count <<<(BATCH*NPTS+255)/256, 256, 0, stream>>>(pts, cellcnt);
  k_blkcount<<<dim3(SCAN_NB,BATCH), 256, 0, stream>>>(cellcnt, blks);
  k_scan  <<<BATCH, 64, 0, stream>>>(blks);
  k_assign<<<dim3(SCAN_NB,BATCH), 256, 0, stream>>>(cellcnt, blks, slotmap, vv, cnt);
  k_fill  <<<(BATCH*NPTS+255)/256, 256, 0, stream>>>(pts, slotmap, fill, plist);
  k_feat  <<<NVOX/2, 64, 0, stream>>>(pts, cnt, plist, feat);

  k_p1<<<NVOX/4, 256, 0, stream>>>(feat, cnt, w1, stats);
  k_p2<<<NVOX/4, 256, 0, stream>>>(feat, cnt, w1, g1, b1, w2, stats, stats+64, vmax1);
  k_p3<<<NVOX/4, 256, 0, stream>>>(feat, cnt, w2, g2, b2, w3, vmax1, stats+64, stats+192, vmax2);
  k_p4<<<NVOX/4, 256, 0, stream>>>(feat, cnt, vv, w3, g3, b3, vmax2, stats+192, convA);

  const float* wptr[5]  = {cs_w, cs_w+36864, rpn_w, rpn_w+36864, rpn_w+73728};
  const float* bptr[5]  = {cs_b, cs_b+64,   rpn_b, rpn_b+64,   rpn_b+128};
  const float* gptr[5]  = {cs_g, cs_g+64,   rpn_g, rpn_g+64,   rpn_g+128};
  const float* beptr[5] = {cs_be,cs_be+64,  rpn_be,rpn_be+64,  rpn_be+128};
  float* bufs[2] = {convA, convB};
  dim3 cgrid(CONVW/CTW, (CONVH+CTH-1)/CTH, BATCH*2);
  for (int l=0;l<5;l++){
    float* src = bufs[l&1];
    float* dst = bufs[(l&1)^1];
    float* stc = stats + 320 + l*128;
    k_conv  <<<cgrid, 128, 0, stream>>>(src, wptr[l], bptr[l], dst, stc);
    k_bnrelu<<<(BATCH*64*NPIX+255)/256, 256, 0, stream>>>(dst, stc, gptr[l], beptr[l]);
  }
  k_head<<<(BATCH*NPIX+255)/256, 256, 0, stream>>>(bufs[1], hw, hb, (float*)d_out);
}

// Round 3
// 1190.230 us; speedup vs baseline: 5.6396x; 1.9020x over previous
//
#include <hip/hip_runtime.h>

// Round 3: convs -> bf16 MFMA implicit GEMM (NHWC chain), PFN/voxelize unchanged.

#define BATCH 2
#define NPTS 100000
#define GNX 176
#define GNY 200
#define GNZ 10
#define NCELL (GNX*GNY*GNZ)
#define PMAX 32
#define MAXV 20000
#define NVOX (BATCH*MAXV)
#define NPFN (NVOX*PMAX)
#define CONVH 200
#define CONVW 176
#define NPIX (CONVH*CONVW)        // 35200
#define NELEM (BATCH*NPIX*64)     // 4,505,600
#define SCAN_NB ((NCELL + 1023)/1024)

typedef __attribute__((ext_vector_type(8))) short short8;
typedef __attribute__((ext_vector_type(4))) float f32x4;

__device__ __forceinline__ unsigned short f2bf(float f){
  unsigned int u = __float_as_uint(f);
  u = (u + 0x7fffu + ((u >> 16) & 1u)) >> 16;
  return (unsigned short)u;
}
__device__ __forceinline__ float bf2f(unsigned short s){
  return __uint_as_float(((unsigned int)s) << 16);
}

__device__ __forceinline__ int voxel_id(float x, float y, float z){
  int ix = (int)floorf(x / 0.4f);
  int iy = (int)floorf((y + 40.0f) / 0.4f);
  int iz = (int)floorf((z + 3.0f) / 0.4f);
  if (ix < 0 || iy < 0 || iz < 0 || ix >= GNX || iy >= GNY || iz >= GNZ) return -1;
  return (ix*GNY + iy)*GNZ + iz;
}

extern "C" __global__ void k_count(const float* __restrict__ pts, int* __restrict__ cellcnt){
  int i = blockIdx.x*256 + threadIdx.x;
  if (i >= BATCH*NPTS) return;
  const float* q = pts + (size_t)i*4;
  int vid = voxel_id(q[0], q[1], q[2]);
  if (vid < 0) return;
  int b = i / NPTS;
  atomicAdd(&cellcnt[b*NCELL + vid], 1);
}

extern "C" __global__ void __launch_bounds__(256) k_blkcount(const int* __restrict__ cellcnt,
                                                             int* __restrict__ blks){
  int b = blockIdx.y, blk = blockIdx.x, t = threadIdx.x;
  int base = blk*1024 + t*4;
  int s = 0;
  #pragma unroll
  for (int i=0;i<4;i++){ int c = base+i; if (c < NCELL) s += (cellcnt[b*NCELL+c] > 0); }
  #pragma unroll
  for (int m=32;m>=1;m>>=1) s += __shfl_xor(s, m);
  __shared__ int red[4];
  if ((t&63)==0) red[t>>6] = s;
  __syncthreads();
  if (t==0) blks[b*512+blk] = red[0]+red[1]+red[2]+red[3];
}

extern "C" __global__ void k_scan(int* __restrict__ blks){
  if (threadIdx.x != 0) return;
  int b = blockIdx.x;
  int acc = 0;
  for (int i=0;i<SCAN_NB;i++){ int v = blks[b*512+i]; blks[b*512+i] = acc; acc += v; }
}

extern "C" __global__ void __launch_bounds__(256) k_assign(const int* __restrict__ cellcnt,
    const int* __restrict__ blks, int* __restrict__ slotmap, int* __restrict__ vv,
    int* __restrict__ cnt){
  int b = blockIdx.y, blk = blockIdx.x, t = threadIdx.x;
  int base = blk*1024 + t*4;
  int flag[4]; int s = 0;
  #pragma unroll
  for (int i=0;i<4;i++){
    int c = base+i;
    flag[i] = (c < NCELL) ? (cellcnt[b*NCELL+c] > 0) : 0;
    s += flag[i];
  }
  __shared__ int lds[256];
  lds[t] = s; __syncthreads();
  for (int o=1;o<256;o<<=1){
    int v = (t>=o) ? lds[t-o] : 0;
    __syncthreads();
    lds[t] += v;
    __syncthreads();
  }
  int run = blks[b*512+blk] + (lds[t]-s);
  #pragma unroll
  for (int i=0;i<4;i++){
    int c = base+i;
    if (c >= NCELL) break;
    int sm = -1;
    if (flag[i]){
      if (run < MAXV){
        sm = run;
        vv[b*MAXV+run]  = c;
        cnt[b*MAXV+run] = min(cellcnt[b*NCELL+c], PMAX);
      }
      run++;
    }
    slotmap[b*NCELL+c] = sm;
  }
}

extern "C" __global__ void k_fill(const float* __restrict__ pts, const int* __restrict__ slotmap,
                                  int* __restrict__ fill, int* __restrict__ plist){
  int i = blockIdx.x*256 + threadIdx.x;
  if (i >= BATCH*NPTS) return;
  const float* q = pts + (size_t)i*4;
  int vid = voxel_id(q[0], q[1], q[2]);
  if (vid < 0) return;
  int b = i / NPTS;
  int slot = slotmap[b*NCELL+vid];
  if (slot < 0) return;
  int pos = atomicAdd(&fill[b*MAXV+slot], 1);
  if (pos < PMAX) plist[((size_t)b*MAXV+slot)*PMAX + pos] = i - b*NPTS;
}

extern "C" __global__ void __launch_bounds__(64) k_feat(const float* __restrict__ pts,
    const int* __restrict__ cnt, const int* __restrict__ plist, float* __restrict__ feat){
  int g  = threadIdx.x >> 5;
  int fv = blockIdx.x*2 + g;
  int p  = threadIdx.x & 31;
  int b  = fv / MAXV;
  __shared__ int lst[2][32];
  int c = cnt[fv];
  if (p < c) lst[g][p] = plist[(size_t)fv*PMAX + p];
  __syncthreads();
  if (p == 0){
    for (int i=1;i<c;i++){
      int key = lst[g][i]; int j = i-1;
      while (j >= 0 && lst[g][j] > key){ lst[g][j+1] = lst[g][j]; j--; }
      lst[g][j+1] = key;
    }
  }
  __syncthreads();
  float4 pt = make_float4(0.f,0.f,0.f,0.f);
  if (p < c){
    int id = lst[g][p];
    pt = *(const float4*)(pts + ((size_t)b*NPTS + id)*4);
  }
  float sx = pt.x, sy = pt.y, sz = pt.z;
  #pragma unroll
  for (int m=16;m>=1;m>>=1){
    sx += __shfl_xor(sx, m, 32); sy += __shfl_xor(sy, m, 32); sz += __shfl_xor(sz, m, 32);
  }
  float cd = (float)max(c, 1);
  if (p < c){
    float* fo = feat + (size_t)fv*(PMAX*8) + p*8;
    *(float4*)fo     = pt;
    *(float4*)(fo+4) = make_float4(pt.x-sx/cd, pt.y-sy/cd, pt.z-sz/cd, 0.f);
  }
}

// ================= PFN (unchanged from round 2 except k_p4 target) =================
extern "C" __global__ void __launch_bounds__(256) k_p1(const float* __restrict__ feat,
    const int* __restrict__ cnt, const float* __restrict__ w1, float* __restrict__ st){
  int w = threadIdx.x >> 6, lane = threadIdx.x & 63;
  int fv = blockIdx.x*4 + w;
  __shared__ float fL[4][256];
  __shared__ float sL[64];
  if (threadIdx.x < 64) sL[threadIdx.x] = 0.f;
  int c_ = cnt[fv];
  for (int idx=lane; idx<c_*8; idx+=64) fL[w][idx] = feat[(size_t)fv*256 + idx];
  __syncthreads();
  int c = lane & 31, half = lane >> 5;
  float wr[7];
  #pragma unroll
  for (int k=0;k<7;k++) wr[k] = w1[k*32+c];
  float s=0.f, q=0.f;
  for (int p=half; p<c_; p+=2){
    float v = 0.f;
    #pragma unroll
    for (int k=0;k<7;k++) v += fL[w][p*8+k]*wr[k];
    s += v; q += v*v;
  }
  s += __shfl_xor(s, 32); q += __shfl_xor(q, 32);
  __syncthreads();
  if (half == 0){ atomicAdd(&sL[c], s); atomicAdd(&sL[32+c], q); }
  __syncthreads();
  if (threadIdx.x < 64) atomicAdd(&st[threadIdx.x], sL[threadIdx.x]);
}

extern "C" __global__ void __launch_bounds__(256) k_p2(const float* __restrict__ feat,
    const int* __restrict__ cnt, const float* __restrict__ w1, const float* __restrict__ g1,
    const float* __restrict__ b1, const float* __restrict__ w2, const float* __restrict__ st1,
    float* __restrict__ st2, float* __restrict__ vmax1){
  int w = threadIdx.x >> 6, lane = threadIdx.x & 63;
  int fv = blockIdx.x*4 + w;
  __shared__ float fL[4][256];
  __shared__ float vL[4][32];
  __shared__ float sL[128];
  if (threadIdx.x < 128) sL[threadIdx.x] = 0.f;
  int c_ = cnt[fv];
  for (int idx=lane; idx<c_*8; idx+=64) fL[w][idx] = feat[(size_t)fv*256 + idx];
  __syncthreads();
  const float invN = 1.f/(float)NPFN;
  int c1 = lane & 31, half = lane >> 5;
  {
    float m  = st1[c1]*invN;
    float va = st1[32+c1]*invN - m*m;
    float sc = g1[c1]*rsqrtf(va + 1e-3f);
    float sh = b1[c1] - m*sc;
    float wr[7];
    #pragma unroll
    for (int k=0;k<7;k++) wr[k] = w1[k*32+c1];
    float vm = 0.f;
    for (int p=half; p<c_; p+=2){
      float v = 0.f;
      #pragma unroll
      for (int k=0;k<7;k++) v += fL[w][p*8+k]*wr[k];
      vm = fmaxf(vm, fmaxf(v*sc+sh, 0.f));
    }
    vm = fmaxf(vm, __shfl_xor(vm, 32));
    if (half == 0){ vmax1[(size_t)fv*32+c1] = vm; vL[w][c1] = vm; }
  }
  __syncthreads();
  {
    int c = lane;
    float wr[7];
    #pragma unroll
    for (int k=0;k<7;k++) wr[k] = w2[k*64+c];
    float K = 0.f;
    #pragma unroll
    for (int j=0;j<32;j++) K += vL[w][j]*w2[(7+j)*64+c];
    float s = (float)(PMAX - c_)*K;
    float q = (float)(PMAX - c_)*K*K;
    for (int p=0; p<c_; p++){
      float a = 0.f;
      #pragma unroll
      for (int k=0;k<7;k++) a += fL[w][p*8+k]*wr[k];
      float x = a + K;
      s += x; q += x*x;
    }
    atomicAdd(&sL[c], s); atomicAdd(&sL[64+c], q);
  }
  __syncthreads();
  if (threadIdx.x < 128) atomicAdd(&st2[threadIdx.x], sL[threadIdx.x]);
}

extern "C" __global__ void __launch_bounds__(256) k_p3(const float* __restrict__ feat,
    const int* __restrict__ cnt, const float* __restrict__ w2, const float* __restrict__ g2,
    const float* __restrict__ b2, const float* __restrict__ w3, const float* __restrict__ vmax1,
    const float* __restrict__ st2, float* __restrict__ st3, float* __restrict__ vmax2){
  int w = threadIdx.x >> 6, lane = threadIdx.x & 63;
  int fv = blockIdx.x*4 + w;
  __shared__ float fL[4][256];
  __shared__ float v1L[4][32];
  __shared__ float v2L[4][64];
  __shared__ float sL[128];
  if (threadIdx.x < 128) sL[threadIdx.x] = 0.f;
  int c_ = cnt[fv];
  for (int idx=lane; idx<c_*8; idx+=64) fL[w][idx] = feat[(size_t)fv*256 + idx];
  if (lane < 32) v1L[w][lane] = vmax1[(size_t)fv*32+lane];
  __syncthreads();
  const float invN = 1.f/(float)NPFN;
  int c = lane;
  {
    float m  = st2[c]*invN;
    float va = st2[64+c]*invN - m*m;
    float sc = g2[c]*rsqrtf(va + 1e-3f);
    float sh = b2[c] - m*sc;
    float wr[7];
    #pragma unroll
    for (int k=0;k<7;k++) wr[k] = w2[k*64+c];
    float K = 0.f;
    #pragma unroll
    for (int j=0;j<32;j++) K += v1L[w][j]*w2[(7+j)*64+c];
    float vm = 0.f;
    for (int p=0; p<c_; p++){
      float a = 0.f;
      #pragma unroll
      for (int k=0;k<7;k++) a += fL[w][p*8+k]*wr[k];
      vm = fmaxf(vm, fmaxf((a+K)*sc+sh, 0.f));
    }
    vmax2[(size_t)fv*64+c] = vm;
    v2L[w][c] = vm;
  }
  __syncthreads();
  {
    float wr[7];
    #pragma unroll
    for (int k=0;k<7;k++) wr[k] = w3[k*64+c];
    float K = 0.f;
    #pragma unroll
    for (int j=0;j<64;j++) K += v2L[w][j]*w3[(7+j)*64+c];
    float s = (float)(PMAX - c_)*K;
    float q = (float)(PMAX - c_)*K*K;
    for (int p=0; p<c_; p++){
      float a = 0.f;
      #pragma unroll
      for (int k=0;k<7;k++) a += fL[w][p*8+k]*wr[k];
      float x = a + K;
      s += x; q += x*x;
    }
    atomicAdd(&sL[c], s); atomicAdd(&sL[64+c], q);
  }
  __syncthreads();
  if (threadIdx.x < 128) atomicAdd(&st3[threadIdx.x], sL[threadIdx.x]);
}

// pass4: vf = per-voxel max; scatter-max into BEV, **NHWC f32** layout
extern "C" __global__ void __launch_bounds__(256) k_p4(const float* __restrict__ feat,
    const int* __restrict__ cnt, const int* __restrict__ vv, const float* __restrict__ w3,
    const float* __restrict__ g3, const float* __restrict__ b3, const float* __restrict__ vmax2,
    const float* __restrict__ st3, float* __restrict__ bev){
  int w = threadIdx.x >> 6, lane = threadIdx.x & 63;
  int fv = blockIdx.x*4 + w;
  __shared__ float fL[4][256];
  __shared__ float v2L[4][64];
  int c_ = cnt[fv];
  for (int idx=lane; idx<c_*8; idx+=64) fL[w][idx] = feat[(size_t)fv*256 + idx];
  v2L[w][lane] = vmax2[(size_t)fv*64+lane];
  __syncthreads();
  const float invN = 1.f/(float)NPFN;
  int c = lane;
  float m  = st3[c]*invN;
  float va = st3[64+c]*invN - m*m;
  float sc = g3[c]*rsqrtf(va + 1e-3f);
  float sh = b3[c] - m*sc;
  float wr[7];
  #pragma unroll
  for (int k=0;k<7;k++) wr[k] = w3[k*64+c];
  float K = 0.f;
  #pragma unroll
  for (int j=0;j<64;j++) K += v2L[w][j]*w3[(7+j)*64+c];
  float vf = 0.f;
  for (int p=0; p<c_; p++){
    float a = 0.f;
    #pragma unroll
    for (int k=0;k<7;k++) a += fL[w][p*8+k]*wr[k];
    vf = fmaxf(vf, fmaxf((a+K)*sc+sh, 0.f));
  }
  if (c_ > 0){
    int vid = vv[fv];
    int b   = fv / MAXV;
    int cx  = vid / (GNY*GNZ);
    int cy  = (vid / GNZ) % GNY;
    // NHWC: [b][cy][cx][c] — 64 lanes write 256 contiguous bytes
    atomicMax((int*)(bev + (((size_t)b*NPIX + (size_t)cy*CONVW + cx)*64) + c),
              __float_as_int(vf));
  }
}

// ---- weight prepack: [oc][ic][3][3] f32 -> [tap][oc][ic] bf16, 5 layers
extern "C" __global__ void k_wprep(const float* __restrict__ cs_w, const float* __restrict__ rpn_w,
                                   unsigned short* __restrict__ Bw){
  int i = blockIdx.x*256 + threadIdx.x;
  if (i >= 5*36864) return;
  int l = i/36864, r = i - l*36864;
  int tap = r >> 12, oc = (r >> 6) & 63, ic = r & 63;
  const float* src = (l < 2) ? (cs_w + (size_t)l*36864) : (rpn_w + (size_t)(l-2)*36864);
  Bw[i] = f2bf(src[((size_t)oc*64 + ic)*9 + tap]);
}

// ---- f32 NHWC -> bf16 NHWC
extern "C" __global__ void k_cvt(const float* __restrict__ x, unsigned short* __restrict__ o){
  int i = blockIdx.x*256 + threadIdx.x;
  if (i*4 >= NELEM) return;
  float4 v = ((const float4*)x)[i];
  ushort4 r;
  r.x = f2bf(v.x); r.y = f2bf(v.y); r.z = f2bf(v.z); r.w = f2bf(v.w);
  ((ushort4*)o)[i] = r;
}

// ---- conv3x3: implicit GEMM, bf16 MFMA. Tile 4y x 16x pixels, 64 oc, 4 waves.
extern "C" __global__ void __launch_bounds__(256) k_conv(const unsigned short* __restrict__ in,
    const unsigned short* __restrict__ Bw, const float* __restrict__ bias,
    float* __restrict__ out, float* __restrict__ st){
  const int b  = blockIdx.z;
  const int x0 = blockIdx.x*16, y0 = blockIdx.y*4;
  const int tid = threadIdx.x;
  const int w = tid >> 6, l = tid & 63;
  const int l15 = l & 15, quad = l >> 4;

  __shared__ unsigned short smemA[6*18*64];   // [y'][x'][ic], 16B-block XOR swizzle on ic
  __shared__ float sA[64], sQ[64];
  if (tid < 64){ sA[tid] = 0.f; sQ[tid] = 0.f; }

  // stage input tile rows y0-1..y0+4, cols x0-1..x0+16
  for (int i = tid; i < 864; i += 256){
    int pos = i >> 3, jb = i & 7;
    int yp = pos/18, xp = pos - yp*18;
    int gy = y0 + yp - 1, gx = x0 + xp - 1;
    uint4 v = make_uint4(0u,0u,0u,0u);
    if (gy >= 0 && gy < CONVH && gx >= 0 && gx < CONVW)
      v = *(const uint4*)(in + (((size_t)b*NPIX + (size_t)gy*CONVW + gx)*64 + jb*8));
    int jsw = jb ^ (xp & 7);
    *(uint4*)&smemA[pos*64 + jsw*8] = v;
  }
  __syncthreads();

  f32x4 acc[4] = {{0.f,0.f,0.f,0.f},{0.f,0.f,0.f,0.f},{0.f,0.f,0.f,0.f},{0.f,0.f,0.f,0.f}};
  for (int tap = 0; tap < 9; tap++){
    int dy = tap/3, dx = tap - dy*3;
    int yp = w + dy, xp = l15 + dx;
    int abase = (yp*18 + xp)*64;
    int xm = (xp & 7);
    #pragma unroll
    for (int par = 0; par < 2; par++){
      int jb = par*4 + quad;
      short8 a = *(const short8*)&smemA[abase + (jb ^ xm)*8];
      #pragma unroll
      for (int nt = 0; nt < 4; nt++){
        const unsigned short* bp = Bw + (((size_t)tap*64 + nt*16 + l15)*64 + par*32 + quad*8);
        short8 bb = *(const short8*)bp;
        acc[nt] = __builtin_amdgcn_mfma_f32_16x16x32_bf16(a, bb, acc[nt], 0, 0, 0);
      }
    }
  }

  // epilogue: +bias, NHWC f32 store, BN stats.  D: col(oc-local)=l15, row(m)=quad*4+r
  const int y = y0 + w;
  #pragma unroll
  for (int nt = 0; nt < 4; nt++){
    int oc = nt*16 + l15;
    float bv = bias[oc];
    float s = 0.f, q = 0.f;
    #pragma unroll
    for (int r = 0; r < 4; r++){
      float v = acc[nt][r] + bv;
      int x = x0 + quad*4 + r;
      out[((size_t)b*NPIX + (size_t)y*CONVW + x)*64 + oc] = v;
      s += v; q += v*v;
    }
    atomicAdd(&sA[oc], s); atomicAdd(&sQ[oc], q);
  }
  __syncthreads();
  if (tid < 64){ atomicAdd(&st[tid], sA[tid]); atomicAdd(&st[64+tid], sQ[tid]); }
}

// ---- BN+relu: f32 NHWC -> bf16 NHWC
extern "C" __global__ void k_bnrelu(const float* __restrict__ x, const float* __restrict__ st,
    const float* __restrict__ g, const float* __restrict__ be, unsigned short* __restrict__ o){
  int i = blockIdx.x*256 + threadIdx.x;
  if (i*4 >= NELEM) return;
  const float invN = 1.f/(float)(BATCH*NPIX);
  float4 v = ((const float4*)x)[i];
  int c0 = (i*4) & 63;
  ushort4 r;
  float vv[4] = {v.x, v.y, v.z, v.w};
  unsigned short rr[4];
  #pragma unroll
  for (int k = 0; k < 4; k++){
    int c = c0 + k;
    float m  = st[c]*invN;
    float va = st[64+c]*invN - m*m;
    float sc = g[c]*rsqrtf(va + 1e-5f);
    rr[k] = f2bf(fmaxf((vv[k]-m)*sc + be[c], 0.f));
  }
  r.x = rr[0]; r.y = rr[1]; r.z = rr[2]; r.w = rr[3];
  ((ushort4*)o)[i] = r;
}

// ---- head 1x1: bf16 NHWC in, f32 out [B, NPIX, 3]
extern "C" __global__ void k_head(const unsigned short* __restrict__ in,
    const float* __restrict__ hw, const float* __restrict__ hb, float* __restrict__ outp){
  int i = blockIdx.x*256 + threadIdx.x;
  if (i >= BATCH*NPIX) return;
  const uint4* p = (const uint4*)(in + (size_t)i*64);
  float a0 = hb[0], a1 = hb[1], a2 = hb[2];
  #pragma unroll
  for (int j = 0; j < 8; j++){
    uint4 u = p[j];
    unsigned int uu[4] = {u.x, u.y, u.z, u.w};
    #pragma unroll
    for (int e = 0; e < 4; e++){
      int ic = j*8 + e*2;
      float v0 = bf2f((unsigned short)(uu[e] & 0xffffu));
      float v1 = bf2f((unsigned short)(uu[e] >> 16));
      a0 += v0*hw[ic] + v1*hw[ic+1];
      a1 += v0*hw[64+ic] + v1*hw[64+ic+1];
      a2 += v0*hw[128+ic] + v1*hw[128+ic+1];
    }
  }
  size_t o = (size_t)i*3;
  outp[o+0] = a0; outp[o+1] = a1; outp[o+2] = a2;
}

extern "C" void kernel_launch(void* const* d_in, const int* in_sizes, int n_in,
                              void* d_out, int out_size, void* d_ws, size_t ws_size,
                              hipStream_t stream){
  (void)in_sizes; (void)n_in; (void)out_size;
  const float* pts   = (const float*)d_in[0];
  const float* w1    = (const float*)d_in[1];
  const float* g1    = (const float*)d_in[2];
  const float* b1    = (const float*)d_in[3];
  const float* w2    = (const float*)d_in[4];
  const float* g2    = (const float*)d_in[5];
  const float* b2    = (const float*)d_in[6];
  const float* w3    = (const float*)d_in[7];
  const float* g3    = (const float*)d_in[8];
  const float* b3    = (const float*)d_in[9];
  const float* cs_w  = (const float*)d_in[10];
  const float* cs_b  = (const float*)d_in[11];
  const float* cs_g  = (const float*)d_in[12];
  const float* cs_be = (const float*)d_in[13];
  const float* rpn_w = (const float*)d_in[14];
  const float* rpn_b = (const float*)d_in[15];
  const float* rpn_g = (const float*)d_in[16];
  const float* rpn_be= (const float*)d_in[17];
  const float* hw    = (const float*)d_in[18];
  const float* hb    = (const float*)d_in[19];

  char* ws = (char*)d_ws;
  size_t off = 0;
  auto alloc = [&](size_t bytes)->char*{
    char* p = ws + off; off += (bytes + 255) & ~(size_t)255; return p;
  };
  int*   cellcnt = (int*)  alloc((size_t)BATCH*NCELL*4);
  int*   slotmap = (int*)  alloc((size_t)BATCH*NCELL*4);
  int*   blks    = (int*)  alloc((size_t)BATCH*512*4);
  int*   vv      = (int*)  alloc((size_t)NVOX*4);
  int*   cnt     = (int*)  alloc((size_t)NVOX*4);
  int*   fill    = (int*)  alloc((size_t)NVOX*4);
  int*   plist   = (int*)  alloc((size_t)NVOX*PMAX*4);
  float* feat    = (float*)alloc((size_t)NPFN*8*4);       // 40.96 MB; reused below
  float* vmax1   = (float*)alloc((size_t)NVOX*32*4);
  float* vmax2   = (float*)alloc((size_t)NVOX*64*4);
  float* stats   = (float*)alloc(4096);
  float* bevf    = (float*)alloc((size_t)NELEM*4);        // 18 MB f32 NHWC
  unsigned short* Bw = (unsigned short*)alloc((size_t)5*36864*2);
  if (off > ws_size) return;

  // alias conv-era buffers into feat's region (feat dead after k_p4)
  float*          convout = (float*)feat;                          // 18,022,400 B
  unsigned short* bfA     = (unsigned short*)((char*)feat + 18022400);  // 9,011,200 B
  unsigned short* bfB     = (unsigned short*)((char*)feat + 27033600);  // 9,011,200 B

  hipMemsetAsync(cellcnt, 0, (size_t)BATCH*NCELL*4, stream);
  hipMemsetAsync(vv,   0, (size_t)NVOX*4, stream);
  hipMemsetAsync(cnt,  0, (size_t)NVOX*4, stream);
  hipMemsetAsync(fill, 0, (size_t)NVOX*4, stream);
  hipMemsetAsync(stats,0, 4096, stream);
  hipMemsetAsync(bevf, 0, (size_t)NELEM*4, stream);

  k_count <<<(BATCH*NPTS+255)/256, 256, 0, stream>>>(pts, cellcnt);
  k_blkcount<<<dim3(SCAN_NB,BATCH), 256, 0, stream>>>(cellcnt, blks);
  k_scan  <<<BATCH, 64, 0, stream>>>(blks);
  k_assign<<<dim3(SCAN_NB,BATCH), 256, 0, stream>>>(cellcnt, blks, slotmap, vv, cnt);
  k_fill  <<<(BATCH*NPTS+255)/256, 256, 0, stream>>>(pts, slotmap, fill, plist);
  k_feat  <<<NVOX/2, 64, 0, stream>>>(pts, cnt, plist, feat);

  k_p1<<<NVOX/4, 256, 0, stream>>>(feat, cnt, w1, stats);
  k_p2<<<NVOX/4, 256, 0, stream>>>(feat, cnt, w1, g1, b1, w2, stats, stats+64, vmax1);
  k_p3<<<NVOX/4, 256, 0, stream>>>(feat, cnt, w2, g2, b2, w3, vmax1, stats+64, stats+192, vmax2);
  k_p4<<<NVOX/4, 256, 0, stream>>>(feat, cnt, vv, w3, g3, b3, vmax2, stats+192, bevf);

  k_wprep<<<(5*36864+255)/256, 256, 0, stream>>>(cs_w, rpn_w, Bw);
  k_cvt  <<<(NELEM/4+255)/256, 256, 0, stream>>>(bevf, bfA);

  const float* bptr[5]  = {cs_b, cs_b+64,   rpn_b, rpn_b+64,   rpn_b+128};
  const float* gptr[5]  = {cs_g, cs_g+64,   rpn_g, rpn_g+64,   rpn_g+128};
  const float* beptr[5] = {cs_be,cs_be+64,  rpn_be,rpn_be+64,  rpn_be+128};
  unsigned short* bufs[2] = {bfA, bfB};
  dim3 cgrid(CONVW/16, CONVH/4, BATCH);
  for (int ll = 0; ll < 5; ll++){
    unsigned short* src = bufs[ll & 1];
    unsigned short* dst = bufs[(ll & 1) ^ 1];
    float* stc = stats + 320 + ll*128;
    k_conv  <<<cgrid, 256, 0, stream>>>(src, Bw + (size_t)ll*36864, bptr[ll], convout, stc);
    k_bnrelu<<<(NELEM/4+255)/256, 256, 0, stream>>>(convout, stc, gptr[ll], beptr[ll], dst);
  }
  k_head<<<(BATCH*NPIX+255)/256, 256, 0, stream>>>(bufs[1], hw, hb, (float*)d_out);
}

// Round 4
// 526.834 us; speedup vs baseline: 12.7411x; 2.2592x over previous
//
#include <hip/hip_runtime.h>

// Round 4: PFN -> persistent blocks + LDS weights + register stats + 8-way
// shadowed stat atomics (kills the 10000-blocks-same-address contention that
// made k_p2/k_p3 248us at 7% VALUBusy). Conv stats also shadowed.

#define BATCH 2
#define NPTS 100000
#define GNX 176
#define GNY 200
#define GNZ 10
#define NCELL (GNX*GNY*GNZ)
#define PMAX 32
#define MAXV 20000
#define NVOX (BATCH*MAXV)
#define NPFN (NVOX*PMAX)
#define CONVH 200
#define CONVW 176
#define NPIX (CONVH*CONVW)
#define NELEM (BATCH*NPIX*64)
#define SCAN_NB ((NCELL + 1023)/1024)
#define PGRID 512
#define SHAD 8

typedef __attribute__((ext_vector_type(8))) short short8;
typedef __attribute__((ext_vector_type(4))) float f32x4;

__device__ __forceinline__ unsigned short f2bf(float f){
  unsigned int u = __float_as_uint(f);
  u = (u + 0x7fffu + ((u >> 16) & 1u)) >> 16;
  return (unsigned short)u;
}
__device__ __forceinline__ float bf2f(unsigned short s){
  return __uint_as_float(((unsigned int)s) << 16);
}

__device__ __forceinline__ int voxel_id(float x, float y, float z){
  int ix = (int)floorf(x / 0.4f);
  int iy = (int)floorf((y + 40.0f) / 0.4f);
  int iz = (int)floorf((z + 3.0f) / 0.4f);
  if (ix < 0 || iy < 0 || iz < 0 || ix >= GNX || iy >= GNY || iz >= GNZ) return -1;
  return (ix*GNY + iy)*GNZ + iz;
}

extern "C" __global__ void k_count(const float* __restrict__ pts, int* __restrict__ cellcnt){
  int i = blockIdx.x*256 + threadIdx.x;
  if (i >= BATCH*NPTS) return;
  const float* q = pts + (size_t)i*4;
  int vid = voxel_id(q[0], q[1], q[2]);
  if (vid < 0) return;
  int b = i / NPTS;
  atomicAdd(&cellcnt[b*NCELL + vid], 1);
}

extern "C" __global__ void __launch_bounds__(256) k_blkcount(const int* __restrict__ cellcnt,
                                                             int* __restrict__ blks){
  int b = blockIdx.y, blk = blockIdx.x, t = threadIdx.x;
  int base = blk*1024 + t*4;
  int s = 0;
  #pragma unroll
  for (int i=0;i<4;i++){ int c = base+i; if (c < NCELL) s += (cellcnt[b*NCELL+c] > 0); }
  #pragma unroll
  for (int m=32;m>=1;m>>=1) s += __shfl_xor(s, m);
  __shared__ int red[4];
  if ((t&63)==0) red[t>>6] = s;
  __syncthreads();
  if (t==0) blks[b*512+blk] = red[0]+red[1]+red[2]+red[3];
}

extern "C" __global__ void k_scan(int* __restrict__ blks){
  if (threadIdx.x != 0) return;
  int b = blockIdx.x;
  int acc = 0;
  for (int i=0;i<SCAN_NB;i++){ int v = blks[b*512+i]; blks[b*512+i] = acc; acc += v; }
}

extern "C" __global__ void __launch_bounds__(256) k_assign(const int* __restrict__ cellcnt,
    const int* __restrict__ blks, int* __restrict__ slotmap, int* __restrict__ vv,
    int* __restrict__ cnt){
  int b = blockIdx.y, blk = blockIdx.x, t = threadIdx.x;
  int base = blk*1024 + t*4;
  int flag[4]; int s = 0;
  #pragma unroll
  for (int i=0;i<4;i++){
    int c = base+i;
    flag[i] = (c < NCELL) ? (cellcnt[b*NCELL+c] > 0) : 0;
    s += flag[i];
  }
  __shared__ int lds[256];
  lds[t] = s; __syncthreads();
  for (int o=1;o<256;o<<=1){
    int v = (t>=o) ? lds[t-o] : 0;
    __syncthreads();
    lds[t] += v;
    __syncthreads();
  }
  int run = blks[b*512+blk] + (lds[t]-s);
  #pragma unroll
  for (int i=0;i<4;i++){
    int c = base+i;
    if (c >= NCELL) break;
    int sm = -1;
    if (flag[i]){
      if (run < MAXV){
        sm = run;
        vv[b*MAXV+run]  = c;
        cnt[b*MAXV+run] = min(cellcnt[b*NCELL+c], PMAX);
      }
      run++;
    }
    slotmap[b*NCELL+c] = sm;
  }
}

extern "C" __global__ void k_fill(const float* __restrict__ pts, const int* __restrict__ slotmap,
                                  int* __restrict__ fill, int* __restrict__ plist){
  int i = blockIdx.x*256 + threadIdx.x;
  if (i >= BATCH*NPTS) return;
  const float* q = pts + (size_t)i*4;
  int vid = voxel_id(q[0], q[1], q[2]);
  if (vid < 0) return;
  int b = i / NPTS;
  int slot = slotmap[b*NCELL+vid];
  if (slot < 0) return;
  int pos = atomicAdd(&fill[b*MAXV+slot], 1);
  if (pos < PMAX) plist[((size_t)b*MAXV+slot)*PMAX + pos] = i - b*NPTS;
}

extern "C" __global__ void __launch_bounds__(64) k_feat(const float* __restrict__ pts,
    const int* __restrict__ cnt, const int* __restrict__ plist, float* __restrict__ feat){
  int g  = threadIdx.x >> 5;
  int fv = blockIdx.x*2 + g;
  int p  = threadIdx.x & 31;
  int b  = fv / MAXV;
  __shared__ int lst[2][32];
  int c = cnt[fv];
  if (p < c) lst[g][p] = plist[(size_t)fv*PMAX + p];
  __syncthreads();
  if (p == 0){
    for (int i=1;i<c;i++){
      int key = lst[g][i]; int j = i-1;
      while (j >= 0 && lst[g][j] > key){ lst[g][j+1] = lst[g][j]; j--; }
      lst[g][j+1] = key;
    }
  }
  __syncthreads();
  float4 pt = make_float4(0.f,0.f,0.f,0.f);
  if (p < c){
    int id = lst[g][p];
    pt = *(const float4*)(pts + ((size_t)b*NPTS + id)*4);
  }
  float sx = pt.x, sy = pt.y, sz = pt.z;
  #pragma unroll
  for (int m=16;m>=1;m>>=1){
    sx += __shfl_xor(sx, m, 32); sy += __shfl_xor(sy, m, 32); sz += __shfl_xor(sz, m, 32);
  }
  float cd = (float)max(c, 1);
  if (p < c){
    float* fo = feat + (size_t)fv*(PMAX*8) + p*8;
    *(float4*)fo     = pt;
    *(float4*)(fo+4) = make_float4(pt.x-sx/cd, pt.y-sy/cd, pt.z-sz/cd, 0.f);
  }
}

// ============ PFN: persistent blocks, lane=channel, shadowed stats ============
extern "C" __global__ void __launch_bounds__(256) k_p1(const float* __restrict__ feat,
    const int* __restrict__ cnt, const float* __restrict__ w1, float* __restrict__ st){
  __shared__ float w1L[224];
  __shared__ float sred[64];
  int tid = threadIdx.x;
  if (tid < 224) w1L[tid] = w1[tid];
  if (tid < 64) sred[tid] = 0.f;
  __syncthreads();
  int w = tid>>6, lane = tid&63, c = lane&31, half = lane>>5;
  float S = 0.f, Q = 0.f;
  for (int fv = blockIdx.x*4 + w; fv < NVOX; fv += PGRID*4){
    int c_ = cnt[fv];
    for (int p = half; p < c_; p += 2){
      const float4* fp = (const float4*)(feat + (size_t)fv*256 + p*8);
      float4 lo = fp[0], hi = fp[1];
      float in[7] = {lo.x,lo.y,lo.z,lo.w,hi.x,hi.y,hi.z};
      float v = 0.f;
      #pragma unroll
      for (int k=0;k<7;k++) v += in[k]*w1L[k*32+c];
      S += v; Q += v*v;
    }
  }
  S += __shfl_xor(S, 32); Q += __shfl_xor(Q, 32);
  if (half == 0){ atomicAdd(&sred[c], S); atomicAdd(&sred[32+c], Q); }
  __syncthreads();
  if (tid < 64) atomicAdd(&st[(blockIdx.x&(SHAD-1))*64 + tid], sred[tid]);
}

extern "C" __global__ void __launch_bounds__(256) k_p2(const float* __restrict__ feat,
    const int* __restrict__ cnt, const float* __restrict__ w1, const float* __restrict__ g1,
    const float* __restrict__ b1, const float* __restrict__ w2, const float* __restrict__ st1,
    float* __restrict__ st2, float* __restrict__ vmax1){
  __shared__ float w1L[224];
  __shared__ float w2L[2496];
  __shared__ float sred[128];
  int tid = threadIdx.x;
  if (tid < 224) w1L[tid] = w1[tid];
  for (int i=tid;i<2496;i+=256) w2L[i] = w2[i];
  if (tid < 128) sred[tid] = 0.f;
  __syncthreads();
  int w = tid>>6, lane = tid&63, c1 = lane&31, half = lane>>5;
  const float invN = 1.f/(float)NPFN;
  float m1=0.f, v1s=0.f;
  #pragma unroll
  for (int s=0;s<SHAD;s++){ m1 += st1[s*64+c1]; v1s += st1[s*64+32+c1]; }
  m1 *= invN; v1s = v1s*invN - m1*m1;
  float sc1 = g1[c1]*rsqrtf(v1s + 1e-3f);
  float sh1 = b1[c1] - m1*sc1;
  float S = 0.f, Q = 0.f;
  for (int fv = blockIdx.x*4 + w; fv < NVOX; fv += PGRID*4){
    int c_ = cnt[fv];
    float vm = 0.f;
    for (int p = half; p < c_; p += 2){
      const float4* fp = (const float4*)(feat + (size_t)fv*256 + p*8);
      float4 lo = fp[0], hi = fp[1];
      float in[7] = {lo.x,lo.y,lo.z,lo.w,hi.x,hi.y,hi.z};
      float v = 0.f;
      #pragma unroll
      for (int k=0;k<7;k++) v += in[k]*w1L[k*32+c1];
      vm = fmaxf(vm, v*sc1 + sh1);
    }
    vm = fmaxf(vm, __shfl_xor(vm, 32));   // >=0: init 0 covers relu+mask
    if (half == 0) vmax1[(size_t)fv*32 + c1] = vm;
    float K = 0.f;
    #pragma unroll
    for (int j=0;j<32;j++) K += __shfl(vm, j)*w2L[(7+j)*64+lane];
    float s = (float)(PMAX-c_)*K, q = (float)(PMAX-c_)*K*K;
    for (int p = 0; p < c_; p++){
      const float4* fp = (const float4*)(feat + (size_t)fv*256 + p*8);
      float4 lo = fp[0], hi = fp[1];
      float in[7] = {lo.x,lo.y,lo.z,lo.w,hi.x,hi.y,hi.z};
      float a = 0.f;
      #pragma unroll
      for (int k=0;k<7;k++) a += in[k]*w2L[k*64+lane];
      float x = a + K; s += x; q += x*x;
    }
    S += s; Q += q;
  }
  atomicAdd(&sred[lane], S); atomicAdd(&sred[64+lane], Q);
  __syncthreads();
  if (tid < 128) atomicAdd(&st2[(blockIdx.x&(SHAD-1))*128 + tid], sred[tid]);
}

extern "C" __global__ void __launch_bounds__(256) k_p3(const float* __restrict__ feat,
    const int* __restrict__ cnt, const float* __restrict__ w2, const float* __restrict__ g2,
    const float* __restrict__ b2, const float* __restrict__ w3, const float* __restrict__ vmax1,
    const float* __restrict__ st2, float* __restrict__ st3, float* __restrict__ vmax2){
  __shared__ float w2L[2496];
  __shared__ float w3L[4544];
  __shared__ float sred[128];
  int tid = threadIdx.x;
  for (int i=tid;i<2496;i+=256) w2L[i] = w2[i];
  for (int i=tid;i<4544;i+=256) w3L[i] = w3[i];
  if (tid < 128) sred[tid] = 0.f;
  __syncthreads();
  int w = tid>>6, lane = tid&63;
  const float invN = 1.f/(float)NPFN;
  float m2=0.f, v2s=0.f;
  #pragma unroll
  for (int s=0;s<SHAD;s++){ m2 += st2[s*128+lane]; v2s += st2[s*128+64+lane]; }
  m2 *= invN; v2s = v2s*invN - m2*m2;
  float sc2 = g2[lane]*rsqrtf(v2s + 1e-3f);
  float sh2 = b2[lane] - m2*sc2;
  float S = 0.f, Q = 0.f;
  for (int fv = blockIdx.x*4 + w; fv < NVOX; fv += PGRID*4){
    int c_ = cnt[fv];
    float K2 = 0.f;
    #pragma unroll
    for (int jb=0;jb<8;jb++){
      float4 vv = *(const float4*)(vmax1 + (size_t)fv*32 + jb*4);
      K2 += vv.x*w2L[(7+jb*4)*64+lane] + vv.y*w2L[(8+jb*4)*64+lane]
          + vv.z*w2L[(9+jb*4)*64+lane] + vv.w*w2L[(10+jb*4)*64+lane];
    }
    float vm = 0.f;
    for (int p = 0; p < c_; p++){
      const float4* fp = (const float4*)(feat + (size_t)fv*256 + p*8);
      float4 lo = fp[0], hi = fp[1];
      float in[7] = {lo.x,lo.y,lo.z,lo.w,hi.x,hi.y,hi.z};
      float a = 0.f;
      #pragma unroll
      for (int k=0;k<7;k++) a += in[k]*w2L[k*64+lane];
      vm = fmaxf(vm, (a+K2)*sc2 + sh2);
    }
    vmax2[(size_t)fv*64 + lane] = vm;
    float K3 = 0.f;
    #pragma unroll
    for (int j=0;j<64;j++) K3 += __shfl(vm, j)*w3L[(7+j)*64+lane];
    float s = (float)(PMAX-c_)*K3, q = (float)(PMAX-c_)*K3*K3;
    for (int p = 0; p < c_; p++){
      const float4* fp = (const float4*)(feat + (size_t)fv*256 + p*8);
      float4 lo = fp[0], hi = fp[1];
      float in[7] = {lo.x,lo.y,lo.z,lo.w,hi.x,hi.y,hi.z};
      float a = 0.f;
      #pragma unroll
      for (int k=0;k<7;k++) a += in[k]*w3L[k*64+lane];
      float x = a + K3; s += x; q += x*x;
    }
    S += s; Q += q;
  }
  atomicAdd(&sred[lane], S); atomicAdd(&sred[64+lane], Q);
  __syncthreads();
  if (tid < 128) atomicAdd(&st3[(blockIdx.x&(SHAD-1))*128 + tid], sred[tid]);
}

extern "C" __global__ void __launch_bounds__(256) k_p4(const float* __restrict__ feat,
    const int* __restrict__ cnt, const int* __restrict__ vv, const float* __restrict__ w3,
    const float* __restrict__ g3, const float* __restrict__ b3, const float* __restrict__ vmax2,
    const float* __restrict__ st3, float* __restrict__ bev){
  __shared__ float w3L[4544];
  int tid = threadIdx.x;
  for (int i=tid;i<4544;i+=256) w3L[i] = w3[i];
  __syncthreads();
  int w = tid>>6, lane = tid&63;
  const float invN = 1.f/(float)NPFN;
  float m3=0.f, v3s=0.f;
  #pragma unroll
  for (int s=0;s<SHAD;s++){ m3 += st3[s*128+lane]; v3s += st3[s*128+64+lane]; }
  m3 *= invN; v3s = v3s*invN - m3*m3;
  float sc3 = g3[lane]*rsqrtf(v3s + 1e-3f);
  float sh3 = b3[lane] - m3*sc3;
  for (int fv = blockIdx.x*4 + w; fv < NVOX; fv += PGRID*4){
    int c_ = cnt[fv];
    if (c_ == 0) continue;
    float K = 0.f;
    #pragma unroll
    for (int jb=0;jb<16;jb++){
      float4 vv2 = *(const float4*)(vmax2 + (size_t)fv*64 + jb*4);
      K += vv2.x*w3L[(7+jb*4)*64+lane] + vv2.y*w3L[(8+jb*4)*64+lane]
         + vv2.z*w3L[(9+jb*4)*64+lane] + vv2.w*w3L[(10+jb*4)*64+lane];
    }
    float vf = 0.f;
    for (int p = 0; p < c_; p++){
      const float4* fp = (const float4*)(feat + (size_t)fv*256 + p*8);
      float4 lo = fp[0], hi = fp[1];
      float in[7] = {lo.x,lo.y,lo.z,lo.w,hi.x,hi.y,hi.z};
      float a = 0.f;
      #pragma unroll
      for (int k=0;k<7;k++) a += in[k]*w3L[k*64+lane];
      vf = fmaxf(vf, (a+K)*sc3 + sh3);
    }
    int vid = vv[fv];
    int b   = fv / MAXV;
    int cx  = vid / (GNY*GNZ);
    int cy  = (vid / GNZ) % GNY;
    atomicMax((int*)(bev + (((size_t)b*NPIX + (size_t)cy*CONVW + cx)*64) + lane),
              __float_as_int(vf));
  }
}

// ---- weight prepack: [oc][ic][3][3] f32 -> [tap][oc][ic] bf16, 5 layers
extern "C" __global__ void k_wprep(const float* __restrict__ cs_w, const float* __restrict__ rpn_w,
                                   unsigned short* __restrict__ Bw){
  int i = blockIdx.x*256 + threadIdx.x;
  if (i >= 5*36864) return;
  int l = i/36864, r = i - l*36864;
  int tap = r >> 12, oc = (r >> 6) & 63, ic = r & 63;
  const float* src = (l < 2) ? (cs_w + (size_t)l*36864) : (rpn_w + (size_t)(l-2)*36864);
  Bw[i] = f2bf(src[((size_t)oc*64 + ic)*9 + tap]);
}

extern "C" __global__ void k_cvt(const float* __restrict__ x, unsigned short* __restrict__ o){
  int i = blockIdx.x*256 + threadIdx.x;
  if (i*4 >= NELEM) return;
  float4 v = ((const float4*)x)[i];
  ushort4 r;
  r.x = f2bf(v.x); r.y = f2bf(v.y); r.z = f2bf(v.z); r.w = f2bf(v.w);
  ((ushort4*)o)[i] = r;
}

// ---- conv3x3: implicit GEMM, bf16 MFMA. Tile 4y x 16x, 64 oc, 4 waves.
extern "C" __global__ void __launch_bounds__(256) k_conv(const unsigned short* __restrict__ in,
    const unsigned short* __restrict__ Bw, const float* __restrict__ bias,
    float* __restrict__ out, float* __restrict__ st){
  const int b  = blockIdx.z;
  const int x0 = blockIdx.x*16, y0 = blockIdx.y*4;
  const int tid = threadIdx.x;
  const int w = tid >> 6, l = tid & 63;
  const int l15 = l & 15, quad = l >> 4;
  const int bid = (blockIdx.z*gridDim.y + blockIdx.y)*gridDim.x + blockIdx.x;
  const int shad = bid & (SHAD-1);

  __shared__ unsigned short smemA[6*18*64];
  __shared__ float sA[64], sQ[64];
  if (tid < 64){ sA[tid] = 0.f; sQ[tid] = 0.f; }

  for (int i = tid; i < 864; i += 256){
    int pos = i >> 3, jb = i & 7;
    int yp = pos/18, xp = pos - yp*18;
    int gy = y0 + yp - 1, gx = x0 + xp - 1;
    uint4 v = make_uint4(0u,0u,0u,0u);
    if (gy >= 0 && gy < CONVH && gx >= 0 && gx < CONVW)
      v = *(const uint4*)(in + (((size_t)b*NPIX + (size_t)gy*CONVW + gx)*64 + jb*8));
    int jsw = jb ^ (xp & 7);
    *(uint4*)&smemA[pos*64 + jsw*8] = v;
  }
  __syncthreads();

  f32x4 acc[4] = {{0.f,0.f,0.f,0.f},{0.f,0.f,0.f,0.f},{0.f,0.f,0.f,0.f},{0.f,0.f,0.f,0.f}};
  for (int tap = 0; tap < 9; tap++){
    int dy = tap/3, dx = tap - dy*3;
    int yp = w + dy, xp = l15 + dx;
    int abase = (yp*18 + xp)*64;
    int xm = (xp & 7);
    #pragma unroll
    for (int par = 0; par < 2; par++){
      int jb = par*4 + quad;
      short8 a = *(const short8*)&smemA[abase + (jb ^ xm)*8];
      #pragma unroll
      for (int nt = 0; nt < 4; nt++){
        const unsigned short* bp = Bw + (((size_t)tap*64 + nt*16 + l15)*64 + par*32 + quad*8);
        short8 bb = *(const short8*)bp;
        acc[nt] = __builtin_amdgcn_mfma_f32_16x16x32_bf16(a, bb, acc[nt], 0, 0, 0);
      }
    }
  }

  const int y = y0 + w;
  #pragma unroll
  for (int nt = 0; nt < 4; nt++){
    int oc = nt*16 + l15;
    float bv = bias[oc];
    float s = 0.f, q = 0.f;
    #pragma unroll
    for (int r = 0; r < 4; r++){
      float v = acc[nt][r] + bv;
      int x = x0 + quad*4 + r;
      out[((size_t)b*NPIX + (size_t)y*CONVW + x)*64 + oc] = v;
      s += v; q += v*v;
    }
    atomicAdd(&sA[oc], s); atomicAdd(&sQ[oc], q);
  }
  __syncthreads();
  if (tid < 64){
    atomicAdd(&st[shad*128 + tid], sA[tid]);
    atomicAdd(&st[shad*128 + 64 + tid], sQ[tid]);
  }
}

// ---- BN+relu: f32 NHWC -> bf16 NHWC (sums 8 stat shadows)
extern "C" __global__ void k_bnrelu(const float* __restrict__ x, const float* __restrict__ st,
    const float* __restrict__ g, const float* __restrict__ be, unsigned short* __restrict__ o){
  int i = blockIdx.x*256 + threadIdx.x;
  if (i*4 >= NELEM) return;
  const float invN = 1.f/(float)(BATCH*NPIX);
  float4 v = ((const float4*)x)[i];
  int c0 = (i*4) & 63;
  float vv[4] = {v.x, v.y, v.z, v.w};
  unsigned short rr[4];
  #pragma unroll
  for (int k = 0; k < 4; k++){
    int c = c0 + k;
    float m = 0.f, q = 0.f;
    #pragma unroll
    for (int s=0;s<SHAD;s++){ m += st[s*128+c]; q += st[s*128+64+c]; }
    m *= invN;
    float va = q*invN - m*m;
    float sc = g[c]*rsqrtf(va + 1e-5f);
    rr[k] = f2bf(fmaxf((vv[k]-m)*sc + be[c], 0.f));
  }
  ushort4 r; r.x = rr[0]; r.y = rr[1]; r.z = rr[2]; r.w = rr[3];
  ((ushort4*)o)[i] = r;
}

extern "C" __global__ void k_head(const unsigned short* __restrict__ in,
    const float* __restrict__ hw, const float* __restrict__ hb, float* __restrict__ outp){
  int i = blockIdx.x*256 + threadIdx.x;
  if (i >= BATCH*NPIX) return;
  const uint4* p = (const uint4*)(in + (size_t)i*64);
  float a0 = hb[0], a1 = hb[1], a2 = hb[2];
  #pragma unroll
  for (int j = 0; j < 8; j++){
    uint4 u = p[j];
    unsigned int uu[4] = {u.x, u.y, u.z, u.w};
    #pragma unroll
    for (int e = 0; e < 4; e++){
      int ic = j*8 + e*2;
      float v0 = bf2f((unsigned short)(uu[e] & 0xffffu));
      float v1 = bf2f((unsigned short)(uu[e] >> 16));
      a0 += v0*hw[ic] + v1*hw[ic+1];
      a1 += v0*hw[64+ic] + v1*hw[64+ic+1];
      a2 += v0*hw[128+ic] + v1*hw[128+ic+1];
    }
  }
  size_t o = (size_t)i*3;
  outp[o+0] = a0; outp[o+1] = a1; outp[o+2] = a2;
}

extern "C" void kernel_launch(void* const* d_in, const int* in_sizes, int n_in,
                              void* d_out, int out_size, void* d_ws, size_t ws_size,
                              hipStream_t stream){
  (void)in_sizes; (void)n_in; (void)out_size;
  const float* pts   = (const float*)d_in[0];
  const float* w1    = (const float*)d_in[1];
  const float* g1    = (const float*)d_in[2];
  const float* b1    = (const float*)d_in[3];
  const float* w2    = (const float*)d_in[4];
  const float* g2    = (const float*)d_in[5];
  const float* b2    = (const float*)d_in[6];
  const float* w3    = (const float*)d_in[7];
  const float* g3    = (const float*)d_in[8];
  const float* b3    = (const float*)d_in[9];
  const float* cs_w  = (const float*)d_in[10];
  const float* cs_b  = (const float*)d_in[11];
  const float* cs_g  = (const float*)d_in[12];
  const float* cs_be = (const float*)d_in[13];
  const float* rpn_w = (const float*)d_in[14];
  const float* rpn_b = (const float*)d_in[15];
  const float* rpn_g = (const float*)d_in[16];
  const float* rpn_be= (const float*)d_in[17];
  const float* hw    = (const float*)d_in[18];
  const float* hb    = (const float*)d_in[19];

  char* ws = (char*)d_ws;
  size_t off = 0;
  auto alloc = [&](size_t bytes)->char*{
    char* p = ws + off; off += (bytes + 255) & ~(size_t)255; return p;
  };
  int*   cellcnt = (int*)  alloc((size_t)BATCH*NCELL*4);
  int*   slotmap = (int*)  alloc((size_t)BATCH*NCELL*4);
  int*   blks    = (int*)  alloc((size_t)BATCH*512*4);
  int*   vv      = (int*)  alloc((size_t)NVOX*4);
  int*   cnt     = (int*)  alloc((size_t)NVOX*4);
  int*   fill    = (int*)  alloc((size_t)NVOX*4);
  int*   plist   = (int*)  alloc((size_t)NVOX*PMAX*4);
  float* feat    = (float*)alloc((size_t)NPFN*8*4);       // reused by conv bufs
  float* vmax1   = (float*)alloc((size_t)NVOX*32*4);
  float* vmax2   = (float*)alloc((size_t)NVOX*64*4);
  float* stats   = (float*)alloc(32768);
  float* bevf    = (float*)alloc((size_t)NELEM*4);
  unsigned short* Bw = (unsigned short*)alloc((size_t)5*36864*2);
  if (off > ws_size) return;

  float* st1 = stats;            // [SHAD][64]
  float* st2 = stats + 512;      // [SHAD][128]
  float* st3 = stats + 1536;     // [SHAD][128]
  float* stc = stats + 2560;     // 5 x [SHAD][128]

  float*          convout = (float*)feat;
  unsigned short* bfA     = (unsigned short*)((char*)feat + 18022400);
  unsigned short* bfB     = (unsigned short*)((char*)feat + 27033600);

  hipMemsetAsync(cellcnt, 0, (size_t)BATCH*NCELL*4, stream);
  hipMemsetAsync(vv,   0, (size_t)NVOX*4, stream);
  hipMemsetAsync(cnt,  0, (size_t)NVOX*4, stream);
  hipMemsetAsync(fill, 0, (size_t)NVOX*4, stream);
  hipMemsetAsync(stats,0, 32768, stream);
  hipMemsetAsync(bevf, 0, (size_t)NELEM*4, stream);

  k_count <<<(BATCH*NPTS+255)/256, 256, 0, stream>>>(pts, cellcnt);
  k_blkcount<<<dim3(SCAN_NB,BATCH), 256, 0, stream>>>(cellcnt, blks);
  k_scan  <<<BATCH, 64, 0, stream>>>(blks);
  k_assign<<<dim3(SCAN_NB,BATCH), 256, 0, stream>>>(cellcnt, blks, slotmap, vv, cnt);
  k_fill  <<<(BATCH*NPTS+255)/256, 256, 0, stream>>>(pts, slotmap, fill, plist);
  k_feat  <<<NVOX/2, 64, 0, stream>>>(pts, cnt, plist, feat);

  k_p1<<<PGRID, 256, 0, stream>>>(feat, cnt, w1, st1);
  k_p2<<<PGRID, 256, 0, stream>>>(feat, cnt, w1, g1, b1, w2, st1, st2, vmax1);
  k_p3<<<PGRID, 256, 0, stream>>>(feat, cnt, w2, g2, b2, w3, vmax1, st2, st3, vmax2);
  k_p4<<<PGRID, 256, 0, stream>>>(feat, cnt, vv, w3, g3, b3, vmax2, st3, bevf);

  k_wprep<<<(5*36864+255)/256, 256, 0, stream>>>(cs_w, rpn_w, Bw);
  k_cvt  <<<(NELEM/4+255)/256, 256, 0, stream>>>(bevf, bfA);

  const float* bptr[5]  = {cs_b, cs_b+64,   rpn_b, rpn_b+64,   rpn_b+128};
  const float* gptr[5]  = {cs_g, cs_g+64,   rpn_g, rpn_g+64,   rpn_g+128};
  const float* beptr[5] = {cs_be,cs_be+64,  rpn_be,rpn_be+64,  rpn_be+128};
  unsigned short* bufs[2] = {bfA, bfB};
  dim3 cgrid(CONVW/16, CONVH/4, BATCH);
  for (int ll = 0; ll < 5; ll++){
    unsigned short* src = bufs[ll & 1];
    unsigned short* dst = bufs[(ll & 1) ^ 1];
    float* stl = stc + ll*1024;
    k_conv  <<<cgrid, 256, 0, stream>>>(src, Bw + (size_t)ll*36864, bptr[ll], convout, stl);
    k_bnrelu<<<(NELEM/4+255)/256, 256, 0, stream>>>(convout, stl, gptr[ll], beptr[ll], dst);
  }
  k_head<<<(BATCH*NPIX+255)/256, 256, 0, stream>>>(bufs[1], hw, hb, (float*)d_out);
}

// Round 5
// 461.890 us; speedup vs baseline: 14.5325x; 1.1406x over previous
//
#include <hip/hip_runtime.h>

// Round 5: (1) PFN grid 512->2048 + 32 stat shadows (occupancy 18%->~50%),
// (2) BN+relu+bf16cvt fused into conv staging / head (f32 ping-pong, no bf16
// intermediates, -6 dispatches), (3) parallel k_scan, k_feat 8 voxels/block.

#define BATCH 2
#define NPTS 100000
#define GNX 176
#define GNY 200
#define GNZ 10
#define NCELL (GNX*GNY*GNZ)
#define PMAX 32
#define MAXV 20000
#define NVOX (BATCH*MAXV)
#define NPFN (NVOX*PMAX)
#define CONVH 200
#define CONVW 176
#define NPIX (CONVH*CONVW)
#define NELEM (BATCH*NPIX*64)
#define SCAN_NB ((NCELL + 1023)/1024)
#define PGRID 2048
#define SHAD 32

typedef __attribute__((ext_vector_type(8))) short short8;
typedef __attribute__((ext_vector_type(4))) float f32x4;

__device__ __forceinline__ unsigned short f2bf(float f){
  unsigned int u = __float_as_uint(f);
  u = (u + 0x7fffu + ((u >> 16) & 1u)) >> 16;
  return (unsigned short)u;
}

__device__ __forceinline__ int voxel_id(float x, float y, float z){
  int ix = (int)floorf(x / 0.4f);
  int iy = (int)floorf((y + 40.0f) / 0.4f);
  int iz = (int)floorf((z + 3.0f) / 0.4f);
  if (ix < 0 || iy < 0 || iz < 0 || ix >= GNX || iy >= GNY || iz >= GNZ) return -1;
  return (ix*GNY + iy)*GNZ + iz;
}

extern "C" __global__ void k_count(const float* __restrict__ pts, int* __restrict__ cellcnt){
  int i = blockIdx.x*256 + threadIdx.x;
  if (i >= BATCH*NPTS) return;
  const float* q = pts + (size_t)i*4;
  int vid = voxel_id(q[0], q[1], q[2]);
  if (vid < 0) return;
  int b = i / NPTS;
  atomicAdd(&cellcnt[b*NCELL + vid], 1);
}

extern "C" __global__ void __launch_bounds__(256) k_blkcount(const int* __restrict__ cellcnt,
                                                             int* __restrict__ blks){
  int b = blockIdx.y, blk = blockIdx.x, t = threadIdx.x;
  int base = blk*1024 + t*4;
  int s = 0;
  #pragma unroll
  for (int i=0;i<4;i++){ int c = base+i; if (c < NCELL) s += (cellcnt[b*NCELL+c] > 0); }
  #pragma unroll
  for (int m=32;m>=1;m>>=1) s += __shfl_xor(s, m);
  __shared__ int red[4];
  if ((t&63)==0) red[t>>6] = s;
  __syncthreads();
  if (t==0) blks[b*512+blk] = red[0]+red[1]+red[2]+red[3];
}

extern "C" __global__ void __launch_bounds__(512) k_scan(int* __restrict__ blks){
  int b = blockIdx.x, t = threadIdx.x;
  __shared__ int l[512];
  int orig = (t < SCAN_NB) ? blks[b*512+t] : 0;
  l[t] = orig;
  __syncthreads();
  for (int o=1;o<512;o<<=1){
    int v = (t>=o) ? l[t-o] : 0;
    __syncthreads();
    l[t] += v;
    __syncthreads();
  }
  if (t < SCAN_NB) blks[b*512+t] = l[t] - orig;   // exclusive
}

extern "C" __global__ void __launch_bounds__(256) k_assign(const int* __restrict__ cellcnt,
    const int* __restrict__ blks, int* __restrict__ slotmap, int* __restrict__ vv,
    int* __restrict__ cnt){
  int b = blockIdx.y, blk = blockIdx.x, t = threadIdx.x;
  int base = blk*1024 + t*4;
  int flag[4]; int s = 0;
  #pragma unroll
  for (int i=0;i<4;i++){
    int c = base+i;
    flag[i] = (c < NCELL) ? (cellcnt[b*NCELL+c] > 0) : 0;
    s += flag[i];
  }
  __shared__ int lds[256];
  lds[t] = s; __syncthreads();
  for (int o=1;o<256;o<<=1){
    int v = (t>=o) ? lds[t-o] : 0;
    __syncthreads();
    lds[t] += v;
    __syncthreads();
  }
  int run = blks[b*512+blk] + (lds[t]-s);
  #pragma unroll
  for (int i=0;i<4;i++){
    int c = base+i;
    if (c >= NCELL) break;
    int sm = -1;
    if (flag[i]){
      if (run < MAXV){
        sm = run;
        vv[b*MAXV+run]  = c;
        cnt[b*MAXV+run] = min(cellcnt[b*NCELL+c], PMAX);
      }
      run++;
    }
    slotmap[b*NCELL+c] = sm;
  }
}

extern "C" __global__ void k_fill(const float* __restrict__ pts, const int* __restrict__ slotmap,
                                  int* __restrict__ fill, int* __restrict__ plist){
  int i = blockIdx.x*256 + threadIdx.x;
  if (i >= BATCH*NPTS) return;
  const float* q = pts + (size_t)i*4;
  int vid = voxel_id(q[0], q[1], q[2]);
  if (vid < 0) return;
  int b = i / NPTS;
  int slot = slotmap[b*NCELL+vid];
  if (slot < 0) return;
  int pos = atomicAdd(&fill[b*MAXV+slot], 1);
  if (pos < PMAX) plist[((size_t)b*MAXV+slot)*PMAX + pos] = i - b*NPTS;
}

extern "C" __global__ void __launch_bounds__(256) k_feat(const float* __restrict__ pts,
    const int* __restrict__ cnt, const int* __restrict__ plist, float* __restrict__ feat){
  int g  = threadIdx.x >> 5;
  int fv = blockIdx.x*8 + g;
  int p  = threadIdx.x & 31;
  int b  = fv / MAXV;
  __shared__ int lst[8][32];
  int c = cnt[fv];
  if (p < c) lst[g][p] = plist[(size_t)fv*PMAX + p];
  __syncthreads();
  if (p == 0){
    for (int i=1;i<c;i++){
      int key = lst[g][i]; int j = i-1;
      while (j >= 0 && lst[g][j] > key){ lst[g][j+1] = lst[g][j]; j--; }
      lst[g][j+1] = key;
    }
  }
  __syncthreads();
  float4 pt = make_float4(0.f,0.f,0.f,0.f);
  if (p < c){
    int id = lst[g][p];
    pt = *(const float4*)(pts + ((size_t)b*NPTS + id)*4);
  }
  float sx = pt.x, sy = pt.y, sz = pt.z;
  #pragma unroll
  for (int m=16;m>=1;m>>=1){
    sx += __shfl_xor(sx, m, 32); sy += __shfl_xor(sy, m, 32); sz += __shfl_xor(sz, m, 32);
  }
  float cd = (float)max(c, 1);
  if (p < c){
    float* fo = feat + (size_t)fv*(PMAX*8) + p*8;
    *(float4*)fo     = pt;
    *(float4*)(fo+4) = make_float4(pt.x-sx/cd, pt.y-sy/cd, pt.z-sz/cd, 0.f);
  }
}

// ============ PFN: persistent blocks, lane=channel, shadowed stats ============
extern "C" __global__ void __launch_bounds__(256) k_p1(const float* __restrict__ feat,
    const int* __restrict__ cnt, const float* __restrict__ w1, float* __restrict__ st){
  __shared__ float w1L[224];
  __shared__ float sred[64];
  int tid = threadIdx.x;
  if (tid < 224) w1L[tid] = w1[tid];
  if (tid < 64) sred[tid] = 0.f;
  __syncthreads();
  int w = tid>>6, lane = tid&63, c = lane&31, half = lane>>5;
  float S = 0.f, Q = 0.f;
  for (int fv = blockIdx.x*4 + w; fv < NVOX; fv += PGRID*4){
    int c_ = cnt[fv];
    for (int p = half; p < c_; p += 2){
      const float4* fp = (const float4*)(feat + (size_t)fv*256 + p*8);
      float4 lo = fp[0], hi = fp[1];
      float in[7] = {lo.x,lo.y,lo.z,lo.w,hi.x,hi.y,hi.z};
      float v = 0.f;
      #pragma unroll
      for (int k=0;k<7;k++) v += in[k]*w1L[k*32+c];
      S += v; Q += v*v;
    }
  }
  S += __shfl_xor(S, 32); Q += __shfl_xor(Q, 32);
  if (half == 0){ atomicAdd(&sred[c], S); atomicAdd(&sred[32+c], Q); }
  __syncthreads();
  if (tid < 64) atomicAdd(&st[(blockIdx.x&(SHAD-1))*64 + tid], sred[tid]);
}

extern "C" __global__ void __launch_bounds__(256) k_p2(const float* __restrict__ feat,
    const int* __restrict__ cnt, const float* __restrict__ w1, const float* __restrict__ g1,
    const float* __restrict__ b1, const float* __restrict__ w2, const float* __restrict__ st1,
    float* __restrict__ st2, float* __restrict__ vmax1){
  __shared__ float w1L[224];
  __shared__ float w2L[2496];
  __shared__ float sred[128];
  int tid = threadIdx.x;
  if (tid < 224) w1L[tid] = w1[tid];
  for (int i=tid;i<2496;i+=256) w2L[i] = w2[i];
  if (tid < 128) sred[tid] = 0.f;
  __syncthreads();
  int w = tid>>6, lane = tid&63, c1 = lane&31, half = lane>>5;
  const float invN = 1.f/(float)NPFN;
  float m1=0.f, v1s=0.f;
  #pragma unroll
  for (int s=0;s<SHAD;s++){ m1 += st1[s*64+c1]; v1s += st1[s*64+32+c1]; }
  m1 *= invN; v1s = v1s*invN - m1*m1;
  float sc1 = g1[c1]*rsqrtf(v1s + 1e-3f);
  float sh1 = b1[c1] - m1*sc1;
  float S = 0.f, Q = 0.f;
  for (int fv = blockIdx.x*4 + w; fv < NVOX; fv += PGRID*4){
    int c_ = cnt[fv];
    float vm = 0.f;
    for (int p = half; p < c_; p += 2){
      const float4* fp = (const float4*)(feat + (size_t)fv*256 + p*8);
      float4 lo = fp[0], hi = fp[1];
      float in[7] = {lo.x,lo.y,lo.z,lo.w,hi.x,hi.y,hi.z};
      float v = 0.f;
      #pragma unroll
      for (int k=0;k<7;k++) v += in[k]*w1L[k*32+c1];
      vm = fmaxf(vm, v*sc1 + sh1);
    }
    vm = fmaxf(vm, __shfl_xor(vm, 32));
    if (half == 0) vmax1[(size_t)fv*32 + c1] = vm;
    float K = 0.f;
    #pragma unroll
    for (int j=0;j<32;j++) K += __shfl(vm, j)*w2L[(7+j)*64+lane];
    float s = (float)(PMAX-c_)*K, q = (float)(PMAX-c_)*K*K;
    for (int p = 0; p < c_; p++){
      const float4* fp = (const float4*)(feat + (size_t)fv*256 + p*8);
      float4 lo = fp[0], hi = fp[1];
      float in[7] = {lo.x,lo.y,lo.z,lo.w,hi.x,hi.y,hi.z};
      float a = 0.f;
      #pragma unroll
      for (int k=0;k<7;k++) a += in[k]*w2L[k*64+lane];
      float x = a + K; s += x; q += x*x;
    }
    S += s; Q += q;
  }
  atomicAdd(&sred[lane], S); atomicAdd(&sred[64+lane], Q);
  __syncthreads();
  if (tid < 128) atomicAdd(&st2[(blockIdx.x&(SHAD-1))*128 + tid], sred[tid]);
}

extern "C" __global__ void __launch_bounds__(256) k_p3(const float* __restrict__ feat,
    const int* __restrict__ cnt, const float* __restrict__ w2, const float* __restrict__ g2,
    const float* __restrict__ b2, const float* __restrict__ w3, const float* __restrict__ vmax1,
    const float* __restrict__ st2, float* __restrict__ st3, float* __restrict__ vmax2){
  __shared__ float w2L[2496];
  __shared__ float w3L[4544];
  __shared__ float sred[128];
  int tid = threadIdx.x;
  for (int i=tid;i<2496;i+=256) w2L[i] = w2[i];
  for (int i=tid;i<4544;i+=256) w3L[i] = w3[i];
  if (tid < 128) sred[tid] = 0.f;
  __syncthreads();
  int w = tid>>6, lane = tid&63;
  const float invN = 1.f/(float)NPFN;
  float m2=0.f, v2s=0.f;
  #pragma unroll
  for (int s=0;s<SHAD;s++){ m2 += st2[s*128+lane]; v2s += st2[s*128+64+lane]; }
  m2 *= invN; v2s = v2s*invN - m2*m2;
  float sc2 = g2[lane]*rsqrtf(v2s + 1e-3f);
  float sh2 = b2[lane] - m2*sc2;
  float S = 0.f, Q = 0.f;
  for (int fv = blockIdx.x*4 + w; fv < NVOX; fv += PGRID*4){
    int c_ = cnt[fv];
    float K2 = 0.f;
    #pragma unroll
    for (int jb=0;jb<8;jb++){
      float4 vv = *(const float4*)(vmax1 + (size_t)fv*32 + jb*4);
      K2 += vv.x*w2L[(7+jb*4)*64+lane] + vv.y*w2L[(8+jb*4)*64+lane]
          + vv.z*w2L[(9+jb*4)*64+lane] + vv.w*w2L[(10+jb*4)*64+lane];
    }
    float vm = 0.f;
    for (int p = 0; p < c_; p++){
      const float4* fp = (const float4*)(feat + (size_t)fv*256 + p*8);
      float4 lo = fp[0], hi = fp[1];
      float in[7] = {lo.x,lo.y,lo.z,lo.w,hi.x,hi.y,hi.z};
      float a = 0.f;
      #pragma unroll
      for (int k=0;k<7;k++) a += in[k]*w2L[k*64+lane];
      vm = fmaxf(vm, (a+K2)*sc2 + sh2);
    }
    vmax2[(size_t)fv*64 + lane] = vm;
    float K3 = 0.f;
    #pragma unroll
    for (int j=0;j<64;j++) K3 += __shfl(vm, j)*w3L[(7+j)*64+lane];
    float s = (float)(PMAX-c_)*K3, q = (float)(PMAX-c_)*K3*K3;
    for (int p = 0; p < c_; p++){
      const float4* fp = (const float4*)(feat + (size_t)fv*256 + p*8);
      float4 lo = fp[0], hi = fp[1];
      float in[7] = {lo.x,lo.y,lo.z,lo.w,hi.x,hi.y,hi.z};
      float a = 0.f;
      #pragma unroll
      for (int k=0;k<7;k++) a += in[k]*w3L[k*64+lane];
      float x = a + K3; s += x; q += x*x;
    }
    S += s; Q += q;
  }
  atomicAdd(&sred[lane], S); atomicAdd(&sred[64+lane], Q);
  __syncthreads();
  if (tid < 128) atomicAdd(&st3[(blockIdx.x&(SHAD-1))*128 + tid], sred[tid]);
}

extern "C" __global__ void __launch_bounds__(256) k_p4(const float* __restrict__ feat,
    const int* __restrict__ cnt, const int* __restrict__ vv, const float* __restrict__ w3,
    const float* __restrict__ g3, const float* __restrict__ b3, const float* __restrict__ vmax2,
    const float* __restrict__ st3, float* __restrict__ bev){
  __shared__ float w3L[4544];
  int tid = threadIdx.x;
  for (int i=tid;i<4544;i+=256) w3L[i] = w3[i];
  __syncthreads();
  int w = tid>>6, lane = tid&63;
  const float invN = 1.f/(float)NPFN;
  float m3=0.f, v3s=0.f;
  #pragma unroll
  for (int s=0;s<SHAD;s++){ m3 += st3[s*128+lane]; v3s += st3[s*128+64+lane]; }
  m3 *= invN; v3s = v3s*invN - m3*m3;
  float sc3 = g3[lane]*rsqrtf(v3s + 1e-3f);
  float sh3 = b3[lane] - m3*sc3;
  for (int fv = blockIdx.x*4 + w; fv < NVOX; fv += PGRID*4){
    int c_ = cnt[fv];
    if (c_ == 0) continue;
    float K = 0.f;
    #pragma unroll
    for (int jb=0;jb<16;jb++){
      float4 vv2 = *(const float4*)(vmax2 + (size_t)fv*64 + jb*4);
      K += vv2.x*w3L[(7+jb*4)*64+lane] + vv2.y*w3L[(8+jb*4)*64+lane]
         + vv2.z*w3L[(9+jb*4)*64+lane] + vv2.w*w3L[(10+jb*4)*64+lane];
    }
    float vf = 0.f;
    for (int p = 0; p < c_; p++){
      const float4* fp = (const float4*)(feat + (size_t)fv*256 + p*8);
      float4 lo = fp[0], hi = fp[1];
      float in[7] = {lo.x,lo.y,lo.z,lo.w,hi.x,hi.y,hi.z};
      float a = 0.f;
      #pragma unroll
      for (int k=0;k<7;k++) a += in[k]*w3L[k*64+lane];
      vf = fmaxf(vf, (a+K)*sc3 + sh3);
    }
    int vid = vv[fv];
    int b   = fv / MAXV;
    int cx  = vid / (GNY*GNZ);
    int cy  = (vid / GNZ) % GNY;
    atomicMax((int*)(bev + (((size_t)b*NPIX + (size_t)cy*CONVW + cx)*64) + lane),
              __float_as_int(vf));
  }
}

// ---- weight prepack: [oc][ic][3][3] f32 -> [tap][oc][ic] bf16, 5 layers
extern "C" __global__ void k_wprep(const float* __restrict__ cs_w, const float* __restrict__ rpn_w,
                                   unsigned short* __restrict__ Bw){
  int i = blockIdx.x*256 + threadIdx.x;
  if (i >= 5*36864) return;
  int l = i/36864, r = i - l*36864;
  int tap = r >> 12, oc = (r >> 6) & 63, ic = r & 63;
  const float* src = (l < 2) ? (cs_w + (size_t)l*36864) : (rpn_w + (size_t)(l-2)*36864);
  Bw[i] = f2bf(src[((size_t)oc*64 + ic)*9 + tap]);
}

// ---- conv3x3: implicit GEMM, bf16 MFMA. f32 NHWC in + fused BN/relu/cvt
//      during staging (stin==null -> identity), f32 NHWC out + shadowed stats.
extern "C" __global__ void __launch_bounds__(256) k_conv(const float* __restrict__ in,
    const float* __restrict__ stin, const float* __restrict__ g, const float* __restrict__ be,
    const unsigned short* __restrict__ Bw, const float* __restrict__ bias,
    float* __restrict__ out, float* __restrict__ st){
  const int b  = blockIdx.z;
  const int x0 = blockIdx.x*16, y0 = blockIdx.y*4;
  const int tid = threadIdx.x;
  const int w = tid >> 6, l = tid & 63;
  const int l15 = l & 15, quad = l >> 4;
  const int bid = (blockIdx.z*gridDim.y + blockIdx.y)*gridDim.x + blockIdx.x;
  const int shad = bid & (SHAD-1);

  __shared__ unsigned short smemA[6*18*64];
  __shared__ float bnsc[64], bnsh[64];
  __shared__ float sA[64], sQ[64];
  if (tid < 64){
    sA[tid] = 0.f; sQ[tid] = 0.f;
    float sc = 1.f, sh = 0.f;
    if (stin){
      const float invN = 1.f/(float)(BATCH*NPIX);
      float m = 0.f, q = 0.f;
      #pragma unroll
      for (int s=0;s<SHAD;s++){ m += stin[s*128+tid]; q += stin[s*128+64+tid]; }
      m *= invN;
      float va = q*invN - m*m;
      sc = g[tid]*rsqrtf(va + 1e-5f);
      sh = be[tid] - m*sc;
    }
    bnsc[tid] = sc; bnsh[tid] = sh;
  }
  __syncthreads();

  for (int i = tid; i < 864; i += 256){
    int pos = i >> 3, jb = i & 7;
    int yp = pos/18, xp = pos - yp*18;
    int gy = y0 + yp - 1, gx = x0 + xp - 1;
    unsigned short h[8] = {0,0,0,0,0,0,0,0};
    if (gy >= 0 && gy < CONVH && gx >= 0 && gx < CONVW){
      const float* src = in + (((size_t)b*NPIX + (size_t)gy*CONVW + gx)*64 + jb*8);
      float4 v0 = *(const float4*)src;
      float4 v1 = *(const float4*)(src+4);
      float vv[8] = {v0.x,v0.y,v0.z,v0.w,v1.x,v1.y,v1.z,v1.w};
      #pragma unroll
      for (int k=0;k<8;k++){
        int c = jb*8 + k;
        h[k] = f2bf(fmaxf(vv[k]*bnsc[c] + bnsh[c], 0.f));
      }
    }
    int jsw = jb ^ (xp & 7);
    *(uint4*)&smemA[pos*64 + jsw*8] = *(uint4*)h;
  }
  __syncthreads();

  f32x4 acc[4] = {{0.f,0.f,0.f,0.f},{0.f,0.f,0.f,0.f},{0.f,0.f,0.f,0.f},{0.f,0.f,0.f,0.f}};
  for (int tap = 0; tap < 9; tap++){
    int dy = tap/3, dx = tap - dy*3;
    int yp = w + dy, xp = l15 + dx;
    int abase = (yp*18 + xp)*64;
    int xm = (xp & 7);
    #pragma unroll
    for (int par = 0; par < 2; par++){
      int jb = par*4 + quad;
      short8 a = *(const short8*)&smemA[abase + (jb ^ xm)*8];
      #pragma unroll
      for (int nt = 0; nt < 4; nt++){
        const unsigned short* bp = Bw + (((size_t)tap*64 + nt*16 + l15)*64 + par*32 + quad*8);
        short8 bb = *(const short8*)bp;
        acc[nt] = __builtin_amdgcn_mfma_f32_16x16x32_bf16(a, bb, acc[nt], 0, 0, 0);
      }
    }
  }

  const int y = y0 + w;
  #pragma unroll
  for (int nt = 0; nt < 4; nt++){
    int oc = nt*16 + l15;
    float bv = bias[oc];
    float s = 0.f, q = 0.f;
    #pragma unroll
    for (int r = 0; r < 4; r++){
      float v = acc[nt][r] + bv;
      int x = x0 + quad*4 + r;
      out[((size_t)b*NPIX + (size_t)y*CONVW + x)*64 + oc] = v;
      s += v; q += v*v;
    }
    atomicAdd(&sA[oc], s); atomicAdd(&sQ[oc], q);
  }
  __syncthreads();
  if (tid < 64){
    atomicAdd(&st[shad*128 + tid], sA[tid]);
    atomicAdd(&st[shad*128 + 64 + tid], sQ[tid]);
  }
}

// ---- head 1x1: f32 NHWC in + fused BN/relu of last conv layer
extern "C" __global__ void __launch_bounds__(256) k_head(const float* __restrict__ in,
    const float* __restrict__ stin, const float* __restrict__ g, const float* __restrict__ be,
    const float* __restrict__ hw, const float* __restrict__ hb, float* __restrict__ outp){
  __shared__ float bnsc[64], bnsh[64];
  int tid = threadIdx.x;
  if (tid < 64){
    const float invN = 1.f/(float)(BATCH*NPIX);
    float m = 0.f, q = 0.f;
    #pragma unroll
    for (int s=0;s<SHAD;s++){ m += stin[s*128+tid]; q += stin[s*128+64+tid]; }
    m *= invN;
    float va = q*invN - m*m;
    float sc = g[tid]*rsqrtf(va + 1e-5f);
    bnsc[tid] = sc; bnsh[tid] = be[tid] - m*sc;
  }
  __syncthreads();
  int i = blockIdx.x*256 + tid;
  if (i >= BATCH*NPIX) return;
  const float* base = in + (size_t)i*64;
  float a0 = hb[0], a1 = hb[1], a2 = hb[2];
  #pragma unroll
  for (int jb = 0; jb < 16; jb++){
    float4 v = *(const float4*)(base + jb*4);
    float vv[4] = {v.x, v.y, v.z, v.w};
    #pragma unroll
    for (int e = 0; e < 4; e++){
      int ic = jb*4 + e;
      float h = fmaxf(vv[e]*bnsc[ic] + bnsh[ic], 0.f);
      a0 += h*hw[ic]; a1 += h*hw[64+ic]; a2 += h*hw[128+ic];
    }
  }
  size_t o = (size_t)i*3;
  outp[o+0] = a0; outp[o+1] = a1; outp[o+2] = a2;
}

extern "C" void kernel_launch(void* const* d_in, const int* in_sizes, int n_in,
                              void* d_out, int out_size, void* d_ws, size_t ws_size,
                              hipStream_t stream){
  (void)in_sizes; (void)n_in; (void)out_size;
  const float* pts   = (const float*)d_in[0];
  const float* w1    = (const float*)d_in[1];
  const float* g1    = (const float*)d_in[2];
  const float* b1    = (const float*)d_in[3];
  const float* w2    = (const float*)d_in[4];
  const float* g2    = (const float*)d_in[5];
  const float* b2    = (const float*)d_in[6];
  const float* w3    = (const float*)d_in[7];
  const float* g3    = (const float*)d_in[8];
  const float* b3    = (const float*)d_in[9];
  const float* cs_w  = (const float*)d_in[10];
  const float* cs_b  = (const float*)d_in[11];
  const float* cs_g  = (const float*)d_in[12];
  const float* cs_be = (const float*)d_in[13];
  const float* rpn_w = (const float*)d_in[14];
  const float* rpn_b = (const float*)d_in[15];
  const float* rpn_g = (const float*)d_in[16];
  const float* rpn_be= (const float*)d_in[17];
  const float* hw    = (const float*)d_in[18];
  const float* hb    = (const float*)d_in[19];

  char* ws = (char*)d_ws;
  size_t off = 0;
  auto alloc = [&](size_t bytes)->char*{
    char* p = ws + off; off += (bytes + 255) & ~(size_t)255; return p;
  };
  int*   cellcnt = (int*)  alloc((size_t)BATCH*NCELL*4);
  int*   slotmap = (int*)  alloc((size_t)BATCH*NCELL*4);
  int*   blks    = (int*)  alloc((size_t)BATCH*512*4);
  int*   vv      = (int*)  alloc((size_t)NVOX*4);
  int*   cnt     = (int*)  alloc((size_t)NVOX*4);
  int*   fill    = (int*)  alloc((size_t)NVOX*4);
  int*   plist   = (int*)  alloc((size_t)NVOX*PMAX*4);
  float* feat    = (float*)alloc((size_t)NPFN*8*4);       // 40.96MB, conv ping-pong later
  float* vmax1   = (float*)alloc((size_t)NVOX*32*4);
  float* vmax2   = (float*)alloc((size_t)NVOX*64*4);
  float* stats   = (float*)alloc(131072);
  float* bevf    = (float*)alloc((size_t)NELEM*4);
  unsigned short* Bw = (unsigned short*)alloc((size_t)5*36864*2);
  if (off > ws_size) return;

  float* st1 = stats;            // [32][64]
  float* st2 = stats + 2048;     // [32][128]
  float* st3 = stats + 6144;     // [32][128]
  float* stc = stats + 10240;    // 5 x [32][128]

  float* convA = (float*)feat;                          // 18,022,400 B
  float* convB = (float*)((char*)feat + 18022400);      // 18,022,400 B

  hipMemsetAsync(cellcnt, 0, (size_t)BATCH*NCELL*4, stream);
  hipMemsetAsync(vv,   0, (size_t)NVOX*4, stream);
  hipMemsetAsync(cnt,  0, (size_t)NVOX*4, stream);
  hipMemsetAsync(fill, 0, (size_t)NVOX*4, stream);
  hipMemsetAsync(stats,0, 131072, stream);
  hipMemsetAsync(bevf, 0, (size_t)NELEM*4, stream);

  k_count <<<(BATCH*NPTS+255)/256, 256, 0, stream>>>(pts, cellcnt);
  k_blkcount<<<dim3(SCAN_NB,BATCH), 256, 0, stream>>>(cellcnt, blks);
  k_scan  <<<BATCH, 512, 0, stream>>>(blks);
  k_assign<<<dim3(SCAN_NB,BATCH), 256, 0, stream>>>(cellcnt, blks, slotmap, vv, cnt);
  k_fill  <<<(BATCH*NPTS+255)/256, 256, 0, stream>>>(pts, slotmap, fill, plist);
  k_feat  <<<NVOX/8, 256, 0, stream>>>(pts, cnt, plist, feat);

  k_p1<<<PGRID, 256, 0, stream>>>(feat, cnt, w1, st1);
  k_p2<<<PGRID, 256, 0, stream>>>(feat, cnt, w1, g1, b1, w2, st1, st2, vmax1);
  k_p3<<<PGRID, 256, 0, stream>>>(feat, cnt, w2, g2, b2, w3, vmax1, st2, st3, vmax2);
  k_wprep<<<(5*36864+255)/256, 256, 0, stream>>>(cs_w, rpn_w, Bw);
  k_p4<<<PGRID, 256, 0, stream>>>(feat, cnt, vv, w3, g3, b3, vmax2, st3, bevf);

  const float* bptr[5]  = {cs_b, cs_b+64,   rpn_b, rpn_b+64,   rpn_b+128};
  const float* gptr[5]  = {cs_g, cs_g+64,   rpn_g, rpn_g+64,   rpn_g+128};
  const float* beptr[5] = {cs_be,cs_be+64,  rpn_be,rpn_be+64,  rpn_be+128};
  const float* srcs[5]  = {bevf, convA, convB, convA, convB};
  float*       dsts[5]  = {convA, convB, convA, convB, convA};
  dim3 cgrid(CONVW/16, CONVH/4, BATCH);
  for (int ll = 0; ll < 5; ll++){
    const float* stin = (ll == 0) ? (const float*)nullptr : (stc + (ll-1)*4096);
    const float* gg   = (ll == 0) ? g1 : gptr[ll-1];   // unused when stin==null
    const float* bb   = (ll == 0) ? b1 : beptr[ll-1];
    k_conv<<<cgrid, 256, 0, stream>>>(srcs[ll], stin, gg, bb,
                                      Bw + (size_t)ll*36864, bptr[ll], dsts[ll],
                                      stc + ll*4096);
  }
  k_head<<<(BATCH*NPIX+255)/256, 256, 0, stream>>>(convA, stc + 4*4096, gptr[4], beptr[4],
                                                   hw, hb, (float*)d_out);
}

// Round 7
// 427.199 us; speedup vs baseline: 15.7127x; 1.0812x over previous
//
#include <hip/hip_runtime.h>

// Round 7: identical to round-6 design; fixes the trailing-backslash comment
// that swallowed the pvox declaration (compile failure). PFN dataflow:
// pvox+mean (no feat buffer), K2/K3/amax/amin passed forward, p4 loop-free.

#define BATCH 2
#define NPTS 100000
#define GNX 176
#define GNY 200
#define GNZ 10
#define NCELL (GNX*GNY*GNZ)
#define PMAX 32
#define MAXV 20000
#define NVOX (BATCH*MAXV)
#define NPFN (NVOX*PMAX)
#define CONVH 200
#define CONVW 176
#define NPIX (CONVH*CONVW)
#define NELEM (BATCH*NPIX*64)
#define SCAN_NB ((NCELL + 1023)/1024)
#define PGRID 1024
#define SHAD 32

typedef __attribute__((ext_vector_type(8))) short short8;
typedef __attribute__((ext_vector_type(4))) float f32x4;

__device__ __forceinline__ unsigned short f2bf(float f){
  unsigned int u = __float_as_uint(f);
  u = (u + 0x7fffu + ((u >> 16) & 1u)) >> 16;
  return (unsigned short)u;
}

__device__ __forceinline__ int voxel_id(float x, float y, float z){
  int ix = (int)floorf(x / 0.4f);
  int iy = (int)floorf((y + 40.0f) / 0.4f);
  int iz = (int)floorf((z + 3.0f) / 0.4f);
  if (ix < 0 || iy < 0 || iz < 0 || ix >= GNX || iy >= GNY || iz >= GNZ) return -1;
  return (ix*GNY + iy)*GNZ + iz;
}

extern "C" __global__ void k_count(const float* __restrict__ pts, int* __restrict__ cellcnt){
  int i = blockIdx.x*256 + threadIdx.x;
  if (i >= BATCH*NPTS) return;
  const float* q = pts + (size_t)i*4;
  int vid = voxel_id(q[0], q[1], q[2]);
  if (vid < 0) return;
  int b = i / NPTS;
  atomicAdd(&cellcnt[b*NCELL + vid], 1);
}

extern "C" __global__ void __launch_bounds__(256) k_blkcount(const int* __restrict__ cellcnt,
                                                             int* __restrict__ blks){
  int b = blockIdx.y, blk = blockIdx.x, t = threadIdx.x;
  int base = blk*1024 + t*4;
  int s = 0;
  #pragma unroll
  for (int i=0;i<4;i++){ int c = base+i; if (c < NCELL) s += (cellcnt[b*NCELL+c] > 0); }
  #pragma unroll
  for (int m=32;m>=1;m>>=1) s += __shfl_xor(s, m);
  __shared__ int red[4];
  if ((t&63)==0) red[t>>6] = s;
  __syncthreads();
  if (t==0) blks[b*512+blk] = red[0]+red[1]+red[2]+red[3];
}

extern "C" __global__ void __launch_bounds__(512) k_scan(int* __restrict__ blks){
  int b = blockIdx.x, t = threadIdx.x;
  __shared__ int l[512];
  int orig = (t < SCAN_NB) ? blks[b*512+t] : 0;
  l[t] = orig;
  __syncthreads();
  for (int o=1;o<512;o<<=1){
    int v = (t>=o) ? l[t-o] : 0;
    __syncthreads();
    l[t] += v;
    __syncthreads();
  }
  if (t < SCAN_NB) blks[b*512+t] = l[t] - orig;   // exclusive
}

extern "C" __global__ void __launch_bounds__(256) k_assign(const int* __restrict__ cellcnt,
    const int* __restrict__ blks, int* __restrict__ slotmap, int* __restrict__ vv,
    int* __restrict__ cnt){
  int b = blockIdx.y, blk = blockIdx.x, t = threadIdx.x;
  int base = blk*1024 + t*4;
  int flag[4]; int s = 0;
  #pragma unroll
  for (int i=0;i<4;i++){
    int c = base+i;
    flag[i] = (c < NCELL) ? (cellcnt[b*NCELL+c] > 0) : 0;
    s += flag[i];
  }
  __shared__ int lds[256];
  lds[t] = s; __syncthreads();
  for (int o=1;o<256;o<<=1){
    int v = (t>=o) ? lds[t-o] : 0;
    __syncthreads();
    lds[t] += v;
    __syncthreads();
  }
  int run = blks[b*512+blk] + (lds[t]-s);
  #pragma unroll
  for (int i=0;i<4;i++){
    int c = base+i;
    if (c >= NCELL) break;
    int sm = -1;
    if (flag[i]){
      if (run < MAXV){
        sm = run;
        vv[b*MAXV+run]  = c;
        cnt[b*MAXV+run] = min(cellcnt[b*NCELL+c], PMAX);
      }
      run++;
    }
    slotmap[b*NCELL+c] = sm;
  }
}

extern "C" __global__ void k_fill(const float* __restrict__ pts, const int* __restrict__ slotmap,
                                  int* __restrict__ fill, int* __restrict__ plist){
  int i = blockIdx.x*256 + threadIdx.x;
  if (i >= BATCH*NPTS) return;
  const float* q = pts + (size_t)i*4;
  int vid = voxel_id(q[0], q[1], q[2]);
  if (vid < 0) return;
  int b = i / NPTS;
  int slot = slotmap[b*NCELL+vid];
  if (slot < 0) return;
  int pos = atomicAdd(&fill[b*MAXV+slot], 1);
  if (pos < PMAX) plist[((size_t)b*MAXV+slot)*PMAX + pos] = i - b*NPTS;
}

// gather sorted points into pvox [NVOX][32] float4 + per-voxel mean [NVOX] float4
extern "C" __global__ void __launch_bounds__(256) k_feat(const float* __restrict__ pts,
    const int* __restrict__ cnt, const int* __restrict__ plist,
    float* __restrict__ pvox, float* __restrict__ mean){
  int g  = threadIdx.x >> 5;
  int fv = blockIdx.x*8 + g;
  int p  = threadIdx.x & 31;
  int b  = fv / MAXV;
  __shared__ int lst[8][32];
  int c = cnt[fv];
  if (p < c) lst[g][p] = plist[(size_t)fv*PMAX + p];
  __syncthreads();
  if (p == 0){           // deterministic order: sort point indices ascending
    for (int i=1;i<c;i++){
      int key = lst[g][i]; int j = i-1;
      while (j >= 0 && lst[g][j] > key){ lst[g][j+1] = lst[g][j]; j--; }
      lst[g][j+1] = key;
    }
  }
  __syncthreads();
  float4 pt = make_float4(0.f,0.f,0.f,0.f);
  if (p < c) pt = *(const float4*)(pts + ((size_t)b*NPTS + lst[g][p])*4);
  float sx = pt.x, sy = pt.y, sz = pt.z;
  #pragma unroll
  for (int m=16;m>=1;m>>=1){
    sx += __shfl_xor(sx, m, 32); sy += __shfl_xor(sy, m, 32); sz += __shfl_xor(sz, m, 32);
  }
  float cd = (float)max(c, 1);
  if (p < c) *(float4*)(pvox + ((size_t)fv*32 + p)*4) = pt;
  if (p == 0) *(float4*)(mean + (size_t)fv*4) = make_float4(sx/cd, sy/cd, sz/cd, 0.f);
}

#define IN7(pt, mn) {pt.x, pt.y, pt.z, pt.w, pt.x-mn.x, pt.y-mn.y, pt.z-mn.z}

// ============ PFN phases ============
extern "C" __global__ void __launch_bounds__(256) k_p1(const float* __restrict__ pvox,
    const float* __restrict__ mean, const int* __restrict__ cnt,
    const float* __restrict__ w1, float* __restrict__ st){
  __shared__ float w1L[224];
  __shared__ float sred[64];
  int tid = threadIdx.x;
  if (tid < 56) ((float4*)w1L)[tid] = ((const float4*)w1)[tid];
  if (tid < 64) sred[tid] = 0.f;
  __syncthreads();
  int w = tid>>6, lane = tid&63, c = lane&31, half = lane>>5;
  float S=0.f, Q=0.f;
  for (int fv = blockIdx.x*4 + w; fv < NVOX; fv += PGRID*4){
    int c_ = cnt[fv];
    if (!c_) continue;
    float4 mn = *(const float4*)(mean + (size_t)fv*4);
    for (int p = half; p < c_; p += 2){
      float4 pt = *(const float4*)(pvox + ((size_t)fv*32+p)*4);
      float in[7] = IN7(pt, mn);
      float v = 0.f;
      #pragma unroll
      for (int k=0;k<7;k++) v += in[k]*w1L[k*32+c];
      S += v; Q += v*v;
    }
  }
  S += __shfl_xor(S,32); Q += __shfl_xor(Q,32);
  if (half==0){ atomicAdd(&sred[c],S); atomicAdd(&sred[32+c],Q); }
  __syncthreads();
  if (tid<64) atomicAdd(&st[(blockIdx.x&(SHAD-1))*64+tid], sred[tid]);
}

extern "C" __global__ void __launch_bounds__(256) k_p2(const float* __restrict__ pvox,
    const float* __restrict__ mean, const int* __restrict__ cnt,
    const float* __restrict__ w1, const float* __restrict__ g1, const float* __restrict__ b1,
    const float* __restrict__ w2, const float* __restrict__ st1, float* __restrict__ st2,
    float* __restrict__ K2buf){
  __shared__ float w1L[224];
  __shared__ float w2L[2496];
  __shared__ float sred[128];
  int tid = threadIdx.x;
  if (tid < 56) ((float4*)w1L)[tid] = ((const float4*)w1)[tid];
  for (int i=tid;i<624;i+=256) ((float4*)w2L)[i] = ((const float4*)w2)[i];
  if (tid < 128) sred[tid] = 0.f;
  __syncthreads();
  int w = tid>>6, lane = tid&63, c1 = lane&31, half = lane>>5;
  const float invN = 1.f/(float)NPFN;
  float m1=0.f, v1s=0.f;
  #pragma unroll
  for (int s=0;s<SHAD;s++){ m1 += st1[s*64+c1]; v1s += st1[s*64+32+c1]; }
  m1 *= invN; v1s = v1s*invN - m1*m1;
  float sc1 = g1[c1]*rsqrtf(v1s + 1e-3f);
  float sh1 = b1[c1] - m1*sc1;
  float S = 0.f, Q = 0.f;
  for (int fv = blockIdx.x*4 + w; fv < NVOX; fv += PGRID*4){
    int c_ = cnt[fv];
    float4 mn = *(const float4*)(mean + (size_t)fv*4);
    float vm = 0.f;
    for (int p = half; p < c_; p += 2){
      float4 pt = *(const float4*)(pvox + ((size_t)fv*32+p)*4);
      float in[7] = IN7(pt, mn);
      float v = 0.f;
      #pragma unroll
      for (int k=0;k<7;k++) v += in[k]*w1L[k*32+c1];
      vm = fmaxf(vm, v*sc1 + sh1);
    }
    vm = fmaxf(vm, __shfl_xor(vm, 32));    // relu+mask floor via init 0
    float K = 0.f;
    #pragma unroll
    for (int j=0;j<32;j++) K += __shfl(vm, j)*w2L[(7+j)*64+lane];
    if (c_) K2buf[(size_t)fv*64 + lane] = K;
    float s = (float)(PMAX-c_)*K, q = (float)(PMAX-c_)*K*K;
    for (int p = 0; p < c_; p++){
      float4 pt = *(const float4*)(pvox + ((size_t)fv*32+p)*4);
      float in[7] = IN7(pt, mn);
      float a = 0.f;
      #pragma unroll
      for (int k=0;k<7;k++) a += in[k]*w2L[k*64+lane];
      float x = a + K; s += x; q += x*x;
    }
    S += s; Q += q;
  }
  atomicAdd(&sred[lane], S); atomicAdd(&sred[64+lane], Q);
  __syncthreads();
  if (tid < 128) atomicAdd(&st2[(blockIdx.x&(SHAD-1))*128 + tid], sred[tid]);
}

extern "C" __global__ void __launch_bounds__(256) k_p3(const float* __restrict__ pvox,
    const float* __restrict__ mean, const int* __restrict__ cnt,
    const float* __restrict__ w2, const float* __restrict__ g2, const float* __restrict__ b2,
    const float* __restrict__ w3, const float* __restrict__ st2, float* __restrict__ st3,
    const float* __restrict__ K2buf, float* __restrict__ K3buf,
    float* __restrict__ amaxb, float* __restrict__ aminb){
  __shared__ float w2L[2496];
  __shared__ float w3L[4544];
  __shared__ float sred[128];
  int tid = threadIdx.x;
  for (int i=tid;i<624;i+=256)  ((float4*)w2L)[i] = ((const float4*)w2)[i];
  for (int i=tid;i<1136;i+=256) ((float4*)w3L)[i] = ((const float4*)w3)[i];
  if (tid < 128) sred[tid] = 0.f;
  __syncthreads();
  int w = tid>>6, lane = tid&63;
  const float invN = 1.f/(float)NPFN;
  float m2=0.f, v2s=0.f;
  #pragma unroll
  for (int s=0;s<SHAD;s++){ m2 += st2[s*128+lane]; v2s += st2[s*128+64+lane]; }
  m2 *= invN; v2s = v2s*invN - m2*m2;
  float sc2 = g2[lane]*rsqrtf(v2s + 1e-3f);
  float sh2 = b2[lane] - m2*sc2;
  float S = 0.f, Q = 0.f;
  for (int fv = blockIdx.x*4 + w; fv < NVOX; fv += PGRID*4){
    int c_ = cnt[fv];
    float4 mn = *(const float4*)(mean + (size_t)fv*4);
    float K2 = (c_) ? K2buf[(size_t)fv*64 + lane] : 0.f;
    float vm = 0.f;
    for (int p = 0; p < c_; p++){
      float4 pt = *(const float4*)(pvox + ((size_t)fv*32+p)*4);
      float in[7] = IN7(pt, mn);
      float a = 0.f;
      #pragma unroll
      for (int k=0;k<7;k++) a += in[k]*w2L[k*64+lane];
      vm = fmaxf(vm, (a+K2)*sc2 + sh2);
    }
    float K3 = 0.f;
    #pragma unroll
    for (int j=0;j<64;j++) K3 += __shfl(vm, j)*w3L[(7+j)*64+lane];
    float s = (float)(PMAX-c_)*K3, q = (float)(PMAX-c_)*K3*K3;
    float amx = -3.4e38f, amn2 = 3.4e38f;
    for (int p = 0; p < c_; p++){
      float4 pt = *(const float4*)(pvox + ((size_t)fv*32+p)*4);
      float in[7] = IN7(pt, mn);
      float a = 0.f;
      #pragma unroll
      for (int k=0;k<7;k++) a += in[k]*w3L[k*64+lane];
      float x = a + K3; s += x; q += x*x;
      amx = fmaxf(amx, a); amn2 = fminf(amn2, a);
    }
    if (c_){
      K3buf[(size_t)fv*64 + lane] = K3;
      amaxb[(size_t)fv*64 + lane] = amx;
      aminb[(size_t)fv*64 + lane] = amn2;
    }
    S += s; Q += q;
  }
  atomicAdd(&sred[lane], S); atomicAdd(&sred[64+lane], Q);
  __syncthreads();
  if (tid < 128) atomicAdd(&st3[(blockIdx.x&(SHAD-1))*128 + tid], sred[tid]);
}

// p4: loop-free per voxel — vf = relu(sc*(best a)+sc*K3+sh), scatter NHWC
extern "C" __global__ void __launch_bounds__(256) k_p4(const int* __restrict__ cnt,
    const int* __restrict__ vv, const float* __restrict__ g3, const float* __restrict__ b3,
    const float* __restrict__ st3, const float* __restrict__ K3buf,
    const float* __restrict__ amaxb, const float* __restrict__ aminb,
    float* __restrict__ bev){
  int tid = threadIdx.x;
  int w = tid>>6, lane = tid&63;
  const float invN = 1.f/(float)NPFN;
  float m3=0.f, q3=0.f;
  #pragma unroll
  for (int s=0;s<SHAD;s++){ m3 += st3[s*128+lane]; q3 += st3[s*128+64+lane]; }
  m3 *= invN;
  float va = q3*invN - m3*m3;
  float sc = g3[lane]*rsqrtf(va + 1e-3f);
  float sh = b3[lane] - m3*sc;
  const float* ab = (sc >= 0.f) ? amaxb : aminb;
  for (int fv = blockIdx.x*4 + w; fv < NVOX; fv += PGRID*4){
    int c_ = cnt[fv];
    if (!c_) continue;
    float K = K3buf[(size_t)fv*64 + lane];
    float a = ab[(size_t)fv*64 + lane];
    float vf = fmaxf(0.f, (a+K)*sc + sh);
    int vid = vv[fv];
    int b   = fv / MAXV;
    int cx  = vid / (GNY*GNZ);
    int cy  = (vid / GNZ) % GNY;
    atomicMax((int*)(bev + (((size_t)b*NPIX + (size_t)cy*CONVW + cx)*64) + lane),
              __float_as_int(vf));
  }
}

// ---- weight prepack: [oc][ic][3][3] f32 -> [tap][oc][ic] bf16, 5 layers
extern "C" __global__ void k_wprep(const float* __restrict__ cs_w, const float* __restrict__ rpn_w,
                                   unsigned short* __restrict__ Bw){
  int i = blockIdx.x*256 + threadIdx.x;
  if (i >= 5*36864) return;
  int l = i/36864, r = i - l*36864;
  int tap = r >> 12, oc = (r >> 6) & 63, ic = r & 63;
  const float* src = (l < 2) ? (cs_w + (size_t)l*36864) : (rpn_w + (size_t)(l-2)*36864);
  Bw[i] = f2bf(src[((size_t)oc*64 + ic)*9 + tap]);
}

// ---- conv3x3: implicit GEMM, bf16 MFMA, fused BN/relu/cvt on staging
extern "C" __global__ void __launch_bounds__(256) k_conv(const float* __restrict__ in,
    const float* __restrict__ stin, const float* __restrict__ g, const float* __restrict__ be,
    const unsigned short* __restrict__ Bw, const float* __restrict__ bias,
    float* __restrict__ out, float* __restrict__ st){
  const int b  = blockIdx.z;
  const int x0 = blockIdx.x*16, y0 = blockIdx.y*4;
  const int tid = threadIdx.x;
  const int w = tid >> 6, l = tid & 63;
  const int l15 = l & 15, quad = l >> 4;
  const int bid = (blockIdx.z*gridDim.y + blockIdx.y)*gridDim.x + blockIdx.x;
  const int shad = bid & (SHAD-1);

  __shared__ unsigned short smemA[6*18*64];
  __shared__ float bnsc[64], bnsh[64];
  __shared__ float sA[64], sQ[64];
  if (tid < 64){
    sA[tid] = 0.f; sQ[tid] = 0.f;
    float sc = 1.f, sh = 0.f;
    if (stin){
      const float invN = 1.f/(float)(BATCH*NPIX);
      float m = 0.f, q = 0.f;
      #pragma unroll
      for (int s=0;s<SHAD;s++){ m += stin[s*128+tid]; q += stin[s*128+64+tid]; }
      m *= invN;
      float va = q*invN - m*m;
      sc = g[tid]*rsqrtf(va + 1e-5f);
      sh = be[tid] - m*sc;
    }
    bnsc[tid] = sc; bnsh[tid] = sh;
  }
  __syncthreads();

  for (int i = tid; i < 864; i += 256){
    int pos = i >> 3, jb = i & 7;
    int yp = pos/18, xp = pos - yp*18;
    int gy = y0 + yp - 1, gx = x0 + xp - 1;
    unsigned short h[8] = {0,0,0,0,0,0,0,0};
    if (gy >= 0 && gy < CONVH && gx >= 0 && gx < CONVW){
      const float* src = in + (((size_t)b*NPIX + (size_t)gy*CONVW + gx)*64 + jb*8);
      float4 v0 = *(const float4*)src;
      float4 v1 = *(const float4*)(src+4);
      float vv[8] = {v0.x,v0.y,v0.z,v0.w,v1.x,v1.y,v1.z,v1.w};
      #pragma unroll
      for (int k=0;k<8;k++){
        int c = jb*8 + k;
        h[k] = f2bf(fmaxf(vv[k]*bnsc[c] + bnsh[c], 0.f));
      }
    }
    int jsw = jb ^ (xp & 7);
    *(uint4*)&smemA[pos*64 + jsw*8] = *(uint4*)h;
  }
  __syncthreads();

  f32x4 acc[4] = {{0.f,0.f,0.f,0.f},{0.f,0.f,0.f,0.f},{0.f,0.f,0.f,0.f},{0.f,0.f,0.f,0.f}};
  for (int tap = 0; tap < 9; tap++){
    int dy = tap/3, dx = tap - dy*3;
    int yp = w + dy, xp = l15 + dx;
    int abase = (yp*18 + xp)*64;
    int xm = (xp & 7);
    #pragma unroll
    for (int par = 0; par < 2; par++){
      int jb = par*4 + quad;
      short8 a = *(const short8*)&smemA[abase + (jb ^ xm)*8];
      #pragma unroll
      for (int nt = 0; nt < 4; nt++){
        const unsigned short* bp = Bw + (((size_t)tap*64 + nt*16 + l15)*64 + par*32 + quad*8);
        short8 bb = *(const short8*)bp;
        acc[nt] = __builtin_amdgcn_mfma_f32_16x16x32_bf16(a, bb, acc[nt], 0, 0, 0);
      }
    }
  }

  const int y = y0 + w;
  #pragma unroll
  for (int nt = 0; nt < 4; nt++){
    int oc = nt*16 + l15;
    float bv = bias[oc];
    float s = 0.f, q = 0.f;
    #pragma unroll
    for (int r = 0; r < 4; r++){
      float v = acc[nt][r] + bv;
      int x = x0 + quad*4 + r;
      out[((size_t)b*NPIX + (size_t)y*CONVW + x)*64 + oc] = v;
      s += v; q += v*v;
    }
    atomicAdd(&sA[oc], s); atomicAdd(&sQ[oc], q);
  }
  __syncthreads();
  if (tid < 64){
    atomicAdd(&st[shad*128 + tid], sA[tid]);
    atomicAdd(&st[shad*128 + 64 + tid], sQ[tid]);
  }
}

// ---- head 1x1: fused BN/relu of last conv layer
extern "C" __global__ void __launch_bounds__(256) k_head(const float* __restrict__ in,
    const float* __restrict__ stin, const float* __restrict__ g, const float* __restrict__ be,
    const float* __restrict__ hw, const float* __restrict__ hb, float* __restrict__ outp){
  __shared__ float bnsc[64], bnsh[64];
  int tid = threadIdx.x;
  if (tid < 64){
    const float invN = 1.f/(float)(BATCH*NPIX);
    float m = 0.f, q = 0.f;
    #pragma unroll
    for (int s=0;s<SHAD;s++){ m += stin[s*128+tid]; q += stin[s*128+64+tid]; }
    m *= invN;
    float va = q*invN - m*m;
    float sc = g[tid]*rsqrtf(va + 1e-5f);
    bnsc[tid] = sc; bnsh[tid] = be[tid] - m*sc;
  }
  __syncthreads();
  int i = blockIdx.x*256 + tid;
  if (i >= BATCH*NPIX) return;
  const float* base = in + (size_t)i*64;
  float a0 = hb[0], a1 = hb[1], a2 = hb[2];
  #pragma unroll
  for (int jb = 0; jb < 16; jb++){
    float4 v = *(const float4*)(base + jb*4);
    float vv[4] = {v.x, v.y, v.z, v.w};
    #pragma unroll
    for (int e = 0; e < 4; e++){
      int ic = jb*4 + e;
      float h = fmaxf(vv[e]*bnsc[ic] + bnsh[ic], 0.f);
      a0 += h*hw[ic]; a1 += h*hw[64+ic]; a2 += h*hw[128+ic];
    }
  }
  size_t o = (size_t)i*3;
  outp[o+0] = a0; outp[o+1] = a1; outp[o+2] = a2;
}

extern "C" void kernel_launch(void* const* d_in, const int* in_sizes, int n_in,
                              void* d_out, int out_size, void* d_ws, size_t ws_size,
                              hipStream_t stream){
  (void)in_sizes; (void)n_in; (void)out_size;
  const float* pts   = (const float*)d_in[0];
  const float* w1    = (const float*)d_in[1];
  const float* g1    = (const float*)d_in[2];
  const float* b1    = (const float*)d_in[3];
  const float* w2    = (const float*)d_in[4];
  const float* g2    = (const float*)d_in[5];
  const float* b2    = (const float*)d_in[6];
  const float* w3    = (const float*)d_in[7];
  const float* g3    = (const float*)d_in[8];
  const float* b3    = (const float*)d_in[9];
  const float* cs_w  = (const float*)d_in[10];
  const float* cs_b  = (const float*)d_in[11];
  const float* cs_g  = (const float*)d_in[12];
  const float* cs_be = (const float*)d_in[13];
  const float* rpn_w = (const float*)d_in[14];
  const float* rpn_b = (const float*)d_in[15];
  const float* rpn_g = (const float*)d_in[16];
  const float* rpn_be= (const float*)d_in[17];
  const float* hw    = (const float*)d_in[18];
  const float* hb    = (const float*)d_in[19];

  char* ws = (char*)d_ws;
  size_t off = 0;
  auto alloc = [&](size_t bytes)->char*{
    char* p = ws + off; off += (bytes + 255) & ~(size_t)255; return p;
  };
  int*   cellcnt = (int*)  alloc((size_t)BATCH*NCELL*4);
  int*   slotmap = (int*)  alloc((size_t)BATCH*NCELL*4);
  int*   blks    = (int*)  alloc((size_t)BATCH*512*4);
  int*   vv      = (int*)  alloc((size_t)NVOX*4);
  int*   cnt     = (int*)  alloc((size_t)NVOX*4);
  int*   fill    = (int*)  alloc((size_t)NVOX*4);
  int*   plist   = (int*)  alloc((size_t)NVOX*PMAX*4);      // 5.12 MB (conv bufs alias from here)
  float* pvox    = (float*)alloc((size_t)NVOX*PMAX*16);     // 20.48 MB
  float* mean    = (float*)alloc((size_t)NVOX*16);          // 0.64 MB
  float* K2buf   = (float*)alloc((size_t)NVOX*64*4);        // 10.24 MB
  float* K3buf   = (float*)alloc((size_t)NVOX*64*4);
  float* amaxb   = (float*)alloc((size_t)NVOX*64*4);
  float* aminb   = (float*)alloc((size_t)NVOX*64*4);
  float* stats   = (float*)alloc(131072);
  float* bevf    = (float*)alloc((size_t)NELEM*4);
  unsigned short* Bw = (unsigned short*)alloc((size_t)5*36864*2);
  if (off > ws_size) return;

  float* st1 = stats;            // [32][64]
  float* st2 = stats + 2048;     // [32][128]
  float* st3 = stats + 6144;     // [32][128]
  float* stc = stats + 10240;    // 5 x [32][128]

  // conv ping-pong aliases plist..K2buf (36.48MB contiguous, dead before convs)
  float* convA = (float*)plist;
  float* convB = (float*)((char*)plist + 18022400);

  hipMemsetAsync(cellcnt, 0, (size_t)BATCH*NCELL*4, stream);
  hipMemsetAsync(vv,   0, (size_t)NVOX*4, stream);
  hipMemsetAsync(cnt,  0, (size_t)NVOX*4, stream);
  hipMemsetAsync(fill, 0, (size_t)NVOX*4, stream);
  hipMemsetAsync(stats,0, 131072, stream);
  hipMemsetAsync(bevf, 0, (size_t)NELEM*4, stream);

  k_count <<<(BATCH*NPTS+255)/256, 256, 0, stream>>>(pts, cellcnt);
  k_blkcount<<<dim3(SCAN_NB,BATCH), 256, 0, stream>>>(cellcnt, blks);
  k_scan  <<<BATCH, 512, 0, stream>>>(blks);
  k_assign<<<dim3(SCAN_NB,BATCH), 256, 0, stream>>>(cellcnt, blks, slotmap, vv, cnt);
  k_fill  <<<(BATCH*NPTS+255)/256, 256, 0, stream>>>(pts, slotmap, fill, plist);
  k_feat  <<<NVOX/8, 256, 0, stream>>>(pts, cnt, plist, pvox, mean);

  k_p1<<<PGRID, 256, 0, stream>>>(pvox, mean, cnt, w1, st1);
  k_p2<<<PGRID, 256, 0, stream>>>(pvox, mean, cnt, w1, g1, b1, w2, st1, st2, K2buf);
  k_p3<<<PGRID, 256, 0, stream>>>(pvox, mean, cnt, w2, g2, b2, w3, st2, st3,
                                  K2buf, K3buf, amaxb, aminb);
  k_wprep<<<(5*36864+255)/256, 256, 0, stream>>>(cs_w, rpn_w, Bw);
  k_p4<<<PGRID, 256, 0, stream>>>(cnt, vv, g3, b3, st3, K3buf, amaxb, aminb, bevf);

  const float* bptr[5]  = {cs_b, cs_b+64,   rpn_b, rpn_b+64,   rpn_b+128};
  const float* gptr[5]  = {cs_g, cs_g+64,   rpn_g, rpn_g+64,   rpn_g+128};
  const float* beptr[5] = {cs_be,cs_be+64,  rpn_be,rpn_be+64,  rpn_be+128};
  const float* srcs[5]  = {bevf, convA, convB, convA, convB};
  float*       dsts[5]  = {convA, convB, convA, convB, convA};
  dim3 cgrid(CONVW/16, CONVH/4, BATCH);
  for (int ll = 0; ll < 5; ll++){
    const float* stin = (ll == 0) ? (const float*)nullptr : (stc + (ll-1)*4096);
    const float* gg   = (ll == 0) ? g1 : gptr[ll-1];   // unused when stin==null
    const float* bb   = (ll == 0) ? b1 : beptr[ll-1];
    k_conv<<<cgrid, 256, 0, stream>>>(srcs[ll], stin, gg, bb,
                                      Bw + (size_t)ll*36864, bptr[ll], dsts[ll],
                                      stc + ll*4096);
  }
  k_head<<<(BATCH*NPIX+255)/256, 256, 0, stream>>>(convA, stc + 4*4096, gptr[4], beptr[4],
                                                   hw, hb, (float*)d_out);
}

// Round 8
// 401.260 us; speedup vs baseline: 16.7284x; 1.0646x over previous
//
#include <hip/hip_runtime.h>

// Round 8: PFN p2/p3 single point-pass (closed-form stats via sum/sumsq),
// 4-way partial-sum K dots (break serial FMA chain), p3 emits one float2
// {K3, asel} buffer. Conv epilogue shfl-reduce. Memsets 6->2.

#define BATCH 2
#define NPTS 100000
#define GNX 176
#define GNY 200
#define GNZ 10
#define NCELL (GNX*GNY*GNZ)
#define PMAX 32
#define MAXV 20000
#define NVOX (BATCH*MAXV)
#define NPFN (NVOX*PMAX)
#define CONVH 200
#define CONVW 176
#define NPIX (CONVH*CONVW)
#define NELEM (BATCH*NPIX*64)
#define SCAN_NB ((NCELL + 1023)/1024)
#define PGRID 1024
#define SHAD 32

typedef __attribute__((ext_vector_type(8))) short short8;
typedef __attribute__((ext_vector_type(4))) float f32x4;

__device__ __forceinline__ unsigned short f2bf(float f){
  unsigned int u = __float_as_uint(f);
  u = (u + 0x7fffu + ((u >> 16) & 1u)) >> 16;
  return (unsigned short)u;
}

__device__ __forceinline__ int voxel_id(float x, float y, float z){
  int ix = (int)floorf(x / 0.4f);
  int iy = (int)floorf((y + 40.0f) / 0.4f);
  int iz = (int)floorf((z + 3.0f) / 0.4f);
  if (ix < 0 || iy < 0 || iz < 0 || ix >= GNX || iy >= GNY || iz >= GNZ) return -1;
  return (ix*GNY + iy)*GNZ + iz;
}

extern "C" __global__ void k_count(const float* __restrict__ pts, int* __restrict__ cellcnt){
  int i = blockIdx.x*256 + threadIdx.x;
  if (i >= BATCH*NPTS) return;
  const float* q = pts + (size_t)i*4;
  int vid = voxel_id(q[0], q[1], q[2]);
  if (vid < 0) return;
  int b = i / NPTS;
  atomicAdd(&cellcnt[b*NCELL + vid], 1);
}

extern "C" __global__ void __launch_bounds__(256) k_blkcount(const int* __restrict__ cellcnt,
                                                             int* __restrict__ blks){
  int b = blockIdx.y, blk = blockIdx.x, t = threadIdx.x;
  int base = blk*1024 + t*4;
  int s = 0;
  #pragma unroll
  for (int i=0;i<4;i++){ int c = base+i; if (c < NCELL) s += (cellcnt[b*NCELL+c] > 0); }
  #pragma unroll
  for (int m=32;m>=1;m>>=1) s += __shfl_xor(s, m);
  __shared__ int red[4];
  if ((t&63)==0) red[t>>6] = s;
  __syncthreads();
  if (t==0) blks[b*512+blk] = red[0]+red[1]+red[2]+red[3];
}

extern "C" __global__ void __launch_bounds__(512) k_scan(int* __restrict__ blks){
  int b = blockIdx.x, t = threadIdx.x;
  __shared__ int l[512];
  int orig = (t < SCAN_NB) ? blks[b*512+t] : 0;
  l[t] = orig;
  __syncthreads();
  for (int o=1;o<512;o<<=1){
    int v = (t>=o) ? l[t-o] : 0;
    __syncthreads();
    l[t] += v;
    __syncthreads();
  }
  if (t < SCAN_NB) blks[b*512+t] = l[t] - orig;   // exclusive
}

extern "C" __global__ void __launch_bounds__(256) k_assign(const int* __restrict__ cellcnt,
    const int* __restrict__ blks, int* __restrict__ slotmap, int* __restrict__ vv,
    int* __restrict__ cnt){
  int b = blockIdx.y, blk = blockIdx.x, t = threadIdx.x;
  int base = blk*1024 + t*4;
  int flag[4]; int s = 0;
  #pragma unroll
  for (int i=0;i<4;i++){
    int c = base+i;
    flag[i] = (c < NCELL) ? (cellcnt[b*NCELL+c] > 0) : 0;
    s += flag[i];
  }
  __shared__ int lds[256];
  lds[t] = s; __syncthreads();
  for (int o=1;o<256;o<<=1){
    int v = (t>=o) ? lds[t-o] : 0;
    __syncthreads();
    lds[t] += v;
    __syncthreads();
  }
  int run = blks[b*512+blk] + (lds[t]-s);
  #pragma unroll
  for (int i=0;i<4;i++){
    int c = base+i;
    if (c >= NCELL) break;
    int sm = -1;
    if (flag[i]){
      if (run < MAXV){
        sm = run;
        vv[b*MAXV+run]  = c;
        cnt[b*MAXV+run] = min(cellcnt[b*NCELL+c], PMAX);
      }
      run++;
    }
    slotmap[b*NCELL+c] = sm;
  }
}

extern "C" __global__ void k_fill(const float* __restrict__ pts, const int* __restrict__ slotmap,
                                  int* __restrict__ fill, int* __restrict__ plist){
  int i = blockIdx.x*256 + threadIdx.x;
  if (i >= BATCH*NPTS) return;
  const float* q = pts + (size_t)i*4;
  int vid = voxel_id(q[0], q[1], q[2]);
  if (vid < 0) return;
  int b = i / NPTS;
  int slot = slotmap[b*NCELL+vid];
  if (slot < 0) return;
  int pos = atomicAdd(&fill[b*MAXV+slot], 1);
  if (pos < PMAX) plist[((size_t)b*MAXV+slot)*PMAX + pos] = i - b*NPTS;
}

// gather sorted points into pvox [NVOX][32] float4 + per-voxel mean [NVOX] float4
extern "C" __global__ void __launch_bounds__(256) k_feat(const float* __restrict__ pts,
    const int* __restrict__ cnt, const int* __restrict__ plist,
    float* __restrict__ pvox, float* __restrict__ mean){
  int g  = threadIdx.x >> 5;
  int fv = blockIdx.x*8 + g;
  int p  = threadIdx.x & 31;
  int b  = fv / MAXV;
  __shared__ int lst[8][32];
  int c = cnt[fv];
  if (p < c) lst[g][p] = plist[(size_t)fv*PMAX + p];
  __syncthreads();
  if (p == 0){
    for (int i=1;i<c;i++){
      int key = lst[g][i]; int j = i-1;
      while (j >= 0 && lst[g][j] > key){ lst[g][j+1] = lst[g][j]; j--; }
      lst[g][j+1] = key;
    }
  }
  __syncthreads();
  float4 pt = make_float4(0.f,0.f,0.f,0.f);
  if (p < c) pt = *(const float4*)(pts + ((size_t)b*NPTS + lst[g][p])*4);
  float sx = pt.x, sy = pt.y, sz = pt.z;
  #pragma unroll
  for (int m=16;m>=1;m>>=1){
    sx += __shfl_xor(sx, m, 32); sy += __shfl_xor(sy, m, 32); sz += __shfl_xor(sz, m, 32);
  }
  float cd = (float)max(c, 1);
  if (p < c) *(float4*)(pvox + ((size_t)fv*32 + p)*4) = pt;
  if (p == 0) *(float4*)(mean + (size_t)fv*4) = make_float4(sx/cd, sy/cd, sz/cd, 0.f);
}

#define IN7(pt, mn) {pt.x, pt.y, pt.z, pt.w, pt.x-mn.x, pt.y-mn.y, pt.z-mn.z}

// ============ PFN phases ============
extern "C" __global__ void __launch_bounds__(256) k_p1(const float* __restrict__ pvox,
    const float* __restrict__ mean, const int* __restrict__ cnt,
    const float* __restrict__ w1, float* __restrict__ st){
  __shared__ float w1L[224];
  __shared__ float sred[64];
  int tid = threadIdx.x;
  if (tid < 56) ((float4*)w1L)[tid] = ((const float4*)w1)[tid];
  if (tid < 64) sred[tid] = 0.f;
  __syncthreads();
  int w = tid>>6, lane = tid&63, c = lane&31, half = lane>>5;
  float S=0.f, Q=0.f;
  for (int fv = blockIdx.x*4 + w; fv < NVOX; fv += PGRID*4){
    int c_ = cnt[fv];
    if (!c_) continue;
    float4 mn = *(const float4*)(mean + (size_t)fv*4);
    for (int p = half; p < c_; p += 2){
      float4 pt = *(const float4*)(pvox + ((size_t)fv*32+p)*4);
      float in[7] = IN7(pt, mn);
      float v = 0.f;
      #pragma unroll
      for (int k=0;k<7;k++) v += in[k]*w1L[k*32+c];
      S += v; Q += v*v;
    }
  }
  S += __shfl_xor(S,32); Q += __shfl_xor(Q,32);
  if (half==0){ atomicAdd(&sred[c],S); atomicAdd(&sred[32+c],Q); }
  __syncthreads();
  if (tid<64) atomicAdd(&st[(blockIdx.x&(SHAD-1))*64+tid], sred[tid]);
}

// p2: ONE point pass. Per point: v1 (7 FMA, channel=lane&31) for vmax1,
// a2 (7 FMA, channel=lane) with sum/sumsq. Stats closed-form:
// S = 32K + sum(a), Q = 32K^2 + sum(a^2) + 2K*sum(a).
extern "C" __global__ void __launch_bounds__(256) k_p2(const float* __restrict__ pvox,
    const float* __restrict__ mean, const int* __restrict__ cnt,
    const float* __restrict__ w1, const float* __restrict__ g1, const float* __restrict__ b1,
    const float* __restrict__ w2, const float* __restrict__ st1, float* __restrict__ st2,
    float* __restrict__ K2buf){
  __shared__ float w1L[224];
  __shared__ float w2L[2496];
  __shared__ float sred[128];
  int tid = threadIdx.x;
  if (tid < 56) ((float4*)w1L)[tid] = ((const float4*)w1)[tid];
  for (int i=tid;i<624;i+=256) ((float4*)w2L)[i] = ((const float4*)w2)[i];
  if (tid < 128) sred[tid] = 0.f;
  __syncthreads();
  int w = tid>>6, lane = tid&63, c1 = lane&31;
  const float invN = 1.f/(float)NPFN;
  float m1=0.f, v1s=0.f;
  #pragma unroll
  for (int s=0;s<SHAD;s++){ m1 += st1[s*64+c1]; v1s += st1[s*64+32+c1]; }
  m1 *= invN; v1s = v1s*invN - m1*m1;
  float sc1 = g1[c1]*rsqrtf(v1s + 1e-3f);
  float sh1 = b1[c1] - m1*sc1;
  float S = 0.f, Q = 0.f;
  for (int fv = blockIdx.x*4 + w; fv < NVOX; fv += PGRID*4){
    int c_ = cnt[fv];
    float4 mn = *(const float4*)(mean + (size_t)fv*4);
    float vm = 0.f, sa = 0.f, sq = 0.f;
    for (int p = 0; p < c_; p++){
      float4 pt = *(const float4*)(pvox + ((size_t)fv*32+p)*4);
      float in[7] = IN7(pt, mn);
      float v1 = 0.f, a2 = 0.f;
      #pragma unroll
      for (int k=0;k<7;k++){ v1 += in[k]*w1L[k*32+c1]; a2 += in[k]*w2L[k*64+lane]; }
      vm = fmaxf(vm, v1*sc1 + sh1);
      sa += a2; sq += a2*a2;
    }
    float k0=0.f,k1=0.f,k2=0.f,k3=0.f;
    #pragma unroll
    for (int j=0;j<32;j+=4){
      k0 += __shfl(vm, j  )*w2L[(7+j )*64+lane];
      k1 += __shfl(vm, j+1)*w2L[(8+j )*64+lane];
      k2 += __shfl(vm, j+2)*w2L[(9+j )*64+lane];
      k3 += __shfl(vm, j+3)*w2L[(10+j)*64+lane];
    }
    float K = (k0+k1)+(k2+k3);
    if (c_) K2buf[(size_t)fv*64 + lane] = K;
    S += (float)PMAX*K + sa;
    Q += (float)PMAX*K*K + sq + 2.f*K*sa;
  }
  atomicAdd(&sred[lane], S); atomicAdd(&sred[64+lane], Q);
  __syncthreads();
  if (tid < 128) atomicAdd(&st2[(blockIdx.x&(SHAD-1))*128 + tid], sred[tid]);
}

// p3: ONE point pass. Per point: v2=a2+K2 for vmax2 (channel=lane),
// a3 with sum/sumsq/max/min. Emits KAbuf = {K3, asel(sign g3)}.
extern "C" __global__ void __launch_bounds__(256) k_p3(const float* __restrict__ pvox,
    const float* __restrict__ mean, const int* __restrict__ cnt,
    const float* __restrict__ w2, const float* __restrict__ g2, const float* __restrict__ b2,
    const float* __restrict__ w3, const float* __restrict__ g3,
    const float* __restrict__ st2, float* __restrict__ st3,
    const float* __restrict__ K2buf, float2* __restrict__ KAbuf){
  __shared__ float w2L[2496];
  __shared__ float w3L[4544];
  __shared__ float sred[128];
  int tid = threadIdx.x;
  for (int i=tid;i<624;i+=256)  ((float4*)w2L)[i] = ((const float4*)w2)[i];
  for (int i=tid;i<1136;i+=256) ((float4*)w3L)[i] = ((const float4*)w3)[i];
  if (tid < 128) sred[tid] = 0.f;
  __syncthreads();
  int w = tid>>6, lane = tid&63;
  const float invN = 1.f/(float)NPFN;
  float m2=0.f, v2s=0.f;
  #pragma unroll
  for (int s=0;s<SHAD;s++){ m2 += st2[s*128+lane]; v2s += st2[s*128+64+lane]; }
  m2 *= invN; v2s = v2s*invN - m2*m2;
  float sc2 = g2[lane]*rsqrtf(v2s + 1e-3f);
  float sh2 = b2[lane] - m2*sc2;
  bool pickmax = (g3[lane] >= 0.f);
  float S = 0.f, Q = 0.f;
  for (int fv = blockIdx.x*4 + w; fv < NVOX; fv += PGRID*4){
    int c_ = cnt[fv];
    float4 mn = *(const float4*)(mean + (size_t)fv*4);
    float K2 = c_ ? K2buf[(size_t)fv*64 + lane] : 0.f;
    float vm = 0.f, sa = 0.f, sq = 0.f;
    float amx = -3.4e38f, amn = 3.4e38f;
    for (int p = 0; p < c_; p++){
      float4 pt = *(const float4*)(pvox + ((size_t)fv*32+p)*4);
      float in[7] = IN7(pt, mn);
      float a2 = 0.f, a3 = 0.f;
      #pragma unroll
      for (int k=0;k<7;k++){ a2 += in[k]*w2L[k*64+lane]; a3 += in[k]*w3L[k*64+lane]; }
      vm = fmaxf(vm, (a2+K2)*sc2 + sh2);
      sa += a3; sq += a3*a3;
      amx = fmaxf(amx, a3); amn = fminf(amn, a3);
    }
    float k0=0.f,k1=0.f,k2=0.f,k3=0.f;
    #pragma unroll
    for (int j=0;j<64;j+=4){
      k0 += __shfl(vm, j  )*w3L[(7+j )*64+lane];
      k1 += __shfl(vm, j+1)*w3L[(8+j )*64+lane];
      k2 += __shfl(vm, j+2)*w3L[(9+j )*64+lane];
      k3 += __shfl(vm, j+3)*w3L[(10+j)*64+lane];
    }
    float K3 = (k0+k1)+(k2+k3);
    if (c_){
      float2 ka; ka.x = K3; ka.y = pickmax ? amx : amn;
      KAbuf[(size_t)fv*64 + lane] = ka;
    }
    S += (float)PMAX*K3 + sa;
    Q += (float)PMAX*K3*K3 + sq + 2.f*K3*sa;
  }
  atomicAdd(&sred[lane], S); atomicAdd(&sred[64+lane], Q);
  __syncthreads();
  if (tid < 128) atomicAdd(&st3[(blockIdx.x&(SHAD-1))*128 + tid], sred[tid]);
}

// p4: loop-free — vf = relu((asel + K3)*sc + sh), scatter-max NHWC
extern "C" __global__ void __launch_bounds__(256) k_p4(const int* __restrict__ cnt,
    const int* __restrict__ vv, const float* __restrict__ g3, const float* __restrict__ b3,
    const float* __restrict__ st3, const float2* __restrict__ KAbuf,
    float* __restrict__ bev){
  int tid = threadIdx.x;
  int w = tid>>6, lane = tid&63;
  const float invN = 1.f/(float)NPFN;
  float m3=0.f, q3=0.f;
  #pragma unroll
  for (int s=0;s<SHAD;s++){ m3 += st3[s*128+lane]; q3 += st3[s*128+64+lane]; }
  m3 *= invN;
  float va = q3*invN - m3*m3;
  float sc = g3[lane]*rsqrtf(va + 1e-3f);
  float sh = b3[lane] - m3*sc;
  for (int fv = blockIdx.x*4 + w; fv < NVOX; fv += PGRID*4){
    int c_ = cnt[fv];
    if (!c_) continue;
    float2 ka = KAbuf[(size_t)fv*64 + lane];
    float vf = fmaxf(0.f, (ka.y + ka.x)*sc + sh);
    int vid = vv[fv];
    int b   = fv / MAXV;
    int cx  = vid / (GNY*GNZ);
    int cy  = (vid / GNZ) % GNY;
    atomicMax((int*)(bev + (((size_t)b*NPIX + (size_t)cy*CONVW + cx)*64) + lane),
              __float_as_int(vf));
  }
}

// ---- weight prepack: [oc][ic][3][3] f32 -> [tap][oc][ic] bf16, 5 layers
extern "C" __global__ void k_wprep(const float* __restrict__ cs_w, const float* __restrict__ rpn_w,
                                   unsigned short* __restrict__ Bw){
  int i = blockIdx.x*256 + threadIdx.x;
  if (i >= 5*36864) return;
  int l = i/36864, r = i - l*36864;
  int tap = r >> 12, oc = (r >> 6) & 63, ic = r & 63;
  const float* src = (l < 2) ? (cs_w + (size_t)l*36864) : (rpn_w + (size_t)(l-2)*36864);
  Bw[i] = f2bf(src[((size_t)oc*64 + ic)*9 + tap]);
}

// ---- conv3x3: implicit GEMM, bf16 MFMA, fused BN/relu/cvt on staging
extern "C" __global__ void __launch_bounds__(256) k_conv(const float* __restrict__ in,
    const float* __restrict__ stin, const float* __restrict__ g, const float* __restrict__ be,
    const unsigned short* __restrict__ Bw, const float* __restrict__ bias,
    float* __restrict__ out, float* __restrict__ st){
  const int b  = blockIdx.z;
  const int x0 = blockIdx.x*16, y0 = blockIdx.y*4;
  const int tid = threadIdx.x;
  const int w = tid >> 6, l = tid & 63;
  const int l15 = l & 15, quad = l >> 4;
  const int bid = (blockIdx.z*gridDim.y + blockIdx.y)*gridDim.x + blockIdx.x;
  const int shad = bid & (SHAD-1);

  __shared__ unsigned short smemA[6*18*64];
  __shared__ float bnsc[64], bnsh[64];
  __shared__ float sA[64], sQ[64];
  if (tid < 64){
    sA[tid] = 0.f; sQ[tid] = 0.f;
    float sc = 1.f, sh = 0.f;
    if (stin){
      const float invN = 1.f/(float)(BATCH*NPIX);
      float m = 0.f, q = 0.f;
      #pragma unroll
      for (int s=0;s<SHAD;s++){ m += stin[s*128+tid]; q += stin[s*128+64+tid]; }
      m *= invN;
      float va = q*invN - m*m;
      sc = g[tid]*rsqrtf(va + 1e-5f);
      sh = be[tid] - m*sc;
    }
    bnsc[tid] = sc; bnsh[tid] = sh;
  }
  __syncthreads();

  for (int i = tid; i < 864; i += 256){
    int pos = i >> 3, jb = i & 7;
    int yp = pos/18, xp = pos - yp*18;
    int gy = y0 + yp - 1, gx = x0 + xp - 1;
    unsigned short h[8] = {0,0,0,0,0,0,0,0};
    if (gy >= 0 && gy < CONVH && gx >= 0 && gx < CONVW){
      const float* src = in + (((size_t)b*NPIX + (size_t)gy*CONVW + gx)*64 + jb*8);
      float4 v0 = *(const float4*)src;
      float4 v1 = *(const float4*)(src+4);
      float vv[8] = {v0.x,v0.y,v0.z,v0.w,v1.x,v1.y,v1.z,v1.w};
      #pragma unroll
      for (int k=0;k<8;k++){
        int c = jb*8 + k;
        h[k] = f2bf(fmaxf(vv[k]*bnsc[c] + bnsh[c], 0.f));
      }
    }
    int jsw = jb ^ (xp & 7);
    *(uint4*)&smemA[pos*64 + jsw*8] = *(uint4*)h;
  }
  __syncthreads();

  f32x4 acc[4] = {{0.f,0.f,0.f,0.f},{0.f,0.f,0.f,0.f},{0.f,0.f,0.f,0.f},{0.f,0.f,0.f,0.f}};
  for (int tap = 0; tap < 9; tap++){
    int dy = tap/3, dx = tap - dy*3;
    int yp = w + dy, xp = l15 + dx;
    int abase = (yp*18 + xp)*64;
    int xm = (xp & 7);
    #pragma unroll
    for (int par = 0; par < 2; par++){
      int jb = par*4 + quad;
      short8 a = *(const short8*)&smemA[abase + (jb ^ xm)*8];
      #pragma unroll
      for (int nt = 0; nt < 4; nt++){
        const unsigned short* bp = Bw + (((size_t)tap*64 + nt*16 + l15)*64 + par*32 + quad*8);
        short8 bb = *(const short8*)bp;
        acc[nt] = __builtin_amdgcn_mfma_f32_16x16x32_bf16(a, bb, acc[nt], 0, 0, 0);
      }
    }
  }

  const int y = y0 + w;
  #pragma unroll
  for (int nt = 0; nt < 4; nt++){
    int oc = nt*16 + l15;
    float bv = bias[oc];
    float s = 0.f, q = 0.f;
    #pragma unroll
    for (int r = 0; r < 4; r++){
      float v = acc[nt][r] + bv;
      int x = x0 + quad*4 + r;
      out[((size_t)b*NPIX + (size_t)y*CONVW + x)*64 + oc] = v;
      s += v; q += v*v;
    }
    s += __shfl_xor(s, 16); s += __shfl_xor(s, 32);
    q += __shfl_xor(q, 16); q += __shfl_xor(q, 32);
    if (quad == 0){ atomicAdd(&sA[oc], s); atomicAdd(&sQ[oc], q); }
  }
  __syncthreads();
  if (tid < 64){
    atomicAdd(&st[shad*128 + tid], sA[tid]);
    atomicAdd(&st[shad*128 + 64 + tid], sQ[tid]);
  }
}

// ---- head 1x1: fused BN/relu of last conv layer
extern "C" __global__ void __launch_bounds__(256) k_head(const float* __restrict__ in,
    const float* __restrict__ stin, const float* __restrict__ g, const float* __restrict__ be,
    const float* __restrict__ hw, const float* __restrict__ hb, float* __restrict__ outp){
  __shared__ float bnsc[64], bnsh[64];
  int tid = threadIdx.x;
  if (tid < 64){
    const float invN = 1.f/(float)(BATCH*NPIX);
    float m = 0.f, q = 0.f;
    #pragma unroll
    for (int s=0;s<SHAD;s++){ m += stin[s*128+tid]; q += stin[s*128+64+tid]; }
    m *= invN;
    float va = q*invN - m*m;
    float sc = g[tid]*rsqrtf(va + 1e-5f);
    bnsc[tid] = sc; bnsh[tid] = be[tid] - m*sc;
  }
  __syncthreads();
  int i = blockIdx.x*256 + tid;
  if (i >= BATCH*NPIX) return;
  const float* base = in + (size_t)i*64;
  float a0 = hb[0], a1 = hb[1], a2 = hb[2];
  #pragma unroll
  for (int jb = 0; jb < 16; jb++){
    float4 v = *(const float4*)(base + jb*4);
    float vv[4] = {v.x, v.y, v.z, v.w};
    #pragma unroll
    for (int e = 0; e < 4; e++){
      int ic = jb*4 + e;
      float h = fmaxf(vv[e]*bnsc[ic] + bnsh[ic], 0.f);
      a0 += h*hw[ic]; a1 += h*hw[64+ic]; a2 += h*hw[128+ic];
    }
  }
  size_t o = (size_t)i*3;
  outp[o+0] = a0; outp[o+1] = a1; outp[o+2] = a2;
}

extern "C" void kernel_launch(void* const* d_in, const int* in_sizes, int n_in,
                              void* d_out, int out_size, void* d_ws, size_t ws_size,
                              hipStream_t stream){
  (void)in_sizes; (void)n_in; (void)out_size;
  const float* pts   = (const float*)d_in[0];
  const float* w1    = (const float*)d_in[1];
  const float* g1    = (const float*)d_in[2];
  const float* b1    = (const float*)d_in[3];
  const float* w2    = (const float*)d_in[4];
  const float* g2    = (const float*)d_in[5];
  const float* b2    = (const float*)d_in[6];
  const float* w3    = (const float*)d_in[7];
  const float* g3    = (const float*)d_in[8];
  const float* b3    = (const float*)d_in[9];
  const float* cs_w  = (const float*)d_in[10];
  const float* cs_b  = (const float*)d_in[11];
  const float* cs_g  = (const float*)d_in[12];
  const float* cs_be = (const float*)d_in[13];
  const float* rpn_w = (const float*)d_in[14];
  const float* rpn_b = (const float*)d_in[15];
  const float* rpn_g = (const float*)d_in[16];
  const float* rpn_be= (const float*)d_in[17];
  const float* hw    = (const float*)d_in[18];
  const float* hb    = (const float*)d_in[19];

  char* ws = (char*)d_ws;
  size_t off = 0;
  auto alloc = [&](size_t bytes)->char*{
    char* p = ws + off; off += (bytes + 255) & ~(size_t)255; return p;
  };
  // ---- zero region (single memset) ----
  int*   cellcnt = (int*)  alloc((size_t)BATCH*NCELL*4);
  int*   vv      = (int*)  alloc((size_t)NVOX*4);
  int*   cnt     = (int*)  alloc((size_t)NVOX*4);
  int*   fill    = (int*)  alloc((size_t)NVOX*4);
  float* stats   = (float*)alloc(131072);
  size_t zbytes  = off;
  // ---- no-init region ----
  int*   slotmap = (int*)  alloc((size_t)BATCH*NCELL*4);
  int*   blks    = (int*)  alloc((size_t)BATCH*512*4);
  int*   plist   = (int*)  alloc((size_t)NVOX*PMAX*4);      // conv alias start, 5.12MB
  float* pvox    = (float*)alloc((size_t)NVOX*PMAX*16);     // 20.48MB
  float* mean    = (float*)alloc((size_t)NVOX*16);          // 0.64MB
  float* K2buf   = (float*)alloc((size_t)NVOX*64*4);        // 10.24MB (alias end)
  float2* KAbuf  = (float2*)alloc((size_t)NVOX*64*8);       // 20.48MB
  float* bevf    = (float*)alloc((size_t)NELEM*4);          // 18.02MB
  unsigned short* Bw = (unsigned short*)alloc((size_t)5*36864*2);
  if (off > ws_size) return;

  float* st1 = stats;            // [32][64]
  float* st2 = stats + 2048;     // [32][128]
  float* st3 = stats + 6144;     // [32][128]
  float* stc = stats + 10240;    // 5 x [32][128]

  // conv ping-pong aliases plist..K2buf (36.49MB contiguous, dead before convs)
  float* convA = (float*)plist;
  float* convB = (float*)((char*)plist + 18022400);

  hipMemsetAsync(ws, 0, zbytes, stream);
  hipMemsetAsync(bevf, 0, (size_t)NELEM*4, stream);

  k_count <<<(BATCH*NPTS+255)/256, 256, 0, stream>>>(pts, cellcnt);
  k_blkcount<<<dim3(SCAN_NB,BATCH), 256, 0, stream>>>(cellcnt, blks);
  k_scan  <<<BATCH, 512, 0, stream>>>(blks);
  k_assign<<<dim3(SCAN_NB,BATCH), 256, 0, stream>>>(cellcnt, blks, slotmap, vv, cnt);
  k_fill  <<<(BATCH*NPTS+255)/256, 256, 0, stream>>>(pts, slotmap, fill, plist);
  k_feat  <<<NVOX/8, 256, 0, stream>>>(pts, cnt, plist, pvox, mean);

  k_p1<<<PGRID, 256, 0, stream>>>(pvox, mean, cnt, w1, st1);
  k_p2<<<PGRID, 256, 0, stream>>>(pvox, mean, cnt, w1, g1, b1, w2, st1, st2, K2buf);
  k_p3<<<PGRID, 256, 0, stream>>>(pvox, mean, cnt, w2, g2, b2, w3, g3, st2, st3,
                                  K2buf, KAbuf);
  k_wprep<<<(5*36864+255)/256, 256, 0, stream>>>(cs_w, rpn_w, Bw);
  k_p4<<<PGRID, 256, 0, stream>>>(cnt, vv, g3, b3, st3, KAbuf, bevf);

  const float* bptr[5]  = {cs_b, cs_b+64,   rpn_b, rpn_b+64,   rpn_b+128};
  const float* gptr[5]  = {cs_g, cs_g+64,   rpn_g, rpn_g+64,   rpn_g+128};
  const float* beptr[5] = {cs_be,cs_be+64,  rpn_be,rpn_be+64,  rpn_be+128};
  const float* srcs[5]  = {bevf, convA, convB, convA, convB};
  float*       dsts[5]  = {convA, convB, convA, convB, convA};
  dim3 cgrid(CONVW/16, CONVH/4, BATCH);
  for (int ll = 0; ll < 5; ll++){
    const float* stin = (ll == 0) ? (const float*)nullptr : (stc + (ll-1)*4096);
    const float* gg   = (ll == 0) ? g1 : gptr[ll-1];   // unused when stin==null
    const float* bb   = (ll == 0) ? b1 : beptr[ll-1];
    k_conv<<<cgrid, 256, 0, stream>>>(srcs[ll], stin, gg, bb,
                                      Bw + (size_t)ll*36864, bptr[ll], dsts[ll],
                                      stc + ll*4096);
  }
  k_head<<<(BATCH*NPIX+255)/256, 256, 0, stream>>>(convA, stc + 4*4096, gptr[4], beptr[4],
                                                   hw, hb, (float*)d_out);
}

// Round 9
// 321.197 us; speedup vs baseline: 20.8982x; 1.2493x over previous
//
#include <hip/hip_runtime.h>

// Round 9: k_conv retiled 16x4 -> 16x8 (550 blocks, 576 MFMA/block, 8 f32x4
// acc/wave, tap loop unrolled). Fixes the 29K-cycles/block latency regime
// (MfmaUtil 3.5%, all pipes idle). PFN/voxelize unchanged from round 8.

#define BATCH 2
#define NPTS 100000
#define GNX 176
#define GNY 200
#define GNZ 10
#define NCELL (GNX*GNY*GNZ)
#define PMAX 32
#define MAXV 20000
#define NVOX (BATCH*MAXV)
#define NPFN (NVOX*PMAX)
#define CONVH 200
#define CONVW 176
#define NPIX (CONVH*CONVW)
#define NELEM (BATCH*NPIX*64)
#define SCAN_NB ((NCELL + 1023)/1024)
#define PGRID 1024
#define SHAD 32

typedef __attribute__((ext_vector_type(8))) short short8;
typedef __attribute__((ext_vector_type(4))) float f32x4;

__device__ __forceinline__ unsigned short f2bf(float f){
  unsigned int u = __float_as_uint(f);
  u = (u + 0x7fffu + ((u >> 16) & 1u)) >> 16;
  return (unsigned short)u;
}

__device__ __forceinline__ int voxel_id(float x, float y, float z){
  int ix = (int)floorf(x / 0.4f);
  int iy = (int)floorf((y + 40.0f) / 0.4f);
  int iz = (int)floorf((z + 3.0f) / 0.4f);
  if (ix < 0 || iy < 0 || iz < 0 || ix >= GNX || iy >= GNY || iz >= GNZ) return -1;
  return (ix*GNY + iy)*GNZ + iz;
}

extern "C" __global__ void k_count(const float* __restrict__ pts, int* __restrict__ cellcnt){
  int i = blockIdx.x*256 + threadIdx.x;
  if (i >= BATCH*NPTS) return;
  const float* q = pts + (size_t)i*4;
  int vid = voxel_id(q[0], q[1], q[2]);
  if (vid < 0) return;
  int b = i / NPTS;
  atomicAdd(&cellcnt[b*NCELL + vid], 1);
}

extern "C" __global__ void __launch_bounds__(256) k_blkcount(const int* __restrict__ cellcnt,
                                                             int* __restrict__ blks){
  int b = blockIdx.y, blk = blockIdx.x, t = threadIdx.x;
  int base = blk*1024 + t*4;
  int s = 0;
  #pragma unroll
  for (int i=0;i<4;i++){ int c = base+i; if (c < NCELL) s += (cellcnt[b*NCELL+c] > 0); }
  #pragma unroll
  for (int m=32;m>=1;m>>=1) s += __shfl_xor(s, m);
  __shared__ int red[4];
  if ((t&63)==0) red[t>>6] = s;
  __syncthreads();
  if (t==0) blks[b*512+blk] = red[0]+red[1]+red[2]+red[3];
}

extern "C" __global__ void __launch_bounds__(512) k_scan(int* __restrict__ blks){
  int b = blockIdx.x, t = threadIdx.x;
  __shared__ int l[512];
  int orig = (t < SCAN_NB) ? blks[b*512+t] : 0;
  l[t] = orig;
  __syncthreads();
  for (int o=1;o<512;o<<=1){
    int v = (t>=o) ? l[t-o] : 0;
    __syncthreads();
    l[t] += v;
    __syncthreads();
  }
  if (t < SCAN_NB) blks[b*512+t] = l[t] - orig;   // exclusive
}

extern "C" __global__ void __launch_bounds__(256) k_assign(const int* __restrict__ cellcnt,
    const int* __restrict__ blks, int* __restrict__ slotmap, int* __restrict__ vv,
    int* __restrict__ cnt){
  int b = blockIdx.y, blk = blockIdx.x, t = threadIdx.x;
  int base = blk*1024 + t*4;
  int flag[4]; int s = 0;
  #pragma unroll
  for (int i=0;i<4;i++){
    int c = base+i;
    flag[i] = (c < NCELL) ? (cellcnt[b*NCELL+c] > 0) : 0;
    s += flag[i];
  }
  __shared__ int lds[256];
  lds[t] = s; __syncthreads();
  for (int o=1;o<256;o<<=1){
    int v = (t>=o) ? lds[t-o] : 0;
    __syncthreads();
    lds[t] += v;
    __syncthreads();
  }
  int run = blks[b*512+blk] + (lds[t]-s);
  #pragma unroll
  for (int i=0;i<4;i++){
    int c = base+i;
    if (c >= NCELL) break;
    int sm = -1;
    if (flag[i]){
      if (run < MAXV){
        sm = run;
        vv[b*MAXV+run]  = c;
        cnt[b*MAXV+run] = min(cellcnt[b*NCELL+c], PMAX);
      }
      run++;
    }
    slotmap[b*NCELL+c] = sm;
  }
}

extern "C" __global__ void k_fill(const float* __restrict__ pts, const int* __restrict__ slotmap,
                                  int* __restrict__ fill, int* __restrict__ plist){
  int i = blockIdx.x*256 + threadIdx.x;
  if (i >= BATCH*NPTS) return;
  const float* q = pts + (size_t)i*4;
  int vid = voxel_id(q[0], q[1], q[2]);
  if (vid < 0) return;
  int b = i / NPTS;
  int slot = slotmap[b*NCELL+vid];
  if (slot < 0) return;
  int pos = atomicAdd(&fill[b*MAXV+slot], 1);
  if (pos < PMAX) plist[((size_t)b*MAXV+slot)*PMAX + pos] = i - b*NPTS;
}

// gather sorted points into pvox [NVOX][32] float4 + per-voxel mean [NVOX] float4
extern "C" __global__ void __launch_bounds__(256) k_feat(const float* __restrict__ pts,
    const int* __restrict__ cnt, const int* __restrict__ plist,
    float* __restrict__ pvox, float* __restrict__ mean){
  int g  = threadIdx.x >> 5;
  int fv = blockIdx.x*8 + g;
  int p  = threadIdx.x & 31;
  int b  = fv / MAXV;
  __shared__ int lst[8][32];
  int c = cnt[fv];
  if (p < c) lst[g][p] = plist[(size_t)fv*PMAX + p];
  __syncthreads();
  if (p == 0){
    for (int i=1;i<c;i++){
      int key = lst[g][i]; int j = i-1;
      while (j >= 0 && lst[g][j] > key){ lst[g][j+1] = lst[g][j]; j--; }
      lst[g][j+1] = key;
    }
  }
  __syncthreads();
  float4 pt = make_float4(0.f,0.f,0.f,0.f);
  if (p < c) pt = *(const float4*)(pts + ((size_t)b*NPTS + lst[g][p])*4);
  float sx = pt.x, sy = pt.y, sz = pt.z;
  #pragma unroll
  for (int m=16;m>=1;m>>=1){
    sx += __shfl_xor(sx, m, 32); sy += __shfl_xor(sy, m, 32); sz += __shfl_xor(sz, m, 32);
  }
  float cd = (float)max(c, 1);
  if (p < c) *(float4*)(pvox + ((size_t)fv*32 + p)*4) = pt;
  if (p == 0) *(float4*)(mean + (size_t)fv*4) = make_float4(sx/cd, sy/cd, sz/cd, 0.f);
}

#define IN7(pt, mn) {pt.x, pt.y, pt.z, pt.w, pt.x-mn.x, pt.y-mn.y, pt.z-mn.z}

// ============ PFN phases (unchanged from round 8) ============
extern "C" __global__ void __launch_bounds__(256) k_p1(const float* __restrict__ pvox,
    const float* __restrict__ mean, const int* __restrict__ cnt,
    const float* __restrict__ w1, float* __restrict__ st){
  __shared__ float w1L[224];
  __shared__ float sred[64];
  int tid = threadIdx.x;
  if (tid < 56) ((float4*)w1L)[tid] = ((const float4*)w1)[tid];
  if (tid < 64) sred[tid] = 0.f;
  __syncthreads();
  int w = tid>>6, lane = tid&63, c = lane&31, half = lane>>5;
  float S=0.f, Q=0.f;
  for (int fv = blockIdx.x*4 + w; fv < NVOX; fv += PGRID*4){
    int c_ = cnt[fv];
    if (!c_) continue;
    float4 mn = *(const float4*)(mean + (size_t)fv*4);
    for (int p = half; p < c_; p += 2){
      float4 pt = *(const float4*)(pvox + ((size_t)fv*32+p)*4);
      float in[7] = IN7(pt, mn);
      float v = 0.f;
      #pragma unroll
      for (int k=0;k<7;k++) v += in[k]*w1L[k*32+c];
      S += v; Q += v*v;
    }
  }
  S += __shfl_xor(S,32); Q += __shfl_xor(Q,32);
  if (half==0){ atomicAdd(&sred[c],S); atomicAdd(&sred[32+c],Q); }
  __syncthreads();
  if (tid<64) atomicAdd(&st[(blockIdx.x&(SHAD-1))*64+tid], sred[tid]);
}

extern "C" __global__ void __launch_bounds__(256) k_p2(const float* __restrict__ pvox,
    const float* __restrict__ mean, const int* __restrict__ cnt,
    const float* __restrict__ w1, const float* __restrict__ g1, const float* __restrict__ b1,
    const float* __restrict__ w2, const float* __restrict__ st1, float* __restrict__ st2,
    float* __restrict__ K2buf){
  __shared__ float w1L[224];
  __shared__ float w2L[2496];
  __shared__ float sred[128];
  int tid = threadIdx.x;
  if (tid < 56) ((float4*)w1L)[tid] = ((const float4*)w1)[tid];
  for (int i=tid;i<624;i+=256) ((float4*)w2L)[i] = ((const float4*)w2)[i];
  if (tid < 128) sred[tid] = 0.f;
  __syncthreads();
  int w = tid>>6, lane = tid&63, c1 = lane&31;
  const float invN = 1.f/(float)NPFN;
  float m1=0.f, v1s=0.f;
  #pragma unroll
  for (int s=0;s<SHAD;s++){ m1 += st1[s*64+c1]; v1s += st1[s*64+32+c1]; }
  m1 *= invN; v1s = v1s*invN - m1*m1;
  float sc1 = g1[c1]*rsqrtf(v1s + 1e-3f);
  float sh1 = b1[c1] - m1*sc1;
  float S = 0.f, Q = 0.f;
  for (int fv = blockIdx.x*4 + w; fv < NVOX; fv += PGRID*4){
    int c_ = cnt[fv];
    float4 mn = *(const float4*)(mean + (size_t)fv*4);
    float vm = 0.f, sa = 0.f, sq = 0.f;
    for (int p = 0; p < c_; p++){
      float4 pt = *(const float4*)(pvox + ((size_t)fv*32+p)*4);
      float in[7] = IN7(pt, mn);
      float v1 = 0.f, a2 = 0.f;
      #pragma unroll
      for (int k=0;k<7;k++){ v1 += in[k]*w1L[k*32+c1]; a2 += in[k]*w2L[k*64+lane]; }
      vm = fmaxf(vm, v1*sc1 + sh1);
      sa += a2; sq += a2*a2;
    }
    float k0=0.f,k1=0.f,k2=0.f,k3=0.f;
    #pragma unroll
    for (int j=0;j<32;j+=4){
      k0 += __shfl(vm, j  )*w2L[(7+j )*64+lane];
      k1 += __shfl(vm, j+1)*w2L[(8+j )*64+lane];
      k2 += __shfl(vm, j+2)*w2L[(9+j )*64+lane];
      k3 += __shfl(vm, j+3)*w2L[(10+j)*64+lane];
    }
    float K = (k0+k1)+(k2+k3);
    if (c_) K2buf[(size_t)fv*64 + lane] = K;
    S += (float)PMAX*K + sa;
    Q += (float)PMAX*K*K + sq + 2.f*K*sa;
  }
  atomicAdd(&sred[lane], S); atomicAdd(&sred[64+lane], Q);
  __syncthreads();
  if (tid < 128) atomicAdd(&st2[(blockIdx.x&(SHAD-1))*128 + tid], sred[tid]);
}

extern "C" __global__ void __launch_bounds__(256) k_p3(const float* __restrict__ pvox,
    const float* __restrict__ mean, const int* __restrict__ cnt,
    const float* __restrict__ w2, const float* __restrict__ g2, const float* __restrict__ b2,
    const float* __restrict__ w3, const float* __restrict__ g3,
    const float* __restrict__ st2, float* __restrict__ st3,
    const float* __restrict__ K2buf, float2* __restrict__ KAbuf){
  __shared__ float w2L[2496];
  __shared__ float w3L[4544];
  __shared__ float sred[128];
  int tid = threadIdx.x;
  for (int i=tid;i<624;i+=256)  ((float4*)w2L)[i] = ((const float4*)w2)[i];
  for (int i=tid;i<1136;i+=256) ((float4*)w3L)[i] = ((const float4*)w3)[i];
  if (tid < 128) sred[tid] = 0.f;
  __syncthreads();
  int w = tid>>6, lane = tid&63;
  const float invN = 1.f/(float)NPFN;
  float m2=0.f, v2s=0.f;
  #pragma unroll
  for (int s=0;s<SHAD;s++){ m2 += st2[s*128+lane]; v2s += st2[s*128+64+lane]; }
  m2 *= invN; v2s = v2s*invN - m2*m2;
  float sc2 = g2[lane]*rsqrtf(v2s + 1e-3f);
  float sh2 = b2[lane] - m2*sc2;
  bool pickmax = (g3[lane] >= 0.f);
  float S = 0.f, Q = 0.f;
  for (int fv = blockIdx.x*4 + w; fv < NVOX; fv += PGRID*4){
    int c_ = cnt[fv];
    float4 mn = *(const float4*)(mean + (size_t)fv*4);
    float K2 = c_ ? K2buf[(size_t)fv*64 + lane] : 0.f;
    float vm = 0.f, sa = 0.f, sq = 0.f;
    float amx = -3.4e38f, amn = 3.4e38f;
    for (int p = 0; p < c_; p++){
      float4 pt = *(const float4*)(pvox + ((size_t)fv*32+p)*4);
      float in[7] = IN7(pt, mn);
      float a2 = 0.f, a3 = 0.f;
      #pragma unroll
      for (int k=0;k<7;k++){ a2 += in[k]*w2L[k*64+lane]; a3 += in[k]*w3L[k*64+lane]; }
      vm = fmaxf(vm, (a2+K2)*sc2 + sh2);
      sa += a3; sq += a3*a3;
      amx = fmaxf(amx, a3); amn = fminf(amn, a3);
    }
    float k0=0.f,k1=0.f,k2=0.f,k3=0.f;
    #pragma unroll
    for (int j=0;j<64;j+=4){
      k0 += __shfl(vm, j  )*w3L[(7+j )*64+lane];
      k1 += __shfl(vm, j+1)*w3L[(8+j )*64+lane];
      k2 += __shfl(vm, j+2)*w3L[(9+j )*64+lane];
      k3 += __shfl(vm, j+3)*w3L[(10+j)*64+lane];
    }
    float K3 = (k0+k1)+(k2+k3);
    if (c_){
      float2 ka; ka.x = K3; ka.y = pickmax ? amx : amn;
      KAbuf[(size_t)fv*64 + lane] = ka;
    }
    S += (float)PMAX*K3 + sa;
    Q += (float)PMAX*K3*K3 + sq + 2.f*K3*sa;
  }
  atomicAdd(&sred[lane], S); atomicAdd(&sred[64+lane], Q);
  __syncthreads();
  if (tid < 128) atomicAdd(&st3[(blockIdx.x&(SHAD-1))*128 + tid], sred[tid]);
}

// p4: loop-free — vf = relu((asel + K3)*sc + sh), scatter-max NHWC
extern "C" __global__ void __launch_bounds__(256) k_p4(const int* __restrict__ cnt,
    const int* __restrict__ vv, const float* __restrict__ g3, const float* __restrict__ b3,
    const float* __restrict__ st3, const float2* __restrict__ KAbuf,
    float* __restrict__ bev){
  int tid = threadIdx.x;
  int w = tid>>6, lane = tid&63;
  const float invN = 1.f/(float)NPFN;
  float m3=0.f, q3=0.f;
  #pragma unroll
  for (int s=0;s<SHAD;s++){ m3 += st3[s*128+lane]; q3 += st3[s*128+64+lane]; }
  m3 *= invN;
  float va = q3*invN - m3*m3;
  float sc = g3[lane]*rsqrtf(va + 1e-3f);
  float sh = b3[lane] - m3*sc;
  for (int fv = blockIdx.x*4 + w; fv < NVOX; fv += PGRID*4){
    int c_ = cnt[fv];
    if (!c_) continue;
    float2 ka = KAbuf[(size_t)fv*64 + lane];
    float vf = fmaxf(0.f, (ka.y + ka.x)*sc + sh);
    int vid = vv[fv];
    int b   = fv / MAXV;
    int cx  = vid / (GNY*GNZ);
    int cy  = (vid / GNZ) % GNY;
    atomicMax((int*)(bev + (((size_t)b*NPIX + (size_t)cy*CONVW + cx)*64) + lane),
              __float_as_int(vf));
  }
}

// ---- weight prepack: [oc][ic][3][3] f32 -> [tap][oc][ic] bf16, 5 layers
extern "C" __global__ void k_wprep(const float* __restrict__ cs_w, const float* __restrict__ rpn_w,
                                   unsigned short* __restrict__ Bw){
  int i = blockIdx.x*256 + threadIdx.x;
  if (i >= 5*36864) return;
  int l = i/36864, r = i - l*36864;
  int tap = r >> 12, oc = (r >> 6) & 63, ic = r & 63;
  const float* src = (l < 2) ? (cs_w + (size_t)l*36864) : (rpn_w + (size_t)(l-2)*36864);
  Bw[i] = f2bf(src[((size_t)oc*64 + ic)*9 + tap]);
}

// ---- conv3x3: implicit GEMM, bf16 MFMA. Tile 16x * 8y, 4 waves (2 rows ea),
//      576 MFMA/block, fused BN/relu/cvt on staging, shadowed stats.
#define CTH 8
extern "C" __global__ void __launch_bounds__(256) k_conv(const float* __restrict__ in,
    const float* __restrict__ stin, const float* __restrict__ g, const float* __restrict__ be,
    const unsigned short* __restrict__ Bw, const float* __restrict__ bias,
    float* __restrict__ out, float* __restrict__ st){
  const int b  = blockIdx.z;
  const int x0 = blockIdx.x*16, y0 = blockIdx.y*CTH;
  const int tid = threadIdx.x;
  const int w = tid >> 6, l = tid & 63;
  const int l15 = l & 15, quad = l >> 4;
  const int bid = (blockIdx.z*gridDim.y + blockIdx.y)*gridDim.x + blockIdx.x;
  const int shad = bid & (SHAD-1);

  __shared__ unsigned short smemA[(CTH+2)*18*64];   // 23040 B, 16B-block XOR swizzle on ic
  __shared__ float bnsc[64], bnsh[64];
  __shared__ float sA[64], sQ[64];
  if (tid < 64){
    sA[tid] = 0.f; sQ[tid] = 0.f;
    float sc = 1.f, sh = 0.f;
    if (stin){
      const float invN = 1.f/(float)(BATCH*NPIX);
      float m = 0.f, q = 0.f;
      #pragma unroll
      for (int s=0;s<SHAD;s++){ m += stin[s*128+tid]; q += stin[s*128+64+tid]; }
      m *= invN;
      float va = q*invN - m*m;
      sc = g[tid]*rsqrtf(va + 1e-5f);
      sh = be[tid] - m*sc;
    }
    bnsc[tid] = sc; bnsh[tid] = sh;
  }
  __syncthreads();

  for (int i = tid; i < (CTH+2)*18*8; i += 256){
    int pos = i >> 3, jb = i & 7;
    int yp = pos/18, xp = pos - yp*18;
    int gy = y0 + yp - 1, gx = x0 + xp - 1;
    unsigned short h[8] = {0,0,0,0,0,0,0,0};
    if (gy >= 0 && gy < CONVH && gx >= 0 && gx < CONVW){
      const float* src = in + (((size_t)b*NPIX + (size_t)gy*CONVW + gx)*64 + jb*8);
      float4 v0 = *(const float4*)src;
      float4 v1 = *(const float4*)(src+4);
      float vv[8] = {v0.x,v0.y,v0.z,v0.w,v1.x,v1.y,v1.z,v1.w};
      #pragma unroll
      for (int k=0;k<8;k++){
        int c = jb*8 + k;
        h[k] = f2bf(fmaxf(vv[k]*bnsc[c] + bnsh[c], 0.f));
      }
    }
    int jsw = jb ^ (xp & 7);
    *(uint4*)&smemA[pos*64 + jsw*8] = *(uint4*)h;
  }
  __syncthreads();

  f32x4 acc[2][4] = {{{0.f,0.f,0.f,0.f},{0.f,0.f,0.f,0.f},{0.f,0.f,0.f,0.f},{0.f,0.f,0.f,0.f}},
                     {{0.f,0.f,0.f,0.f},{0.f,0.f,0.f,0.f},{0.f,0.f,0.f,0.f},{0.f,0.f,0.f,0.f}}};
  #pragma unroll
  for (int tap = 0; tap < 9; tap++){
    const int dy = tap/3, dx = tap - dy*3;
    const int xp = l15 + dx;
    const int xm = xp & 7;
    short8 b0[4], b1[4];
    #pragma unroll
    for (int nt = 0; nt < 4; nt++){
      const unsigned short* bp = Bw + (((size_t)tap*64 + nt*16 + l15)*64 + quad*8);
      b0[nt] = *(const short8*)bp;
      b1[nt] = *(const short8*)(bp + 32);
    }
    #pragma unroll
    for (int rr = 0; rr < 2; rr++){
      int yp = 2*w + rr + dy;
      int abase = (yp*18 + xp)*64;
      short8 aL = *(const short8*)&smemA[abase + ((quad    ) ^ xm)*8];
      short8 aH = *(const short8*)&smemA[abase + ((4 + quad) ^ xm)*8];
      #pragma unroll
      for (int nt = 0; nt < 4; nt++)
        acc[rr][nt] = __builtin_amdgcn_mfma_f32_16x16x32_bf16(aL, b0[nt], acc[rr][nt], 0,0,0);
      #pragma unroll
      for (int nt = 0; nt < 4; nt++)
        acc[rr][nt] = __builtin_amdgcn_mfma_f32_16x16x32_bf16(aH, b1[nt], acc[rr][nt], 0,0,0);
    }
  }

  #pragma unroll
  for (int nt = 0; nt < 4; nt++){
    int oc = nt*16 + l15;
    float bv = bias[oc];
    float s = 0.f, q = 0.f;
    #pragma unroll
    for (int rr = 0; rr < 2; rr++){
      int y = y0 + 2*w + rr;
      size_t rbase = ((size_t)b*NPIX + (size_t)y*CONVW)*64;
      #pragma unroll
      for (int r = 0; r < 4; r++){
        float v = acc[rr][nt][r] + bv;
        int x = x0 + quad*4 + r;
        out[rbase + (size_t)x*64 + oc] = v;
        s += v; q += v*v;
      }
    }
    s += __shfl_xor(s, 16); s += __shfl_xor(s, 32);
    q += __shfl_xor(q, 16); q += __shfl_xor(q, 32);
    if (quad == 0){ atomicAdd(&sA[oc], s); atomicAdd(&sQ[oc], q); }
  }
  __syncthreads();
  if (tid < 64){
    atomicAdd(&st[shad*128 + tid], sA[tid]);
    atomicAdd(&st[shad*128 + 64 + tid], sQ[tid]);
  }
}

// ---- head 1x1: fused BN/relu of last conv layer
extern "C" __global__ void __launch_bounds__(256) k_head(const float* __restrict__ in,
    const float* __restrict__ stin, const float* __restrict__ g, const float* __restrict__ be,
    const float* __restrict__ hw, const float* __restrict__ hb, float* __restrict__ outp){
  __shared__ float bnsc[64], bnsh[64];
  int tid = threadIdx.x;
  if (tid < 64){
    const float invN = 1.f/(float)(BATCH*NPIX);
    float m = 0.f, q = 0.f;
    #pragma unroll
    for (int s=0;s<SHAD;s++){ m += stin[s*128+tid]; q += stin[s*128+64+tid]; }
    m *= invN;
    float va = q*invN - m*m;
    float sc = g[tid]*rsqrtf(va + 1e-5f);
    bnsc[tid] = sc; bnsh[tid] = be[tid] - m*sc;
  }
  __syncthreads();
  int i = blockIdx.x*256 + tid;
  if (i >= BATCH*NPIX) return;
  const float* base = in + (size_t)i*64;
  float a0 = hb[0], a1 = hb[1], a2 = hb[2];
  #pragma unroll
  for (int jb = 0; jb < 16; jb++){
    float4 v = *(const float4*)(base + jb*4);
    float vv[4] = {v.x, v.y, v.z, v.w};
    #pragma unroll
    for (int e = 0; e < 4; e++){
      int ic = jb*4 + e;
      float h = fmaxf(vv[e]*bnsc[ic] + bnsh[ic], 0.f);
      a0 += h*hw[ic]; a1 += h*hw[64+ic]; a2 += h*hw[128+ic];
    }
  }
  size_t o = (size_t)i*3;
  outp[o+0] = a0; outp[o+1] = a1; outp[o+2] = a2;
}

extern "C" void kernel_launch(void* const* d_in, const int* in_sizes, int n_in,
                              void* d_out, int out_size, void* d_ws, size_t ws_size,
                              hipStream_t stream){
  (void)in_sizes; (void)n_in; (void)out_size;
  const float* pts   = (const float*)d_in[0];
  const float* w1    = (const float*)d_in[1];
  const float* g1    = (const float*)d_in[2];
  const float* b1    = (const float*)d_in[3];
  const float* w2    = (const float*)d_in[4];
  const float* g2    = (const float*)d_in[5];
  const float* b2    = (const float*)d_in[6];
  const float* w3    = (const float*)d_in[7];
  const float* g3    = (const float*)d_in[8];
  const float* b3    = (const float*)d_in[9];
  const float* cs_w  = (const float*)d_in[10];
  const float* cs_b  = (const float*)d_in[11];
  const float* cs_g  = (const float*)d_in[12];
  const float* cs_be = (const float*)d_in[13];
  const float* rpn_w = (const float*)d_in[14];
  const float* rpn_b = (const float*)d_in[15];
  const float* rpn_g = (const float*)d_in[16];
  const float* rpn_be= (const float*)d_in[17];
  const float* hw    = (const float*)d_in[18];
  const float* hb    = (const float*)d_in[19];

  char* ws = (char*)d_ws;
  size_t off = 0;
  auto alloc = [&](size_t bytes)->char*{
    char* p = ws + off; off += (bytes + 255) & ~(size_t)255; return p;
  };
  // ---- zero region (single memset) ----
  int*   cellcnt = (int*)  alloc((size_t)BATCH*NCELL*4);
  int*   vv      = (int*)  alloc((size_t)NVOX*4);
  int*   cnt     = (int*)  alloc((size_t)NVOX*4);
  int*   fill    = (int*)  alloc((size_t)NVOX*4);
  float* stats   = (float*)alloc(131072);
  size_t zbytes  = off;
  // ---- no-init region ----
  int*   slotmap = (int*)  alloc((size_t)BATCH*NCELL*4);
  int*   blks    = (int*)  alloc((size_t)BATCH*512*4);
  int*   plist   = (int*)  alloc((size_t)NVOX*PMAX*4);      // conv alias start, 5.12MB
  float* pvox    = (float*)alloc((size_t)NVOX*PMAX*16);     // 20.48MB
  float* mean    = (float*)alloc((size_t)NVOX*16);          // 0.64MB
  float* K2buf   = (float*)alloc((size_t)NVOX*64*4);        // 10.24MB (alias end)
  float2* KAbuf  = (float2*)alloc((size_t)NVOX*64*8);       // 20.48MB
  float* bevf    = (float*)alloc((size_t)NELEM*4);          // 18.02MB
  unsigned short* Bw = (unsigned short*)alloc((size_t)5*36864*2);
  if (off > ws_size) return;

  float* st1 = stats;            // [32][64]
  float* st2 = stats + 2048;     // [32][128]
  float* st3 = stats + 6144;     // [32][128]
  float* stc = stats + 10240;    // 5 x [32][128]

  // conv ping-pong aliases plist..K2buf (36.49MB contiguous, dead before convs)
  float* convA = (float*)plist;
  float* convB = (float*)((char*)plist + 18022400);

  hipMemsetAsync(ws, 0, zbytes, stream);
  hipMemsetAsync(bevf, 0, (size_t)NELEM*4, stream);

  k_count <<<(BATCH*NPTS+255)/256, 256, 0, stream>>>(pts, cellcnt);
  k_blkcount<<<dim3(SCAN_NB,BATCH), 256, 0, stream>>>(cellcnt, blks);
  k_scan  <<<BATCH, 512, 0, stream>>>(blks);
  k_assign<<<dim3(SCAN_NB,BATCH), 256, 0, stream>>>(cellcnt, blks, slotmap, vv, cnt);
  k_fill  <<<(BATCH*NPTS+255)/256, 256, 0, stream>>>(pts, slotmap, fill, plist);
  k_feat  <<<NVOX/8, 256, 0, stream>>>(pts, cnt, plist, pvox, mean);

  k_p1<<<PGRID, 256, 0, stream>>>(pvox, mean, cnt, w1, st1);
  k_p2<<<PGRID, 256, 0, stream>>>(pvox, mean, cnt, w1, g1, b1, w2, st1, st2, K2buf);
  k_p3<<<PGRID, 256, 0, stream>>>(pvox, mean, cnt, w2, g2, b2, w3, g3, st2, st3,
                                  K2buf, KAbuf);
  k_wprep<<<(5*36864+255)/256, 256, 0, stream>>>(cs_w, rpn_w, Bw);
  k_p4<<<PGRID, 256, 0, stream>>>(cnt, vv, g3, b3, st3, KAbuf, bevf);

  const float* bptr[5]  = {cs_b, cs_b+64,   rpn_b, rpn_b+64,   rpn_b+128};
  const float* gptr[5]  = {cs_g, cs_g+64,   rpn_g, rpn_g+64,   rpn_g+128};
  const float* beptr[5] = {cs_be,cs_be+64,  rpn_be,rpn_be+64,  rpn_be+128};
  const float* srcs[5]  = {bevf, convA, convB, convA, convB};
  float*       dsts[5]  = {convA, convB, convA, convB, convA};
  dim3 cgrid(CONVW/16, CONVH/CTH, BATCH);
  for (int ll = 0; ll < 5; ll++){
    const float* stin = (ll == 0) ? (const float*)nullptr : (stc + (ll-1)*4096);
    const float* gg   = (ll == 0) ? g1 : gptr[ll-1];   // unused when stin==null
    const float* bb   = (ll == 0) ? b1 : beptr[ll-1];
    k_conv<<<cgrid, 256, 0, stream>>>(srcs[ll], stin, gg, bb,
                                      Bw + (size_t)ll*36864, bptr[ll], dsts[ll],
                                      stc + ll*4096);
  }
  k_head<<<(BATCH*NPIX+255)/256, 256, 0, stream>>>(convA, stc + 4*4096, gptr[4], beptr[4],
                                                   hw, hb, (float*)d_out);
}

// Round 10
// 314.734 us; speedup vs baseline: 21.3273x; 1.0205x over previous
//
#include <hip/hip_runtime.h>

// Round 10: software-pipelined voxel loops in k_p1/k_p2/k_p3 — issue next
// voxel's loads (cnt/mean/K2/pt0/pt1) before processing current voxel from
// registers. Breaks the per-voxel serial load chain (p3 was 78% stall).
// Math identical to round 9. Convs/voxelize unchanged.

#define BATCH 2
#define NPTS 100000
#define GNX 176
#define GNY 200
#define GNZ 10
#define NCELL (GNX*GNY*GNZ)
#define PMAX 32
#define MAXV 20000
#define NVOX (BATCH*MAXV)
#define NPFN (NVOX*PMAX)
#define CONVH 200
#define CONVW 176
#define NPIX (CONVH*CONVW)
#define NELEM (BATCH*NPIX*64)
#define SCAN_NB ((NCELL + 1023)/1024)
#define PGRID 1024
#define SHAD 32

typedef __attribute__((ext_vector_type(8))) short short8;
typedef __attribute__((ext_vector_type(4))) float f32x4;

__device__ __forceinline__ unsigned short f2bf(float f){
  unsigned int u = __float_as_uint(f);
  u = (u + 0x7fffu + ((u >> 16) & 1u)) >> 16;
  return (unsigned short)u;
}

__device__ __forceinline__ int voxel_id(float x, float y, float z){
  int ix = (int)floorf(x / 0.4f);
  int iy = (int)floorf((y + 40.0f) / 0.4f);
  int iz = (int)floorf((z + 3.0f) / 0.4f);
  if (ix < 0 || iy < 0 || iz < 0 || ix >= GNX || iy >= GNY || iz >= GNZ) return -1;
  return (ix*GNY + iy)*GNZ + iz;
}

extern "C" __global__ void k_count(const float* __restrict__ pts, int* __restrict__ cellcnt){
  int i = blockIdx.x*256 + threadIdx.x;
  if (i >= BATCH*NPTS) return;
  const float* q = pts + (size_t)i*4;
  int vid = voxel_id(q[0], q[1], q[2]);
  if (vid < 0) return;
  int b = i / NPTS;
  atomicAdd(&cellcnt[b*NCELL + vid], 1);
}

extern "C" __global__ void __launch_bounds__(256) k_blkcount(const int* __restrict__ cellcnt,
                                                             int* __restrict__ blks){
  int b = blockIdx.y, blk = blockIdx.x, t = threadIdx.x;
  int base = blk*1024 + t*4;
  int s = 0;
  #pragma unroll
  for (int i=0;i<4;i++){ int c = base+i; if (c < NCELL) s += (cellcnt[b*NCELL+c] > 0); }
  #pragma unroll
  for (int m=32;m>=1;m>>=1) s += __shfl_xor(s, m);
  __shared__ int red[4];
  if ((t&63)==0) red[t>>6] = s;
  __syncthreads();
  if (t==0) blks[b*512+blk] = red[0]+red[1]+red[2]+red[3];
}

extern "C" __global__ void __launch_bounds__(512) k_scan(int* __restrict__ blks){
  int b = blockIdx.x, t = threadIdx.x;
  __shared__ int l[512];
  int orig = (t < SCAN_NB) ? blks[b*512+t] : 0;
  l[t] = orig;
  __syncthreads();
  for (int o=1;o<512;o<<=1){
    int v = (t>=o) ? l[t-o] : 0;
    __syncthreads();
    l[t] += v;
    __syncthreads();
  }
  if (t < SCAN_NB) blks[b*512+t] = l[t] - orig;   // exclusive
}

extern "C" __global__ void __launch_bounds__(256) k_assign(const int* __restrict__ cellcnt,
    const int* __restrict__ blks, int* __restrict__ slotmap, int* __restrict__ vv,
    int* __restrict__ cnt){
  int b = blockIdx.y, blk = blockIdx.x, t = threadIdx.x;
  int base = blk*1024 + t*4;
  int flag[4]; int s = 0;
  #pragma unroll
  for (int i=0;i<4;i++){
    int c = base+i;
    flag[i] = (c < NCELL) ? (cellcnt[b*NCELL+c] > 0) : 0;
    s += flag[i];
  }
  __shared__ int lds[256];
  lds[t] = s; __syncthreads();
  for (int o=1;o<256;o<<=1){
    int v = (t>=o) ? lds[t-o] : 0;
    __syncthreads();
    lds[t] += v;
    __syncthreads();
  }
  int run = blks[b*512+blk] + (lds[t]-s);
  #pragma unroll
  for (int i=0;i<4;i++){
    int c = base+i;
    if (c >= NCELL) break;
    int sm = -1;
    if (flag[i]){
      if (run < MAXV){
        sm = run;
        vv[b*MAXV+run]  = c;
        cnt[b*MAXV+run] = min(cellcnt[b*NCELL+c], PMAX);
      }
      run++;
    }
    slotmap[b*NCELL+c] = sm;
  }
}

extern "C" __global__ void k_fill(const float* __restrict__ pts, const int* __restrict__ slotmap,
                                  int* __restrict__ fill, int* __restrict__ plist){
  int i = blockIdx.x*256 + threadIdx.x;
  if (i >= BATCH*NPTS) return;
  const float* q = pts + (size_t)i*4;
  int vid = voxel_id(q[0], q[1], q[2]);
  if (vid < 0) return;
  int b = i / NPTS;
  int slot = slotmap[b*NCELL+vid];
  if (slot < 0) return;
  int pos = atomicAdd(&fill[b*MAXV+slot], 1);
  if (pos < PMAX) plist[((size_t)b*MAXV+slot)*PMAX + pos] = i - b*NPTS;
}

// gather sorted points into pvox [NVOX][32] float4 + per-voxel mean [NVOX] float4
extern "C" __global__ void __launch_bounds__(256) k_feat(const float* __restrict__ pts,
    const int* __restrict__ cnt, const int* __restrict__ plist,
    float* __restrict__ pvox, float* __restrict__ mean){
  int g  = threadIdx.x >> 5;
  int fv = blockIdx.x*8 + g;
  int p  = threadIdx.x & 31;
  int b  = fv / MAXV;
  __shared__ int lst[8][32];
  int c = cnt[fv];
  if (p < c) lst[g][p] = plist[(size_t)fv*PMAX + p];
  __syncthreads();
  if (p == 0){
    for (int i=1;i<c;i++){
      int key = lst[g][i]; int j = i-1;
      while (j >= 0 && lst[g][j] > key){ lst[g][j+1] = lst[g][j]; j--; }
      lst[g][j+1] = key;
    }
  }
  __syncthreads();
  float4 pt = make_float4(0.f,0.f,0.f,0.f);
  if (p < c) pt = *(const float4*)(pts + ((size_t)b*NPTS + lst[g][p])*4);
  float sx = pt.x, sy = pt.y, sz = pt.z;
  #pragma unroll
  for (int m=16;m>=1;m>>=1){
    sx += __shfl_xor(sx, m, 32); sy += __shfl_xor(sy, m, 32); sz += __shfl_xor(sz, m, 32);
  }
  float cd = (float)max(c, 1);
  if (p < c) *(float4*)(pvox + ((size_t)fv*32 + p)*4) = pt;
  if (p == 0) *(float4*)(mean + (size_t)fv*4) = make_float4(sx/cd, sy/cd, sz/cd, 0.f);
}

#define IN7(pt, mn) {pt.x, pt.y, pt.z, pt.w, pt.x-mn.x, pt.y-mn.y, pt.z-mn.z}

// ============ PFN phases: software-pipelined voxel loops ============
extern "C" __global__ void __launch_bounds__(256) k_p1(const float* __restrict__ pvox,
    const float* __restrict__ mean, const int* __restrict__ cnt,
    const float* __restrict__ w1, float* __restrict__ st){
  __shared__ float w1L[224];
  __shared__ float sred[64];
  int tid = threadIdx.x;
  if (tid < 56) ((float4*)w1L)[tid] = ((const float4*)w1)[tid];
  if (tid < 64) sred[tid] = 0.f;
  __syncthreads();
  int w = tid>>6, lane = tid&63, c = lane&31, half = lane>>5;
  const int STR = PGRID*4;
  int fv = blockIdx.x*4 + w;
  int c_n = 0;
  float4 mn_n = make_float4(0.f,0.f,0.f,0.f), pA_n = mn_n;
  if (fv < NVOX){
    c_n  = cnt[fv];
    mn_n = *(const float4*)(mean + (size_t)fv*4);
    pA_n = *(const float4*)(pvox + ((size_t)fv*32 + half)*4);
  }
  float S=0.f, Q=0.f;
  while (fv < NVOX){
    const int fvc = fv;
    const int c_ = c_n;
    const float4 mn = mn_n, pA = pA_n;
    fv += STR;
    if (fv < NVOX){
      c_n  = cnt[fv];
      mn_n = *(const float4*)(mean + (size_t)fv*4);
      pA_n = *(const float4*)(pvox + ((size_t)fv*32 + half)*4);
    }
    {
      float in[7] = IN7(pA, mn);
      float v = 0.f;
      #pragma unroll
      for (int k=0;k<7;k++) v += in[k]*w1L[k*32+c];
      if (half < c_){ S += v; Q += v*v; }
    }
    for (int p = half+2; p < c_; p += 2){
      float4 pt = *(const float4*)(pvox + ((size_t)fvc*32+p)*4);
      float in[7] = IN7(pt, mn);
      float v = 0.f;
      #pragma unroll
      for (int k=0;k<7;k++) v += in[k]*w1L[k*32+c];
      S += v; Q += v*v;
    }
  }
  S += __shfl_xor(S,32); Q += __shfl_xor(Q,32);
  if (half==0){ atomicAdd(&sred[c],S); atomicAdd(&sred[32+c],Q); }
  __syncthreads();
  if (tid<64) atomicAdd(&st[(blockIdx.x&(SHAD-1))*64+tid], sred[tid]);
}

extern "C" __global__ void __launch_bounds__(256) k_p2(const float* __restrict__ pvox,
    const float* __restrict__ mean, const int* __restrict__ cnt,
    const float* __restrict__ w1, const float* __restrict__ g1, const float* __restrict__ b1,
    const float* __restrict__ w2, const float* __restrict__ st1, float* __restrict__ st2,
    float* __restrict__ K2buf){
  __shared__ float w1L[224];
  __shared__ float w2L[2496];
  __shared__ float sred[128];
  int tid = threadIdx.x;
  if (tid < 56) ((float4*)w1L)[tid] = ((const float4*)w1)[tid];
  for (int i=tid;i<624;i+=256) ((float4*)w2L)[i] = ((const float4*)w2)[i];
  if (tid < 128) sred[tid] = 0.f;
  __syncthreads();
  int w = tid>>6, lane = tid&63, c1 = lane&31;
  const float invN = 1.f/(float)NPFN;
  float m1=0.f, v1s=0.f;
  #pragma unroll
  for (int s=0;s<SHAD;s++){ m1 += st1[s*64+c1]; v1s += st1[s*64+32+c1]; }
  m1 *= invN; v1s = v1s*invN - m1*m1;
  float sc1 = g1[c1]*rsqrtf(v1s + 1e-3f);
  float sh1 = b1[c1] - m1*sc1;
  const int STR = PGRID*4;
  int fv = blockIdx.x*4 + w;
  int c_n = 0;
  float4 mn_n = make_float4(0.f,0.f,0.f,0.f), p0_n = mn_n, p1_n = mn_n;
  if (fv < NVOX){
    c_n  = cnt[fv];
    mn_n = *(const float4*)(mean + (size_t)fv*4);
    p0_n = *(const float4*)(pvox + ((size_t)fv*32+0)*4);
    p1_n = *(const float4*)(pvox + ((size_t)fv*32+1)*4);
  }
  float S = 0.f, Q = 0.f;
  while (fv < NVOX){
    const int fvc = fv;
    const int c_ = c_n;
    const float4 mn = mn_n, p0 = p0_n, p1 = p1_n;
    fv += STR;
    if (fv < NVOX){
      c_n  = cnt[fv];
      mn_n = *(const float4*)(mean + (size_t)fv*4);
      p0_n = *(const float4*)(pvox + ((size_t)fv*32+0)*4);
      p1_n = *(const float4*)(pvox + ((size_t)fv*32+1)*4);
    }
    float vm = 0.f, sa = 0.f, sq = 0.f;
    {
      float in[7] = IN7(p0, mn);
      float v1 = 0.f, a2 = 0.f;
      #pragma unroll
      for (int k=0;k<7;k++){ v1 += in[k]*w1L[k*32+c1]; a2 += in[k]*w2L[k*64+lane]; }
      if (c_ > 0){ vm = fmaxf(vm, v1*sc1 + sh1); sa += a2; sq += a2*a2; }
    }
    {
      float in[7] = IN7(p1, mn);
      float v1 = 0.f, a2 = 0.f;
      #pragma unroll
      for (int k=0;k<7;k++){ v1 += in[k]*w1L[k*32+c1]; a2 += in[k]*w2L[k*64+lane]; }
      if (c_ > 1){ vm = fmaxf(vm, v1*sc1 + sh1); sa += a2; sq += a2*a2; }
    }
    for (int p = 2; p < c_; p++){
      float4 pt = *(const float4*)(pvox + ((size_t)fvc*32+p)*4);
      float in[7] = IN7(pt, mn);
      float v1 = 0.f, a2 = 0.f;
      #pragma unroll
      for (int k=0;k<7;k++){ v1 += in[k]*w1L[k*32+c1]; a2 += in[k]*w2L[k*64+lane]; }
      vm = fmaxf(vm, v1*sc1 + sh1);
      sa += a2; sq += a2*a2;
    }
    float k0=0.f,k1=0.f,k2=0.f,k3=0.f;
    #pragma unroll
    for (int j=0;j<32;j+=4){
      k0 += __shfl(vm, j  )*w2L[(7+j )*64+lane];
      k1 += __shfl(vm, j+1)*w2L[(8+j )*64+lane];
      k2 += __shfl(vm, j+2)*w2L[(9+j )*64+lane];
      k3 += __shfl(vm, j+3)*w2L[(10+j)*64+lane];
    }
    float K = (k0+k1)+(k2+k3);
    if (c_) K2buf[(size_t)fvc*64 + lane] = K;
    S += (float)PMAX*K + sa;
    Q += (float)PMAX*K*K + sq + 2.f*K*sa;
  }
  atomicAdd(&sred[lane], S); atomicAdd(&sred[64+lane], Q);
  __syncthreads();
  if (tid < 128) atomicAdd(&st2[(blockIdx.x&(SHAD-1))*128 + tid], sred[tid]);
}

extern "C" __global__ void __launch_bounds__(256) k_p3(const float* __restrict__ pvox,
    const float* __restrict__ mean, const int* __restrict__ cnt,
    const float* __restrict__ w2, const float* __restrict__ g2, const float* __restrict__ b2,
    const float* __restrict__ w3, const float* __restrict__ g3,
    const float* __restrict__ st2, float* __restrict__ st3,
    const float* __restrict__ K2buf, float2* __restrict__ KAbuf){
  __shared__ float w2L[2496];
  __shared__ float w3L[4544];
  __shared__ float sred[128];
  int tid = threadIdx.x;
  for (int i=tid;i<624;i+=256)  ((float4*)w2L)[i] = ((const float4*)w2)[i];
  for (int i=tid;i<1136;i+=256) ((float4*)w3L)[i] = ((const float4*)w3)[i];
  if (tid < 128) sred[tid] = 0.f;
  __syncthreads();
  int w = tid>>6, lane = tid&63;
  const float invN = 1.f/(float)NPFN;
  float m2=0.f, v2s=0.f;
  #pragma unroll
  for (int s=0;s<SHAD;s++){ m2 += st2[s*128+lane]; v2s += st2[s*128+64+lane]; }
  m2 *= invN; v2s = v2s*invN - m2*m2;
  float sc2 = g2[lane]*rsqrtf(v2s + 1e-3f);
  float sh2 = b2[lane] - m2*sc2;
  bool pickmax = (g3[lane] >= 0.f);
  const int STR = PGRID*4;
  int fv = blockIdx.x*4 + w;
  int c_n = 0; float K2_n = 0.f;
  float4 mn_n = make_float4(0.f,0.f,0.f,0.f), p0_n = mn_n, p1_n = mn_n;
  if (fv < NVOX){
    c_n  = cnt[fv];
    mn_n = *(const float4*)(mean + (size_t)fv*4);
    K2_n = K2buf[(size_t)fv*64 + lane];
    p0_n = *(const float4*)(pvox + ((size_t)fv*32+0)*4);
    p1_n = *(const float4*)(pvox + ((size_t)fv*32+1)*4);
  }
  float S = 0.f, Q = 0.f;
  while (fv < NVOX){
    const int fvc = fv;
    const int c_ = c_n;
    const float K2 = K2_n;
    const float4 mn = mn_n, p0 = p0_n, p1 = p1_n;
    fv += STR;
    if (fv < NVOX){
      c_n  = cnt[fv];
      mn_n = *(const float4*)(mean + (size_t)fv*4);
      K2_n = K2buf[(size_t)fv*64 + lane];
      p0_n = *(const float4*)(pvox + ((size_t)fv*32+0)*4);
      p1_n = *(const float4*)(pvox + ((size_t)fv*32+1)*4);
    }
    float vm = 0.f, sa = 0.f, sq = 0.f;
    float amx = -3.4e38f, amn = 3.4e38f;
    {
      float in[7] = IN7(p0, mn);
      float a2 = 0.f, a3 = 0.f;
      #pragma unroll
      for (int k=0;k<7;k++){ a2 += in[k]*w2L[k*64+lane]; a3 += in[k]*w3L[k*64+lane]; }
      if (c_ > 0){
        vm = fmaxf(vm, (a2+K2)*sc2 + sh2);
        sa += a3; sq += a3*a3;
        amx = fmaxf(amx, a3); amn = fminf(amn, a3);
      }
    }
    {
      float in[7] = IN7(p1, mn);
      float a2 = 0.f, a3 = 0.f;
      #pragma unroll
      for (int k=0;k<7;k++){ a2 += in[k]*w2L[k*64+lane]; a3 += in[k]*w3L[k*64+lane]; }
      if (c_ > 1){
        vm = fmaxf(vm, (a2+K2)*sc2 + sh2);
        sa += a3; sq += a3*a3;
        amx = fmaxf(amx, a3); amn = fminf(amn, a3);
      }
    }
    for (int p = 2; p < c_; p++){
      float4 pt = *(const float4*)(pvox + ((size_t)fvc*32+p)*4);
      float in[7] = IN7(pt, mn);
      float a2 = 0.f, a3 = 0.f;
      #pragma unroll
      for (int k=0;k<7;k++){ a2 += in[k]*w2L[k*64+lane]; a3 += in[k]*w3L[k*64+lane]; }
      vm = fmaxf(vm, (a2+K2)*sc2 + sh2);
      sa += a3; sq += a3*a3;
      amx = fmaxf(amx, a3); amn = fminf(amn, a3);
    }
    float k0=0.f,k1=0.f,k2=0.f,k3=0.f;
    #pragma unroll
    for (int j=0;j<64;j+=4){
      k0 += __shfl(vm, j  )*w3L[(7+j )*64+lane];
      k1 += __shfl(vm, j+1)*w3L[(8+j )*64+lane];
      k2 += __shfl(vm, j+2)*w3L[(9+j )*64+lane];
      k3 += __shfl(vm, j+3)*w3L[(10+j)*64+lane];
    }
    float K3 = (k0+k1)+(k2+k3);
    if (c_){
      float2 ka; ka.x = K3; ka.y = pickmax ? amx : amn;
      KAbuf[(size_t)fvc*64 + lane] = ka;
    }
    S += (float)PMAX*K3 + sa;
    Q += (float)PMAX*K3*K3 + sq + 2.f*K3*sa;
  }
  atomicAdd(&sred[lane], S); atomicAdd(&sred[64+lane], Q);
  __syncthreads();
  if (tid < 128) atomicAdd(&st3[(blockIdx.x&(SHAD-1))*128 + tid], sred[tid]);
}

// p4: loop-free — vf = relu((asel + K3)*sc + sh), scatter-max NHWC
extern "C" __global__ void __launch_bounds__(256) k_p4(const int* __restrict__ cnt,
    const int* __restrict__ vv, const float* __restrict__ g3, const float* __restrict__ b3,
    const float* __restrict__ st3, const float2* __restrict__ KAbuf,
    float* __restrict__ bev){
  int tid = threadIdx.x;
  int w = tid>>6, lane = tid&63;
  const float invN = 1.f/(float)NPFN;
  float m3=0.f, q3=0.f;
  #pragma unroll
  for (int s=0;s<SHAD;s++){ m3 += st3[s*128+lane]; q3 += st3[s*128+64+lane]; }
  m3 *= invN;
  float va = q3*invN - m3*m3;
  float sc = g3[lane]*rsqrtf(va + 1e-3f);
  float sh = b3[lane] - m3*sc;
  for (int fv = blockIdx.x*4 + w; fv < NVOX; fv += PGRID*4){
    int c_ = cnt[fv];
    if (!c_) continue;
    float2 ka = KAbuf[(size_t)fv*64 + lane];
    float vf = fmaxf(0.f, (ka.y + ka.x)*sc + sh);
    int vid = vv[fv];
    int b   = fv / MAXV;
    int cx  = vid / (GNY*GNZ);
    int cy  = (vid / GNZ) % GNY;
    atomicMax((int*)(bev + (((size_t)b*NPIX + (size_t)cy*CONVW + cx)*64) + lane),
              __float_as_int(vf));
  }
}

// ---- weight prepack: [oc][ic][3][3] f32 -> [tap][oc][ic] bf16, 5 layers
extern "C" __global__ void k_wprep(const float* __restrict__ cs_w, const float* __restrict__ rpn_w,
                                   unsigned short* __restrict__ Bw){
  int i = blockIdx.x*256 + threadIdx.x;
  if (i >= 5*36864) return;
  int l = i/36864, r = i - l*36864;
  int tap = r >> 12, oc = (r >> 6) & 63, ic = r & 63;
  const float* src = (l < 2) ? (cs_w + (size_t)l*36864) : (rpn_w + (size_t)(l-2)*36864);
  Bw[i] = f2bf(src[((size_t)oc*64 + ic)*9 + tap]);
}

// ---- conv3x3: implicit GEMM, bf16 MFMA. Tile 16x * 8y, 4 waves (2 rows ea),
//      576 MFMA/block, fused BN/relu/cvt on staging, shadowed stats.
#define CTH 8
extern "C" __global__ void __launch_bounds__(256) k_conv(const float* __restrict__ in,
    const float* __restrict__ stin, const float* __restrict__ g, const float* __restrict__ be,
    const unsigned short* __restrict__ Bw, const float* __restrict__ bias,
    float* __restrict__ out, float* __restrict__ st){
  const int b  = blockIdx.z;
  const int x0 = blockIdx.x*16, y0 = blockIdx.y*CTH;
  const int tid = threadIdx.x;
  const int w = tid >> 6, l = tid & 63;
  const int l15 = l & 15, quad = l >> 4;
  const int bid = (blockIdx.z*gridDim.y + blockIdx.y)*gridDim.x + blockIdx.x;
  const int shad = bid & (SHAD-1);

  __shared__ unsigned short smemA[(CTH+2)*18*64];
  __shared__ float bnsc[64], bnsh[64];
  __shared__ float sA[64], sQ[64];
  if (tid < 64){
    sA[tid] = 0.f; sQ[tid] = 0.f;
    float sc = 1.f, sh = 0.f;
    if (stin){
      const float invN = 1.f/(float)(BATCH*NPIX);
      float m = 0.f, q = 0.f;
      #pragma unroll
      for (int s=0;s<SHAD;s++){ m += stin[s*128+tid]; q += stin[s*128+64+tid]; }
      m *= invN;
      float va = q*invN - m*m;
      sc = g[tid]*rsqrtf(va + 1e-5f);
      sh = be[tid] - m*sc;
    }
    bnsc[tid] = sc; bnsh[tid] = sh;
  }
  __syncthreads();

  for (int i = tid; i < (CTH+2)*18*8; i += 256){
    int pos = i >> 3, jb = i & 7;
    int yp = pos/18, xp = pos - yp*18;
    int gy = y0 + yp - 1, gx = x0 + xp - 1;
    unsigned short h[8] = {0,0,0,0,0,0,0,0};
    if (gy >= 0 && gy < CONVH && gx >= 0 && gx < CONVW){
      const float* src = in + (((size_t)b*NPIX + (size_t)gy*CONVW + gx)*64 + jb*8);
      float4 v0 = *(const float4*)src;
      float4 v1 = *(const float4*)(src+4);
      float vv[8] = {v0.x,v0.y,v0.z,v0.w,v1.x,v1.y,v1.z,v1.w};
      #pragma unroll
      for (int k=0;k<8;k++){
        int c = jb*8 + k;
        h[k] = f2bf(fmaxf(vv[k]*bnsc[c] + bnsh[c], 0.f));
      }
    }
    int jsw = jb ^ (xp & 7);
    *(uint4*)&smemA[pos*64 + jsw*8] = *(uint4*)h;
  }
  __syncthreads();

  f32x4 acc[2][4] = {{{0.f,0.f,0.f,0.f},{0.f,0.f,0.f,0.f},{0.f,0.f,0.f,0.f},{0.f,0.f,0.f,0.f}},
                     {{0.f,0.f,0.f,0.f},{0.f,0.f,0.f,0.f},{0.f,0.f,0.f,0.f},{0.f,0.f,0.f,0.f}}};
  #pragma unroll
  for (int tap = 0; tap < 9; tap++){
    const int dy = tap/3, dx = tap - dy*3;
    const int xp = l15 + dx;
    const int xm = xp & 7;
    short8 b0[4], b1[4];
    #pragma unroll
    for (int nt = 0; nt < 4; nt++){
      const unsigned short* bp = Bw + (((size_t)tap*64 + nt*16 + l15)*64 + quad*8);
      b0[nt] = *(const short8*)bp;
      b1[nt] = *(const short8*)(bp + 32);
    }
    #pragma unroll
    for (int rr = 0; rr < 2; rr++){
      int yp = 2*w + rr + dy;
      int abase = (yp*18 + xp)*64;
      short8 aL = *(const short8*)&smemA[abase + ((quad    ) ^ xm)*8];
      short8 aH = *(const short8*)&smemA[abase + ((4 + quad) ^ xm)*8];
      #pragma unroll
      for (int nt = 0; nt < 4; nt++)
        acc[rr][nt] = __builtin_amdgcn_mfma_f32_16x16x32_bf16(aL, b0[nt], acc[rr][nt], 0,0,0);
      #pragma unroll
      for (int nt = 0; nt < 4; nt++)
        acc[rr][nt] = __builtin_amdgcn_mfma_f32_16x16x32_bf16(aH, b1[nt], acc[rr][nt], 0,0,0);
    }
  }

  #pragma unroll
  for (int nt = 0; nt < 4; nt++){
    int oc = nt*16 + l15;
    float bv = bias[oc];
    float s = 0.f, q = 0.f;
    #pragma unroll
    for (int rr = 0; rr < 2; rr++){
      int y = y0 + 2*w + rr;
      size_t rbase = ((size_t)b*NPIX + (size_t)y*CONVW)*64;
      #pragma unroll
      for (int r = 0; r < 4; r++){
        float v = acc[rr][nt][r] + bv;
        int x = x0 + quad*4 + r;
        out[rbase + (size_t)x*64 + oc] = v;
        s += v; q += v*v;
      }
    }
    s += __shfl_xor(s, 16); s += __shfl_xor(s, 32);
    q += __shfl_xor(q, 16); q += __shfl_xor(q, 32);
    if (quad == 0){ atomicAdd(&sA[oc], s); atomicAdd(&sQ[oc], q); }
  }
  __syncthreads();
  if (tid < 64){
    atomicAdd(&st[shad*128 + tid], sA[tid]);
    atomicAdd(&st[shad*128 + 64 + tid], sQ[tid]);
  }
}

// ---- head 1x1: fused BN/relu of last conv layer
extern "C" __global__ void __launch_bounds__(256) k_head(const float* __restrict__ in,
    const float* __restrict__ stin, const float* __restrict__ g, const float* __restrict__ be,
    const float* __restrict__ hw, const float* __restrict__ hb, float* __restrict__ outp){
  __shared__ float bnsc[64], bnsh[64];
  int tid = threadIdx.x;
  if (tid < 64){
    const float invN = 1.f/(float)(BATCH*NPIX);
    float m = 0.f, q = 0.f;
    #pragma unroll
    for (int s=0;s<SHAD;s++){ m += stin[s*128+tid]; q += stin[s*128+64+tid]; }
    m *= invN;
    float va = q*invN - m*m;
    float sc = g[tid]*rsqrtf(va + 1e-5f);
    bnsc[tid] = sc; bnsh[tid] = be[tid] - m*sc;
  }
  __syncthreads();
  int i = blockIdx.x*256 + tid;
  if (i >= BATCH*NPIX) return;
  const float* base = in + (size_t)i*64;
  float a0 = hb[0], a1 = hb[1], a2 = hb[2];
  #pragma unroll
  for (int jb = 0; jb < 16; jb++){
    float4 v = *(const float4*)(base + jb*4);
    float vv[4] = {v.x, v.y, v.z, v.w};
    #pragma unroll
    for (int e = 0; e < 4; e++){
      int ic = jb*4 + e;
      float h = fmaxf(vv[e]*bnsc[ic] + bnsh[ic], 0.f);
      a0 += h*hw[ic]; a1 += h*hw[64+ic]; a2 += h*hw[128+ic];
    }
  }
  size_t o = (size_t)i*3;
  outp[o+0] = a0; outp[o+1] = a1; outp[o+2] = a2;
}

extern "C" void kernel_launch(void* const* d_in, const int* in_sizes, int n_in,
                              void* d_out, int out_size, void* d_ws, size_t ws_size,
                              hipStream_t stream){
  (void)in_sizes; (void)n_in; (void)out_size;
  const float* pts   = (const float*)d_in[0];
  const float* w1    = (const float*)d_in[1];
  const float* g1    = (const float*)d_in[2];
  const float* b1    = (const float*)d_in[3];
  const float* w2    = (const float*)d_in[4];
  const float* g2    = (const float*)d_in[5];
  const float* b2    = (const float*)d_in[6];
  const float* w3    = (const float*)d_in[7];
  const float* g3    = (const float*)d_in[8];
  const float* b3    = (const float*)d_in[9];
  const float* cs_w  = (const float*)d_in[10];
  const float* cs_b  = (const float*)d_in[11];
  const float* cs_g  = (const float*)d_in[12];
  const float* cs_be = (const float*)d_in[13];
  const float* rpn_w = (const float*)d_in[14];
  const float* rpn_b = (const float*)d_in[15];
  const float* rpn_g = (const float*)d_in[16];
  const float* rpn_be= (const float*)d_in[17];
  const float* hw    = (const float*)d_in[18];
  const float* hb    = (const float*)d_in[19];

  char* ws = (char*)d_ws;
  size_t off = 0;
  auto alloc = [&](size_t bytes)->char*{
    char* p = ws + off; off += (bytes + 255) & ~(size_t)255; return p;
  };
  // ---- zero region (single memset) ----
  int*   cellcnt = (int*)  alloc((size_t)BATCH*NCELL*4);
  int*   vv      = (int*)  alloc((size_t)NVOX*4);
  int*   cnt     = (int*)  alloc((size_t)NVOX*4);
  int*   fill    = (int*)  alloc((size_t)NVOX*4);
  float* stats   = (float*)alloc(131072);
  size_t zbytes  = off;
  // ---- no-init region ----
  int*   slotmap = (int*)  alloc((size_t)BATCH*NCELL*4);
  int*   blks    = (int*)  alloc((size_t)BATCH*512*4);
  int*   plist   = (int*)  alloc((size_t)NVOX*PMAX*4);      // conv alias start, 5.12MB
  float* pvox    = (float*)alloc((size_t)NVOX*PMAX*16);     // 20.48MB
  float* mean    = (float*)alloc((size_t)NVOX*16);          // 0.64MB
  float* K2buf   = (float*)alloc((size_t)NVOX*64*4);        // 10.24MB (alias end)
  float2* KAbuf  = (float2*)alloc((size_t)NVOX*64*8);       // 20.48MB
  float* bevf    = (float*)alloc((size_t)NELEM*4);          // 18.02MB
  unsigned short* Bw = (unsigned short*)alloc((size_t)5*36864*2);
  if (off > ws_size) return;

  float* st1 = stats;            // [32][64]
  float* st2 = stats + 2048;     // [32][128]
  float* st3 = stats + 6144;     // [32][128]
  float* stc = stats + 10240;    // 5 x [32][128]

  // conv ping-pong aliases plist..K2buf (36.49MB contiguous, dead before convs)
  float* convA = (float*)plist;
  float* convB = (float*)((char*)plist + 18022400);

  hipMemsetAsync(ws, 0, zbytes, stream);
  hipMemsetAsync(bevf, 0, (size_t)NELEM*4, stream);

  k_count <<<(BATCH*NPTS+255)/256, 256, 0, stream>>>(pts, cellcnt);
  k_blkcount<<<dim3(SCAN_NB,BATCH), 256, 0, stream>>>(cellcnt, blks);
  k_scan  <<<BATCH, 512, 0, stream>>>(blks);
  k_assign<<<dim3(SCAN_NB,BATCH), 256, 0, stream>>>(cellcnt, blks, slotmap, vv, cnt);
  k_fill  <<<(BATCH*NPTS+255)/256, 256, 0, stream>>>(pts, slotmap, fill, plist);
  k_feat  <<<NVOX/8, 256, 0, stream>>>(pts, cnt, plist, pvox, mean);

  k_p1<<<PGRID, 256, 0, stream>>>(pvox, mean, cnt, w1, st1);
  k_p2<<<PGRID, 256, 0, stream>>>(pvox, mean, cnt, w1, g1, b1, w2, st1, st2, K2buf);
  k_p3<<<PGRID, 256, 0, stream>>>(pvox, mean, cnt, w2, g2, b2, w3, g3, st2, st3,
                                  K2buf, KAbuf);
  k_wprep<<<(5*36864+255)/256, 256, 0, stream>>>(cs_w, rpn_w, Bw);
  k_p4<<<PGRID, 256, 0, stream>>>(cnt, vv, g3, b3, st3, KAbuf, bevf);

  const float* bptr[5]  = {cs_b, cs_b+64,   rpn_b, rpn_b+64,   rpn_b+128};
  const float* gptr[5]  = {cs_g, cs_g+64,   rpn_g, rpn_g+64,   rpn_g+128};
  const float* beptr[5] = {cs_be,cs_be+64,  rpn_be,rpn_be+64,  rpn_be+128};
  const float* srcs[5]  = {bevf, convA, convB, convA, convB};
  float*       dsts[5]  = {convA, convB, convA, convB, convA};
  dim3 cgrid(CONVW/16, CONVH/CTH, BATCH);
  for (int ll = 0; ll < 5; ll++){
    const float* stin = (ll == 0) ? (const float*)nullptr : (stc + (ll-1)*4096);
    const float* gg   = (ll == 0) ? g1 : gptr[ll-1];   // unused when stin==null
    const float* bb   = (ll == 0) ? b1 : beptr[ll-1];
    k_conv<<<cgrid, 256, 0, stream>>>(srcs[ll], stin, gg, bb,
                                      Bw + (size_t)ll*36864, bptr[ll], dsts[ll],
                                      stc + ll*4096);
  }
  k_head<<<(BATCH*NPIX+255)/256, 256, 0, stream>>>(convA, stc + 4*4096, gptr[4], beptr[4],
                                                   hw, hb, (float*)d_out);
}